// Round 7
// baseline (675.229 us; speedup 1.0000x reference)
//
#include <hip/hip_runtime.h>
#include <hip/hip_fp16.h>

#define HD 64
#define SEQ 2304

typedef unsigned short u16;
typedef unsigned int u32;
using f32x4 = __attribute__((ext_vector_type(4))) float;
using s16x8 = __attribute__((ext_vector_type(8))) short;

static __device__ __forceinline__ float bf2f(u16 h) {
  union { float f; u32 u; } a; a.u = ((u32)h) << 16; return a.f;
}
// truncation split: x ~= hi + lo, |err| ~ 2^-16 |x|; dropped lo*lo term in products
static __device__ __forceinline__ void split2(float x, u16& h, u16& l) {
  u32 u = __float_as_uint(x);
  h = (u16)(u >> 16);
  float r = x - __uint_as_float(u & 0xffff0000u);
  l = (u16)(__float_as_uint(r) >> 16);
}

// ---------------- split fp32 -> bf16 hi/lo (no transpose), 8 elems/thread
__global__ __launch_bounds__(256) void conv_split_k(
    const float* __restrict__ src, u16* __restrict__ dhi, u16* __restrict__ dlo)
{
  const size_t i = ((size_t)blockIdx.x * 256 + threadIdx.x) * 8;
  f32x4 a = *(const f32x4*)(src + i);
  f32x4 b = *(const f32x4*)(src + i + 4);
  u16 h[8], l[8];
#pragma unroll
  for (int j = 0; j < 8; j++) {
    float x = j < 4 ? a[j] : b[j - 4];
    split2(x, h[j], l[j]);
  }
  *(uint4*)(dhi + i) = *(uint4*)&h[0];
  *(uint4*)(dlo + i) = *(uint4*)&l[0];
}

// ---------------- convert + transpose weights: w[K][N] f32 -> wT[N][K] bf16 hi/lo
__global__ __launch_bounds__(256) void conv_wT_k(
    const float* __restrict__ src, u16* __restrict__ dhi, u16* __restrict__ dlo,
    int K, int N)
{
  __shared__ u32 t[64][65];
  const int tid = threadIdx.x;
  const int n0 = blockIdx.x * 64, k0 = blockIdx.y * 64;
  const int r = tid >> 2, c0 = (tid & 3) * 16;
  const float* sp = src + (size_t)(k0 + r) * N + n0 + c0;
#pragma unroll
  for (int j = 0; j < 16; j += 4) {
    f32x4 v = *(const f32x4*)(sp + j);
#pragma unroll
    for (int e = 0; e < 4; e++) {
      u16 h, l;
      split2(v[e], h, l);
      t[r][c0 + j + e] = (u32)h | ((u32)l << 16);
    }
  }
  __syncthreads();
  u16 hb[16], lb[16];
#pragma unroll
  for (int j = 0; j < 16; j++) {
    u32 p = t[c0 + j][r];
    hb[j] = (u16)(p & 0xffffu);
    lb[j] = (u16)(p >> 16);
  }
  size_t off = (size_t)(n0 + r) * K + k0 + c0;
  *(uint4*)(dhi + off)     = *(uint4*)&hb[0];
  *(uint4*)(dhi + off + 8) = *(uint4*)&hb[8];
  *(uint4*)(dlo + off)     = *(uint4*)&lb[0];
  *(uint4*)(dlo + off + 8) = *(uint4*)&lb[8];
}

// ---------------- QKV GEMM via split-bf16 MFMA (A pre-split): -> q fp32 + K/V images
__global__ __launch_bounds__(256) void qkv_mfma_k(
    const u16* __restrict__ xhi, const u16* __restrict__ xlo,
    const u16* __restrict__ bthi, const u16* __restrict__ btlo,
    const float* __restrict__ bias,
    float* __restrict__ qbuf, u16* __restrict__ khi, u16* __restrict__ klo,
    u16* __restrict__ vhi, u16* __restrict__ vlo)
{
  __shared__ __align__(16) u16 Ah[128*40], Al[128*40], Bh2[128*40], Bl2[128*40];
  const int tid = threadIdx.x;
  const int lane = tid & 63, wid = tid >> 6;
  const int g = lane >> 4, ql = lane & 15;
  const int wr = wid >> 1, wc = wid & 1;
  const int c0 = blockIdx.x * 128, r0 = blockIdx.y * 128;
  const int srow = tid >> 1, half = tid & 1;

  const u16* agh = xhi + (size_t)(r0 + srow) * 768 + half * 16;
  const u16* agl = xlo + (size_t)(r0 + srow) * 768 + half * 16;
  const u16* bgh = bthi + (size_t)(c0 + srow) * 768 + half * 16;
  const u16* bgl = btlo + (size_t)(c0 + srow) * 768 + half * 16;

  uint4 pah[2], pal[2], pbh[2], pbl[2];
  pah[0] = *(const uint4*)agh; pah[1] = *(const uint4*)(agh + 8);
  pal[0] = *(const uint4*)agl; pal[1] = *(const uint4*)(agl + 8);
  pbh[0] = *(const uint4*)bgh; pbh[1] = *(const uint4*)(bgh + 8);
  pbl[0] = *(const uint4*)bgl; pbl[1] = *(const uint4*)(bgl + 8);

  f32x4 acc[4][4] = {};

  for (int ks = 0; ks < 24; ks++) {
    __syncthreads();
    {
      u16* d1 = Ah + srow * 40 + half * 16;
      u16* d2 = Al + srow * 40 + half * 16;
      u16* d3 = Bh2 + srow * 40 + half * 16;
      u16* d4 = Bl2 + srow * 40 + half * 16;
      *(uint4*)d1 = pah[0]; *(uint4*)(d1 + 8) = pah[1];
      *(uint4*)d2 = pal[0]; *(uint4*)(d2 + 8) = pal[1];
      *(uint4*)d3 = pbh[0]; *(uint4*)(d3 + 8) = pbh[1];
      *(uint4*)d4 = pbl[0]; *(uint4*)(d4 + 8) = pbl[1];
    }
    __syncthreads();
    if (ks < 23) {
      const int o = (ks + 1) * 32;
      pah[0] = *(const uint4*)(agh + o); pah[1] = *(const uint4*)(agh + o + 8);
      pal[0] = *(const uint4*)(agl + o); pal[1] = *(const uint4*)(agl + o + 8);
      pbh[0] = *(const uint4*)(bgh + o); pbh[1] = *(const uint4*)(bgh + o + 8);
      pbl[0] = *(const uint4*)(bgl + o); pbl[1] = *(const uint4*)(bgl + o + 8);
    }
    s16x8 bfh[4], bfl[4];
#pragma unroll
    for (int nt = 0; nt < 4; nt++) {
      bfh[nt] = *(const s16x8*)(Bh2 + (wc * 64 + nt * 16 + ql) * 40 + g * 8);
      bfl[nt] = *(const s16x8*)(Bl2 + (wc * 64 + nt * 16 + ql) * 40 + g * 8);
    }
#pragma unroll
    for (int mt = 0; mt < 4; mt++) {
      s16x8 ah = *(const s16x8*)(Ah + (wr * 64 + mt * 16 + ql) * 40 + g * 8);
      s16x8 al = *(const s16x8*)(Al + (wr * 64 + mt * 16 + ql) * 40 + g * 8);
#pragma unroll
      for (int nt = 0; nt < 4; nt++) {
        acc[mt][nt] = __builtin_amdgcn_mfma_f32_16x16x32_bf16(ah, bfh[nt], acc[mt][nt], 0, 0, 0);
        acc[mt][nt] = __builtin_amdgcn_mfma_f32_16x16x32_bf16(ah, bfl[nt], acc[mt][nt], 0, 0, 0);
        acc[mt][nt] = __builtin_amdgcn_mfma_f32_16x16x32_bf16(al, bfh[nt], acc[mt][nt], 0, 0, 0);
      }
    }
  }
  // ---- epilogue: scatter to q fp32 / K,V permuted tile-images
  const int col0 = c0 + wc * 64;
  const int row0 = r0 + wr * 64;
  const int hb36 = col0 >> 6;
  const int which = hb36 / 12, head = hb36 - (hb36 / 12) * 12;
  const int b = row0 / 2304;
  const int sb = row0 - b * 2304;
  const int bh = b * 12 + head;
  float bb[4];
#pragma unroll
  for (int nt = 0; nt < 4; nt++) bb[nt] = bias[col0 + nt * 16 + ql];
  if (which == 0) {
#pragma unroll
    for (int mt = 0; mt < 4; mt++)
#pragma unroll
      for (int nt = 0; nt < 4; nt++)
#pragma unroll
        for (int r = 0; r < 4; r++) {
          int s = sb + mt * 16 + g * 4 + r;
          qbuf[((size_t)bh * SEQ + s) * 64 + nt * 16 + ql] = acc[mt][nt][r] + bb[nt];
        }
  } else {
    const int kt = sb >> 6;
    const size_t tile = ((size_t)bh * 36 + kt) * 4096;
    if (which == 1) {
#pragma unroll
      for (int mt = 0; mt < 4; mt++)
#pragma unroll
        for (int nt = 0; nt < 4; nt++) {
          int pc = (nt >> 1) * 32 + (ql >> 2) * 8 + (nt & 1) * 4 + (ql & 3);
#pragma unroll
          for (int r = 0; r < 4; r++) {
            int key = mt * 16 + g * 4 + r;
            u16 h, l;
            split2(acc[mt][nt][r] + bb[nt], h, l);
            khi[tile + key * 64 + pc] = h;
            klo[tile + key * 64 + pc] = l;
          }
        }
    } else {
#pragma unroll
      for (int mt = 0; mt < 4; mt++)
#pragma unroll
        for (int nt = 0; nt < 4; nt++)
#pragma unroll
          for (int r = 0; r < 4; r++) {
            int d = nt * 16 + ql;
            int vc = (mt >> 1) * 32 + g * 8 + (mt & 1) * 4 + r;
            u16 h, l;
            split2(acc[mt][nt][r] + bb[nt], h, l);
            vhi[tile + d * 64 + vc] = h;
            vlo[tile + d * 64 + vc] = l;
          }
    }
  }
}

// ---------------- Fused attention: LDS-staged K/V, 128 q-rows/block, lean softmax.
// grid(bh=24, qt=18): bh%8 pins each head's K/V image to one XCD L2.
#define BHP_OFF 36864
#define BWP_OFF (BHP_OFF + 12960)
#define MS_OFF  (BWP_OFF + 12960)
#define LS_OFF  (MS_OFF + 512)
__global__ __launch_bounds__(512, 4) void attn_k(
    const float* __restrict__ qb,
    const u16* __restrict__ khi, const u16* __restrict__ klo,
    const u16* __restrict__ vhi, const u16* __restrict__ vlo,
    const float* __restrict__ rph, const float* __restrict__ rpw,
    u16* __restrict__ aoh, u16* __restrict__ aol)
{
  __shared__ __align__(16) char pool[LS_OFF + 512];
  u16* KhiL = (u16*)pool;              // [64 key][72]
  u16* KloL = (u16*)(pool + 9216);
  u16* VhL  = (u16*)(pool + 18432);    // [64 d][72]
  u16* VlL  = (u16*)(pool + 27648);
  u32* BhP = (u32*)(pool + BHP_OFF);   // [49 kh][66] half2 {qs0,qs1}
  u32* BwP = (u32*)(pool + BWP_OFF);   // [48 kw][66] half2 (49 alloc)
  float* m_s = (float*)(pool + MS_OFF);   // [128]
  float* l_s = (float*)(pool + LS_OFF);   // [128]
  float* qlds = (float*)pool;             // prologue alias [128][68] f32 (34816B)
  float* o_s  = (float*)pool;             // epilogue alias [128][68] f32

  const int tid  = threadIdx.x;
  const int lane = tid & 63;
  const int wid  = tid >> 6;
  const int g    = lane >> 4;
  const int ql   = lane & 15;
  const int wqq  = wid & 3;     // q-quad: rows [32*wqq, 32*wqq+32)
  const int hh   = wid >> 2;    // key-half stream
  const int bh   = blockIdx.x;  // 24
  const int qt   = blockIdx.y;  // 18
  const int s0   = qt * 128;

  // ---- stage Q tile fp32 -> LDS (128 rows)
  {
    int row = tid >> 2, c0 = (tid & 3) * 16;
    const float* src = qb + ((size_t)bh * SEQ + s0 + row) * HD + c0;
#pragma unroll
    for (int j = 0; j < 16; j += 4)
      *(f32x4*)&qlds[row * 68 + c0 + j] = *(const f32x4*)(src + j);
  }
  __syncthreads();

  // ---- Q fragments hi/lo: [qsub][ds]; lane's q-rows = wqq*32 + qsub*16 + ql
  s16x8 qfh[2][2], qfl[2][2];
#pragma unroll
  for (int qs = 0; qs < 2; qs++) {
    int qrow = wqq * 32 + qs * 16 + ql;
#pragma unroll
    for (int ds = 0; ds < 2; ds++) {
#pragma unroll
      for (int h2 = 0; h2 < 2; h2++) {
        f32x4 qv = *(const f32x4*)&qlds[qrow * 68 + g * 4 + h2 * 16 + ds * 32];
#pragma unroll
        for (int j = 0; j < 4; j++) {
          u16 hi, lo;
          split2(qv[j], hi, lo);
          qfh[qs][ds][h2 * 4 + j] = (short)hi;
          qfl[qs][ds][h2 * 4 + j] = (short)lo;
        }
      }
    }
  }

  // ---- prefetch tile 0; chunk-permuted staging (conflict-free writes)
  const size_t tbK = (size_t)bh * 36 * 4096;
  const int srow = tid >> 3;
  const int sch  = ((tid & 7) - (srow & 7)) & 7;
  const size_t soff = (size_t)srow * 64 + sch * 8;
  uint4 rkh = *(const uint4*)(khi + tbK + soff);
  uint4 rkl = *(const uint4*)(klo + tbK + soff);
  uint4 rvh = *(const uint4*)(vhi + tbK + soff);
  uint4 rvl = *(const uint4*)(vlo + tbK + soff);

  // ---- bias tables: half2-packed {qs0,qs1}, rows = kh (49) / kw (48), stride 66
  for (int i = tid; i < 64 * 97; i += 512) {
    int p64 = i / 97, col = i - (i / 97) * 97;
    int q0 = ((p64 >> 4) << 5) + (p64 & 15);
    int sA = s0 + q0, sB = sA + 16;
    const float* rpA;
    const float* rpB;
    u32* dst;
    if (col < 49) {
      int hA = sA / 48, hB = sB / 48;
      int rA = hA - col + 47; rA = rA < 0 ? 0 : rA;
      int rB = hB - col + 47; rB = rB < 0 ? 0 : rB;
      rpA = rph + (size_t)rA * HD;
      rpB = rph + (size_t)rB * HD;
      dst = BhP + col * 66 + p64;
    } else {
      int kw = col - 49;
      int wA = sA - (sA / 48) * 48, wB = sB - (sB / 48) * 48;
      rpA = rpw + (size_t)(wA - kw + 47) * HD;
      rpB = rpw + (size_t)(wB - kw + 47) * HD;
      dst = BwP + kw * 66 + p64;
    }
    const float* qpA = &qlds[q0 * 68];
    const float* qpB = &qlds[(q0 + 16) * 68];
    float s1 = 0.f, s2 = 0.f;
#pragma unroll 4
    for (int d = 0; d < 64; d += 4) {
      f32x4 a = *(const f32x4*)(qpA + d);
      f32x4 b = *(const f32x4*)(qpB + d);
      f32x4 u = *(const f32x4*)(rpA + d);
      f32x4 v = *(const f32x4*)(rpB + d);
      s1 += a[0]*u[0] + a[1]*u[1] + a[2]*u[2] + a[3]*u[3];
      s2 += b[0]*v[0] + b[1]*v[1] + b[2]*v[2] + b[3]*v[3];
    }
    __half2 hv = __floats2half2_rn(s1, s2);
    *dst = *(u32*)&hv;
  }

  float m_r[2] = {-3.0e38f, -3.0e38f};
  float l_r[2] = {0.f, 0.f};
  f32x4 oacc[2][4] = {};
  const int p64 = wqq * 16 + ql;

  for (int kt = 0; kt < 36; kt++) {
    __syncthreads();
    *(uint4*)(KhiL + srow * 72 + sch * 8) = rkh;
    *(uint4*)(KloL + srow * 72 + sch * 8) = rkl;
    *(uint4*)(VhL  + srow * 72 + sch * 8) = rvh;
    *(uint4*)(VlL  + srow * 72 + sch * 8) = rvl;
    __syncthreads();
    if (kt < 35) {
      size_t tb = tbK + (size_t)(kt + 1) * 4096;
      rkh = *(const uint4*)(khi + tb + soff);
      rkl = *(const uint4*)(klo + tb + soff);
      rvh = *(const uint4*)(vhi + tb + soff);
      rvl = *(const uint4*)(vlo + tb + soff);
    }

    // ---- QK^T (swapped): S^T[key][q] for both q-subtiles
    f32x4 sacc[2][2] = {};   // [t2][qsub]
    __builtin_amdgcn_s_setprio(1);
#pragma unroll
    for (int ds = 0; ds < 2; ds++) {
#pragma unroll
      for (int t2 = 0; t2 < 2; t2++) {
        int row = (hh * 2 + t2) * 16 + ql;
        s16x8 af = *(const s16x8*)(KhiL + row * 72 + ds * 32 + g * 8);
        s16x8 al = *(const s16x8*)(KloL + row * 72 + ds * 32 + g * 8);
#pragma unroll
        for (int qs = 0; qs < 2; qs++) {
          sacc[t2][qs] = __builtin_amdgcn_mfma_f32_16x16x32_bf16(af, qfh[qs][ds], sacc[t2][qs], 0, 0, 0);
          sacc[t2][qs] = __builtin_amdgcn_mfma_f32_16x16x32_bf16(af, qfl[qs][ds], sacc[t2][qs], 0, 0, 0);
          sacc[t2][qs] = __builtin_amdgcn_mfma_f32_16x16x32_bf16(al, qfh[qs][ds], sacc[t2][qs], 0, 0, 0);
        }
      }
    }
    __builtin_amdgcn_s_setprio(0);

    // ---- bias gather: kh in {kh0,kh0+1} within a tile; packed {qs0,qs1} reads
    u32 kg0 = (u32)(kt * 64 + hh * 32);
    u32 kh0 = kg0 / 48u;
    int kwg = (int)(kg0 - kh0 * 48u) + g * 4;
    float2 bh0, bh1;
    {
      u32 u0 = BhP[kh0 * 66 + p64];
      u32 u1 = BhP[(kh0 + 1) * 66 + p64];
      __half2 h0 = *(__half2*)&u0, h1 = *(__half2*)&u1;
      bh0 = make_float2(__low2float(h0), __high2float(h0));
      bh1 = make_float2(__low2float(h1), __high2float(h1));
    }
    float baddx[8], baddy[8];
#pragma unroll
    for (int t2 = 0; t2 < 2; t2++)
#pragma unroll
      for (int r = 0; r < 4; r++) {
        int j = t2 * 4 + r;
        int w = kwg + t2 * 16 + r;
        bool wrap = w >= 48;
        int wi = wrap ? w - 48 : w;
        u32 u = BwP[wi * 66 + p64];
        __half2 hw = *(__half2*)&u;
        float bwx = __low2float(hw), bwy = __high2float(hw);
        baddx[j] = (wrap ? bh1.x : bh0.x) + bwx;
        baddy[j] = (wrap ? bh1.y : bh0.y) + bwy;
      }

    // ---- online softmax per q-subtile
    s16x8 pfh[2], pfl[2];
#pragma unroll
    for (int qs = 0; qs < 2; qs++) {
      float lg[8];
      float tmax = -3.0e38f;
#pragma unroll
      for (int t2 = 0; t2 < 2; t2++)
#pragma unroll
        for (int r = 0; r < 4; r++) {
          int j = t2 * 4 + r;
          float x = sacc[t2][qs][r] * 0.125f + (qs ? baddy[j] : baddx[j]);
          lg[j] = x;
          tmax = fmaxf(tmax, x);
        }
      tmax = fmaxf(tmax, __shfl_xor(tmax, 16));
      tmax = fmaxf(tmax, __shfl_xor(tmax, 32));
      if (__any(tmax > m_r[qs] + 6.0f)) {   // T13 defer-max
        float mnew = fmaxf(m_r[qs], tmax);
        float corr = __expf(m_r[qs] - mnew);
        l_r[qs] *= corr;
        m_r[qs] = mnew;
        float cq[4];
#pragma unroll
        for (int r = 0; r < 4; r++) cq[r] = __shfl(corr, g * 4 + r);
#pragma unroll
        for (int dt = 0; dt < 4; dt++)
#pragma unroll
          for (int r = 0; r < 4; r++) oacc[qs][dt][r] *= cq[r];
      }
      float psum = 0.f;
#pragma unroll
      for (int j = 0; j < 8; j++) {
        float p = __expf(lg[j] - m_r[qs]);
        psum += p;
        u16 hi, lo;
        split2(p, hi, lo);
        pfh[qs][j] = (short)hi;
        pfl[qs][j] = (short)lo;
      }
      psum += __shfl_xor(psum, 16);
      psum += __shfl_xor(psum, 32);
      l_r[qs] += psum;
    }

    // ---- PV: each V-frag read feeds both q-subtiles
    __builtin_amdgcn_s_setprio(1);
#pragma unroll
    for (int dt = 0; dt < 4; dt++) {
      int row = ql + 16 * dt;
      s16x8 bhf = *(const s16x8*)(VhL + row * 72 + hh * 32 + g * 8);
      s16x8 blf = *(const s16x8*)(VlL + row * 72 + hh * 32 + g * 8);
#pragma unroll
      for (int qs = 0; qs < 2; qs++) {
        oacc[qs][dt] = __builtin_amdgcn_mfma_f32_16x16x32_bf16(pfh[qs], bhf, oacc[qs][dt], 0, 0, 0);
        oacc[qs][dt] = __builtin_amdgcn_mfma_f32_16x16x32_bf16(pfh[qs], blf, oacc[qs][dt], 0, 0, 0);
        oacc[qs][dt] = __builtin_amdgcn_mfma_f32_16x16x32_bf16(pfl[qs], bhf, oacc[qs][dt], 0, 0, 0);
      }
    }
    __builtin_amdgcn_s_setprio(0);
  }

  // ---- merge the two key-streams per q-row, write out (bf16 hi/lo for proj)
  __syncthreads();
  if (hh == 1) {
#pragma unroll
    for (int qs = 0; qs < 2; qs++) {
      if (g == 0) {
        m_s[wqq * 32 + qs * 16 + ql] = m_r[qs];
        l_s[wqq * 32 + qs * 16 + ql] = l_r[qs];
      }
#pragma unroll
      for (int dt = 0; dt < 4; dt++)
#pragma unroll
        for (int r = 0; r < 4; r++)
          o_s[(wqq * 32 + qs * 16 + g * 4 + r) * 68 + ql + 16 * dt] = oacc[qs][dt][r];
    }
  }
  __syncthreads();
  if (hh == 0) {
    const int b = bh / 12, head = bh - (bh / 12) * 12;
#pragma unroll
    for (int qs = 0; qs < 2; qs++) {
      const int q128 = wqq * 32 + qs * 16 + ql;
      float m2 = m_s[q128];
      float l2 = l_s[q128];
      float mf = fmaxf(m_r[qs], m2);
      float c1 = __expf(m_r[qs] - mf);
      float c2 = __expf(m2 - mf);
      float lf = l_r[qs] * c1 + l2 * c2;
      float c1q[4], c2q[4], lfq[4];
#pragma unroll
      for (int r = 0; r < 4; r++) {
        c1q[r] = __shfl(c1, g * 4 + r);
        c2q[r] = __shfl(c2, g * 4 + r);
        lfq[r] = __shfl(lf, g * 4 + r);
      }
#pragma unroll
      for (int dt = 0; dt < 4; dt++)
#pragma unroll
        for (int r = 0; r < 4; r++) {
          float oo = oacc[qs][dt][r] * c1q[r]
                   + o_s[(wqq * 32 + qs * 16 + g * 4 + r) * 68 + ql + 16 * dt] * c2q[r];
          float on = oo / lfq[r];
          int s = s0 + wqq * 32 + qs * 16 + g * 4 + r;
          size_t idx = ((size_t)b * SEQ + s) * 768 + head * 64 + ql + 16 * dt;
          u16 h, l;
          split2(on, h, l);
          aoh[idx] = h;
          aol[idx] = l;
        }
    }
  }
}

// ---------------- proj GEMM via split-bf16 MFMA (A pre-split by attn): -> out
__global__ __launch_bounds__(256) void proj_mfma_k(
    const u16* __restrict__ ahi, const u16* __restrict__ alo,
    const u16* __restrict__ bthi, const u16* __restrict__ btlo,
    const float* __restrict__ bias, float* __restrict__ out)
{
  __shared__ __align__(16) u16 Ah[128*40], Al[128*40], Bh2[128*40], Bl2[128*40];
  const int tid = threadIdx.x;
  const int lane = tid & 63, wid = tid >> 6;
  const int g = lane >> 4, ql = lane & 15;
  const int wr = wid >> 1, wc = wid & 1;
  const int c0 = blockIdx.x * 128, r0 = blockIdx.y * 128;
  const int srow = tid >> 1, half = tid & 1;

  const u16* agh = ahi + (size_t)(r0 + srow) * 768 + half * 16;
  const u16* agl = alo + (size_t)(r0 + srow) * 768 + half * 16;
  const u16* bgh = bthi + (size_t)(c0 + srow) * 768 + half * 16;
  const u16* bgl = btlo + (size_t)(c0 + srow) * 768 + half * 16;

  uint4 pah[2], pal[2], pbh[2], pbl[2];
  pah[0] = *(const uint4*)agh; pah[1] = *(const uint4*)(agh + 8);
  pal[0] = *(const uint4*)agl; pal[1] = *(const uint4*)(agl + 8);
  pbh[0] = *(const uint4*)bgh; pbh[1] = *(const uint4*)(bgh + 8);
  pbl[0] = *(const uint4*)bgl; pbl[1] = *(const uint4*)(bgl + 8);

  f32x4 acc[4][4] = {};

  for (int ks = 0; ks < 24; ks++) {
    __syncthreads();
    {
      u16* d1 = Ah + srow * 40 + half * 16;
      u16* d2 = Al + srow * 40 + half * 16;
      u16* d3 = Bh2 + srow * 40 + half * 16;
      u16* d4 = Bl2 + srow * 40 + half * 16;
      *(uint4*)d1 = pah[0]; *(uint4*)(d1 + 8) = pah[1];
      *(uint4*)d2 = pal[0]; *(uint4*)(d2 + 8) = pal[1];
      *(uint4*)d3 = pbh[0]; *(uint4*)(d3 + 8) = pbh[1];
      *(uint4*)d4 = pbl[0]; *(uint4*)(d4 + 8) = pbl[1];
    }
    __syncthreads();
    if (ks < 23) {
      const int o = (ks + 1) * 32;
      pah[0] = *(const uint4*)(agh + o); pah[1] = *(const uint4*)(agh + o + 8);
      pal[0] = *(const uint4*)(agl + o); pal[1] = *(const uint4*)(agl + o + 8);
      pbh[0] = *(const uint4*)(bgh + o); pbh[1] = *(const uint4*)(bgh + o + 8);
      pbl[0] = *(const uint4*)(bgl + o); pbl[1] = *(const uint4*)(bgl + o + 8);
    }
    s16x8 bfh[4], bfl[4];
#pragma unroll
    for (int nt = 0; nt < 4; nt++) {
      bfh[nt] = *(const s16x8*)(Bh2 + (wc * 64 + nt * 16 + ql) * 40 + g * 8);
      bfl[nt] = *(const s16x8*)(Bl2 + (wc * 64 + nt * 16 + ql) * 40 + g * 8);
    }
#pragma unroll
    for (int mt = 0; mt < 4; mt++) {
      s16x8 ah = *(const s16x8*)(Ah + (wr * 64 + mt * 16 + ql) * 40 + g * 8);
      s16x8 al = *(const s16x8*)(Al + (wr * 64 + mt * 16 + ql) * 40 + g * 8);
#pragma unroll
      for (int nt = 0; nt < 4; nt++) {
        acc[mt][nt] = __builtin_amdgcn_mfma_f32_16x16x32_bf16(ah, bfh[nt], acc[mt][nt], 0, 0, 0);
        acc[mt][nt] = __builtin_amdgcn_mfma_f32_16x16x32_bf16(ah, bfl[nt], acc[mt][nt], 0, 0, 0);
        acc[mt][nt] = __builtin_amdgcn_mfma_f32_16x16x32_bf16(al, bfh[nt], acc[mt][nt], 0, 0, 0);
      }
    }
  }
  const int col0 = c0 + wc * 64;
  const int row0 = r0 + wr * 64;
  float bb[4];
#pragma unroll
  for (int nt = 0; nt < 4; nt++) bb[nt] = bias[col0 + nt * 16 + ql];
#pragma unroll
  for (int mt = 0; mt < 4; mt++)
#pragma unroll
    for (int nt = 0; nt < 4; nt++)
#pragma unroll
      for (int r = 0; r < 4; r++)
        out[(size_t)(row0 + mt * 16 + g * 4 + r) * 768 + col0 + nt * 16 + ql] =
            acc[mt][nt][r] + bb[nt];
}

extern "C" void kernel_launch(void* const* d_in, const int* in_sizes, int n_in,
                              void* d_out, int out_size, void* d_ws, size_t ws_size,
                              hipStream_t stream) {
  const float* x      = (const float*)d_in[0];
  const float* qkv_w  = (const float*)d_in[1];
  const float* qkv_b  = (const float*)d_in[2];
  const float* proj_w = (const float*)d_in[3];
  const float* proj_b = (const float*)d_in[4];
  const float* rph    = (const float*)d_in[5];
  const float* rpw    = (const float*)d_in[6];
  float* out = (float*)d_out;
  float* ws  = (float*)d_ws;

  const size_t SZ = (size_t)24 * SEQ * HD;   // 3,538,944 elems (== 4608*768)
  float* qbuf = ws;                          // SZ f32
  u16* khi = (u16*)(ws + SZ);                // 4 x SZ u16
  u16* klo = khi + SZ;
  u16* vhi = klo + SZ;
  u16* vlo = vhi + SZ;
  u16* xhi = (u16*)(ws + 3 * SZ);            // 2 x SZ u16
  u16* xlo = xhi + SZ;
  u16* aoh = (u16*)(ws + 4 * SZ);            // 2 x SZ u16
  u16* aol = aoh + SZ;
  u16* wqThi = (u16*)(ws + 5 * SZ);          // 768*2304 x2
  u16* wqTlo = wqThi + 768 * 2304;
  u16* wpThi = wqTlo + 768 * 2304;           // 768*768 x2
  u16* wpTlo = wpThi + 768 * 768;

  conv_split_k<<<1728, 256, 0, stream>>>(x, xhi, xlo);
  conv_wT_k <<<dim3(36, 12), 256, 0, stream>>>(qkv_w, wqThi, wqTlo, 768, 2304);
  conv_wT_k <<<dim3(12, 12), 256, 0, stream>>>(proj_w, wpThi, wpTlo, 768, 768);
  qkv_mfma_k<<<dim3(18, 36), 256, 0, stream>>>(xhi, xlo, wqThi, wqTlo, qkv_b,
                                               qbuf, khi, klo, vhi, vlo);
  attn_k    <<<dim3(24, 18), 512, 0, stream>>>(qbuf, khi, klo, vhi, vlo, rph, rpw, aoh, aol);
  proj_mfma_k<<<dim3(6, 36), 256, 0, stream>>>(aoh, aol, wpThi, wpTlo, proj_b, out);
}

// Round 8
// 587.760 us; speedup vs baseline: 1.1488x; 1.1488x over previous
//
#include <hip/hip_runtime.h>
#include <hip/hip_fp16.h>

#define HD 64
#define SEQ 2304

typedef unsigned short u16;
typedef unsigned int u32;
using f32x4 = __attribute__((ext_vector_type(4))) float;
using s16x8 = __attribute__((ext_vector_type(8))) short;

static __device__ __forceinline__ float bf2f(u16 h) {
  union { float f; u32 u; } a; a.u = ((u32)h) << 16; return a.f;
}
// truncation split: x ~= hi + lo, |err| ~ 2^-16 |x|
static __device__ __forceinline__ void split2(float x, u16& h, u16& l) {
  u32 u = __float_as_uint(x);
  h = (u16)(u >> 16);
  float r = x - __uint_as_float(u & 0xffff0000u);
  l = (u16)(__float_as_uint(r) >> 16);
}

// ---------------- split fp32 -> bf16 hi/lo, 8 elems/thread
__global__ __launch_bounds__(256) void conv_split_k(
    const float* __restrict__ src, u16* __restrict__ dhi, u16* __restrict__ dlo)
{
  const size_t i = ((size_t)blockIdx.x * 256 + threadIdx.x) * 8;
  f32x4 a = *(const f32x4*)(src + i);
  f32x4 b = *(const f32x4*)(src + i + 4);
  u16 h[8], l[8];
#pragma unroll
  for (int j = 0; j < 8; j++) {
    float x = j < 4 ? a[j] : b[j - 4];
    split2(x, h[j], l[j]);
  }
  *(uint4*)(dhi + i) = *(uint4*)&h[0];
  *(uint4*)(dlo + i) = *(uint4*)&l[0];
}

// ---------------- convert + transpose weights: w[K][N] f32 -> wT[N][K] bf16 hi/lo
__global__ __launch_bounds__(256) void conv_wT_k(
    const float* __restrict__ src, u16* __restrict__ dhi, u16* __restrict__ dlo,
    int K, int N)
{
  __shared__ u32 t[64][65];
  const int tid = threadIdx.x;
  const int n0 = blockIdx.x * 64, k0 = blockIdx.y * 64;
  const int r = tid >> 2, c0 = (tid & 3) * 16;
  const float* sp = src + (size_t)(k0 + r) * N + n0 + c0;
#pragma unroll
  for (int j = 0; j < 16; j += 4) {
    f32x4 v = *(const f32x4*)(sp + j);
#pragma unroll
    for (int e = 0; e < 4; e++) {
      u16 h, l;
      split2(v[e], h, l);
      t[r][c0 + j + e] = (u32)h | ((u32)l << 16);
    }
  }
  __syncthreads();
  u16 hb[16], lb[16];
#pragma unroll
  for (int j = 0; j < 16; j++) {
    u32 p = t[c0 + j][r];
    hb[j] = (u16)(p & 0xffffu);
    lb[j] = (u16)(p >> 16);
  }
  size_t off = (size_t)(n0 + r) * K + k0 + c0;
  *(uint4*)(dhi + off)     = *(uint4*)&hb[0];
  *(uint4*)(dhi + off + 8) = *(uint4*)&hb[8];
  *(uint4*)(dlo + off)     = *(uint4*)&lb[0];
  *(uint4*)(dlo + off + 8) = *(uint4*)&lb[8];
}

// ---------------- QKV GEMM via split-bf16 MFMA (A pre-split): -> q fp32 + K/V images
__global__ __launch_bounds__(256) void qkv_mfma_k(
    const u16* __restrict__ xhi, const u16* __restrict__ xlo,
    const u16* __restrict__ bthi, const u16* __restrict__ btlo,
    const float* __restrict__ bias,
    float* __restrict__ qbuf, u16* __restrict__ khi, u16* __restrict__ klo,
    u16* __restrict__ vhi, u16* __restrict__ vlo)
{
  __shared__ __align__(16) u16 Ah[128*40], Al[128*40], Bh2[128*40], Bl2[128*40];
  const int tid = threadIdx.x;
  const int lane = tid & 63, wid = tid >> 6;
  const int g = lane >> 4, ql = lane & 15;
  const int wr = wid >> 1, wc = wid & 1;
  const int c0 = blockIdx.x * 128, r0 = blockIdx.y * 128;
  const int srow = tid >> 1, half = tid & 1;

  const u16* agh = xhi + (size_t)(r0 + srow) * 768 + half * 16;
  const u16* agl = xlo + (size_t)(r0 + srow) * 768 + half * 16;
  const u16* bgh = bthi + (size_t)(c0 + srow) * 768 + half * 16;
  const u16* bgl = btlo + (size_t)(c0 + srow) * 768 + half * 16;

  uint4 pah[2], pal[2], pbh[2], pbl[2];
  pah[0] = *(const uint4*)agh; pah[1] = *(const uint4*)(agh + 8);
  pal[0] = *(const uint4*)agl; pal[1] = *(const uint4*)(agl + 8);
  pbh[0] = *(const uint4*)bgh; pbh[1] = *(const uint4*)(bgh + 8);
  pbl[0] = *(const uint4*)bgl; pbl[1] = *(const uint4*)(bgl + 8);

  f32x4 acc[4][4] = {};

  for (int ks = 0; ks < 24; ks++) {
    __syncthreads();
    {
      u16* d1 = Ah + srow * 40 + half * 16;
      u16* d2 = Al + srow * 40 + half * 16;
      u16* d3 = Bh2 + srow * 40 + half * 16;
      u16* d4 = Bl2 + srow * 40 + half * 16;
      *(uint4*)d1 = pah[0]; *(uint4*)(d1 + 8) = pah[1];
      *(uint4*)d2 = pal[0]; *(uint4*)(d2 + 8) = pal[1];
      *(uint4*)d3 = pbh[0]; *(uint4*)(d3 + 8) = pbh[1];
      *(uint4*)d4 = pbl[0]; *(uint4*)(d4 + 8) = pbl[1];
    }
    __syncthreads();
    if (ks < 23) {
      const int o = (ks + 1) * 32;
      pah[0] = *(const uint4*)(agh + o); pah[1] = *(const uint4*)(agh + o + 8);
      pal[0] = *(const uint4*)(agl + o); pal[1] = *(const uint4*)(agl + o + 8);
      pbh[0] = *(const uint4*)(bgh + o); pbh[1] = *(const uint4*)(bgh + o + 8);
      pbl[0] = *(const uint4*)(bgl + o); pbl[1] = *(const uint4*)(bgl + o + 8);
    }
    s16x8 bfh[4], bfl[4];
#pragma unroll
    for (int nt = 0; nt < 4; nt++) {
      bfh[nt] = *(const s16x8*)(Bh2 + (wc * 64 + nt * 16 + ql) * 40 + g * 8);
      bfl[nt] = *(const s16x8*)(Bl2 + (wc * 64 + nt * 16 + ql) * 40 + g * 8);
    }
#pragma unroll
    for (int mt = 0; mt < 4; mt++) {
      s16x8 ah = *(const s16x8*)(Ah + (wr * 64 + mt * 16 + ql) * 40 + g * 8);
      s16x8 al = *(const s16x8*)(Al + (wr * 64 + mt * 16 + ql) * 40 + g * 8);
#pragma unroll
      for (int nt = 0; nt < 4; nt++) {
        acc[mt][nt] = __builtin_amdgcn_mfma_f32_16x16x32_bf16(ah, bfh[nt], acc[mt][nt], 0, 0, 0);
        acc[mt][nt] = __builtin_amdgcn_mfma_f32_16x16x32_bf16(ah, bfl[nt], acc[mt][nt], 0, 0, 0);
        acc[mt][nt] = __builtin_amdgcn_mfma_f32_16x16x32_bf16(al, bfh[nt], acc[mt][nt], 0, 0, 0);
      }
    }
  }
  // ---- epilogue: scatter to q fp32 / K,V permuted tile-images
  const int col0 = c0 + wc * 64;
  const int row0 = r0 + wr * 64;
  const int hb36 = col0 >> 6;
  const int which = hb36 / 12, head = hb36 - (hb36 / 12) * 12;
  const int b = row0 / 2304;
  const int sb = row0 - b * 2304;
  const int bh = b * 12 + head;
  float bb[4];
#pragma unroll
  for (int nt = 0; nt < 4; nt++) bb[nt] = bias[col0 + nt * 16 + ql];
  if (which == 0) {
#pragma unroll
    for (int mt = 0; mt < 4; mt++)
#pragma unroll
      for (int nt = 0; nt < 4; nt++)
#pragma unroll
        for (int r = 0; r < 4; r++) {
          int s = sb + mt * 16 + g * 4 + r;
          qbuf[((size_t)bh * SEQ + s) * 64 + nt * 16 + ql] = acc[mt][nt][r] + bb[nt];
        }
  } else {
    const int kt = sb >> 6;
    const size_t tile = ((size_t)bh * 36 + kt) * 4096;
    if (which == 1) {
#pragma unroll
      for (int mt = 0; mt < 4; mt++)
#pragma unroll
        for (int nt = 0; nt < 4; nt++) {
          int pc = (nt >> 1) * 32 + (ql >> 2) * 8 + (nt & 1) * 4 + (ql & 3);
#pragma unroll
          for (int r = 0; r < 4; r++) {
            int key = mt * 16 + g * 4 + r;
            u16 h, l;
            split2(acc[mt][nt][r] + bb[nt], h, l);
            khi[tile + key * 64 + pc] = h;
            klo[tile + key * 64 + pc] = l;
          }
        }
    } else {
#pragma unroll
      for (int mt = 0; mt < 4; mt++)
#pragma unroll
        for (int nt = 0; nt < 4; nt++)
#pragma unroll
          for (int r = 0; r < 4; r++) {
            int d = nt * 16 + ql;
            int vc = (mt >> 1) * 32 + g * 8 + (mt & 1) * 4 + r;
            u16 h, l;
            split2(acc[mt][nt][r] + bb[nt], h, l);
            vhi[tile + d * 64 + vc] = h;
            vlo[tile + d * 64 + vc] = l;
          }
    }
  }
}

// ---------------- Fused attention (r4 geometry): 64 q-rows/block, 864 blocks,
// LDS-staged K/V, split-bf16 MFMA, swapped QK^T, online softmax.
// grid(bh=24, qt=36): 24%8==0 -> XCD = bh%8 for all qt (K/V image L2-pinned).
#define BH_OFF 36864                      // Bh: 49 x 66 u16 (row 48 = wrap slack)
#define BW_OFF (BH_OFF + 49*66*2)         // 43332
#define MS_OFF (BW_OFF + 48*66*2)         // 49668
#define LS_OFF (MS_OFF + 256)             // 49924
__global__ __launch_bounds__(512) void attn_k(
    const float* __restrict__ qb,
    const u16* __restrict__ khi, const u16* __restrict__ klo,
    const u16* __restrict__ vhi, const u16* __restrict__ vlo,
    const float* __restrict__ rph, const float* __restrict__ rpw,
    u32* __restrict__ aop)
{
  __shared__ __align__(16) char pool[LS_OFF + 256];
  u16* KhiL = (u16*)pool;              // [64 key][72]
  u16* KloL = (u16*)(pool + 9216);
  u16* VhL  = (u16*)(pool + 18432);    // [64 d][72]
  u16* VlL  = (u16*)(pool + 27648);
  __half* Bh = (__half*)(pool + BH_OFF);  // [49 kh][66 pad]
  __half* Bw = (__half*)(pool + BW_OFF);  // [48 kw][66 pad]
  float* m_s = (float*)(pool + MS_OFF);   // [64]
  float* l_s = (float*)(pool + LS_OFF);   // [64]
  float* qlds = (float*)pool;             // prologue alias [64][68] f32
  float* o_s  = (float*)pool;             // epilogue alias [64][68] f32

  const int tid  = threadIdx.x;
  const int lane = tid & 63;
  const int wid  = tid >> 6;
  const int g    = lane >> 4;
  const int ql   = lane & 15;
  const int wq   = wid & 3;     // q-group: rows [16*wq, 16*wq+16)
  const int hh   = wid >> 2;    // key-half stream
  const int bh   = blockIdx.x;  // 24
  const int qt   = blockIdx.y;  // 36
  const int s0   = qt * 64;

  // ---- stage Q tile fp32 -> LDS
  {
    int row = tid >> 3, c0 = (tid & 7) * 8;
    const float* src = qb + ((size_t)bh * SEQ + s0 + row) * HD + c0;
    f32x4 v0 = *(const f32x4*)src;
    f32x4 v1 = *(const f32x4*)(src + 4);
    *(f32x4*)&qlds[row * 68 + c0]     = v0;
    *(f32x4*)&qlds[row * 68 + c0 + 4] = v1;
  }
  __syncthreads();

  // ---- Q fragments hi/lo (lane's q = 16*wq + ql)
  s16x8 qfh[2], qfl[2];
  {
    int qrow = wq * 16 + ql;
#pragma unroll
    for (int ds = 0; ds < 2; ds++) {
#pragma unroll
      for (int h2 = 0; h2 < 2; h2++) {
        f32x4 qv = *(const f32x4*)&qlds[qrow * 68 + g * 4 + h2 * 16 + ds * 32];
#pragma unroll
        for (int j = 0; j < 4; j++) {
          u16 hi, lo;
          split2(qv[j], hi, lo);
          qfh[ds][h2 * 4 + j] = (short)hi;
          qfl[ds][h2 * 4 + j] = (short)lo;
        }
      }
    }
  }

  // ---- prefetch tile 0; chunk-permuted staging (conflict-free writes)
  const size_t tbK = (size_t)bh * 36 * 4096;
  const int srow = tid >> 3;
  const int sch  = ((tid & 7) - (srow & 7)) & 7;
  const size_t soff = (size_t)srow * 64 + sch * 8;
  uint4 rkh = *(const uint4*)(khi + tbK + soff);
  uint4 rkl = *(const uint4*)(klo + tbK + soff);
  uint4 rvh = *(const uint4*)(vhi + tbK + soff);
  uint4 rvl = *(const uint4*)(vlo + tbK + soff);

  // ---- decomposed rel-pos bias tables (fp16, stride 66: conflict-free reads)
  for (int i = tid; i < 64 * 96; i += 512) {
    int q = i / 96, j = i - (i / 96) * 96;
    int s = s0 + q;
    int qhg = s / 48, qw = s - qhg * 48;
    const float* tab;
    int ridx, col;
    if (j < 48) { col = j;      ridx = qhg - j + 47;        tab = rph; }
    else        { col = j - 48; ridx = qw - (j - 48) + 47;  tab = rpw; }
    const float* rp = tab + (size_t)ridx * HD;
    const float* qp = &qlds[q * 68];
    float s1 = 0.f;
#pragma unroll 4
    for (int d = 0; d < 64; d += 4) {
      f32x4 a = *(const f32x4*)(qp + d);
      f32x4 bv = *(const f32x4*)(rp + d);
      s1 += a[0]*bv[0] + a[1]*bv[1] + a[2]*bv[2] + a[3]*bv[3];
    }
    if (j < 48) Bh[col * 66 + q] = __float2half_rn(s1);
    else        Bw[col * 66 + q] = __float2half_rn(s1);
  }

  float m_r = -3.0e38f, l_r = 0.f;
  f32x4 oacc[4] = {};   // O[q = 4g+r][d = ql + 16*dt]
  const int q64b = wq * 16 + ql;

  for (int kt = 0; kt < 36; kt++) {
    __syncthreads();   // prev tile's frag reads done (first iter: bias/qlds done)
    *(uint4*)(KhiL + srow * 72 + sch * 8) = rkh;
    *(uint4*)(KloL + srow * 72 + sch * 8) = rkl;
    *(uint4*)(VhL  + srow * 72 + sch * 8) = rvh;
    *(uint4*)(VlL  + srow * 72 + sch * 8) = rvl;
    __syncthreads();
    if (kt < 35) {     // T14: issue next-tile loads; land under MFMA phase
      size_t tb = tbK + (size_t)(kt + 1) * 4096;
      rkh = *(const uint4*)(khi + tb + soff);
      rkl = *(const uint4*)(klo + tb + soff);
      rvh = *(const uint4*)(vhi + tb + soff);
      rvl = *(const uint4*)(vlo + tb + soff);
    }

    // ---- QK^T (swapped): S^T[key][q]; A-frag = one b128 (permuted image)
    f32x4 sacc[2] = {};
    __builtin_amdgcn_s_setprio(1);
#pragma unroll
    for (int ds = 0; ds < 2; ds++) {
#pragma unroll
      for (int t2 = 0; t2 < 2; t2++) {
        int row = (hh * 2 + t2) * 16 + ql;
        s16x8 af = *(const s16x8*)(KhiL + row * 72 + ds * 32 + g * 8);
        s16x8 al = *(const s16x8*)(KloL + row * 72 + ds * 32 + g * 8);
        sacc[t2] = __builtin_amdgcn_mfma_f32_16x16x32_bf16(af, qfh[ds], sacc[t2], 0, 0, 0);
        sacc[t2] = __builtin_amdgcn_mfma_f32_16x16x32_bf16(af, qfl[ds], sacc[t2], 0, 0, 0);
        sacc[t2] = __builtin_amdgcn_mfma_f32_16x16x32_bf16(al, qfh[ds], sacc[t2], 0, 0, 0);
      }
    }
    __builtin_amdgcn_s_setprio(0);

    // ---- bias gather: kh in {kh0,kh0+1} within a half-tile; 2+8 LDS reads
    u32 kg0 = (u32)(kt * 64 + hh * 32);
    u32 kh0 = kg0 / 48u;
    int kw0 = (int)(kg0 - kh0 * 48u);
    float bh0 = __half2float(Bh[kh0 * 66 + q64b]);
    float bh1 = __half2float(Bh[(kh0 + 1) * 66 + q64b]);
    float lg[8];
    float tmax = -3.0e38f;
#pragma unroll
    for (int t2 = 0; t2 < 2; t2++)
#pragma unroll
      for (int r = 0; r < 4; r++) {
        int j = t2 * 4 + r;
        int w = kw0 + t2 * 16 + g * 4 + r;
        bool wrap = w >= 48;
        float bw = __half2float(Bw[(wrap ? w - 48 : w) * 66 + q64b]);
        float x = sacc[t2][r] * 0.125f + (wrap ? bh1 : bh0) + bw;
        lg[j] = x;
        tmax = fmaxf(tmax, x);
      }
    tmax = fmaxf(tmax, __shfl_xor(tmax, 16));
    tmax = fmaxf(tmax, __shfl_xor(tmax, 32));
    if (__any(tmax > m_r + 6.0f)) {   // T13 defer-max
      float mnew = fmaxf(m_r, tmax);
      float corr = __expf(m_r - mnew);
      l_r *= corr;
      m_r = mnew;
      float cq[4];
#pragma unroll
      for (int r = 0; r < 4; r++) cq[r] = __shfl(corr, g * 4 + r);
#pragma unroll
      for (int dt = 0; dt < 4; dt++)
#pragma unroll
        for (int r = 0; r < 4; r++) oacc[dt][r] *= cq[r];
    }
    float psum = 0.f;
    s16x8 pfh, pfl;
#pragma unroll
    for (int j = 0; j < 8; j++) {
      float p = __expf(lg[j] - m_r);
      psum += p;
      u16 hi, lo;
      split2(p, hi, lo);
      pfh[j] = (short)hi;
      pfl[j] = (short)lo;
    }
    psum += __shfl_xor(psum, 16);
    psum += __shfl_xor(psum, 32);
    l_r += psum;

    // ---- PV: B-frag = one b128 from permuted V^T image
    __builtin_amdgcn_s_setprio(1);
#pragma unroll
    for (int dt = 0; dt < 4; dt++) {
      int row = ql + 16 * dt;
      s16x8 bhf = *(const s16x8*)(VhL + row * 72 + hh * 32 + g * 8);
      s16x8 blf = *(const s16x8*)(VlL + row * 72 + hh * 32 + g * 8);
      oacc[dt] = __builtin_amdgcn_mfma_f32_16x16x32_bf16(pfh, bhf, oacc[dt], 0, 0, 0);
      oacc[dt] = __builtin_amdgcn_mfma_f32_16x16x32_bf16(pfh, blf, oacc[dt], 0, 0, 0);
      oacc[dt] = __builtin_amdgcn_mfma_f32_16x16x32_bf16(pfl, bhf, oacc[dt], 0, 0, 0);
    }
    __builtin_amdgcn_s_setprio(0);
  }

  // ---- merge the two key-streams per q-group, write out (packed u32 hi|lo)
  __syncthreads();
  if (hh == 1) {
    if (g == 0) { m_s[q64b] = m_r; l_s[q64b] = l_r; }
#pragma unroll
    for (int dt = 0; dt < 4; dt++)
#pragma unroll
      for (int r = 0; r < 4; r++)
        o_s[(wq * 16 + g * 4 + r) * 68 + ql + 16 * dt] = oacc[dt][r];
  }
  __syncthreads();
  if (hh == 0) {
    float m2 = m_s[q64b];
    float l2 = l_s[q64b];
    float mf = fmaxf(m_r, m2);
    float c1 = __expf(m_r - mf);
    float c2 = __expf(m2 - mf);
    float lf = l_r * c1 + l2 * c2;
    float c1q[4], c2q[4], lfq[4];
#pragma unroll
    for (int r = 0; r < 4; r++) {
      c1q[r] = __shfl(c1, g * 4 + r);
      c2q[r] = __shfl(c2, g * 4 + r);
      lfq[r] = __shfl(lf, g * 4 + r);
    }
    const int b = bh / 12, head = bh - (bh / 12) * 12;
#pragma unroll
    for (int dt = 0; dt < 4; dt++)
#pragma unroll
      for (int r = 0; r < 4; r++) {
        float oo = oacc[dt][r] * c1q[r]
                 + o_s[(wq * 16 + g * 4 + r) * 68 + ql + 16 * dt] * c2q[r];
        float on = oo / lfq[r];
        int s = s0 + wq * 16 + g * 4 + r;
        size_t idx = ((size_t)b * SEQ + s) * 768 + head * 64 + ql + 16 * dt;
        u16 h, l;
        split2(on, h, l);
        aop[idx] = (u32)h | ((u32)l << 16);
      }
  }
}

// ---------------- proj GEMM via split-bf16 MFMA (A = packed u32 hi|lo): -> out
__global__ __launch_bounds__(256) void proj_mfma_k(
    const u32* __restrict__ aop,
    const u16* __restrict__ bthi, const u16* __restrict__ btlo,
    const float* __restrict__ bias, float* __restrict__ out)
{
  __shared__ __align__(16) u16 Ah[128*40], Al[128*40], Bh2[128*40], Bl2[128*40];
  const int tid = threadIdx.x;
  const int lane = tid & 63, wid = tid >> 6;
  const int g = lane >> 4, ql = lane & 15;
  const int wr = wid >> 1, wc = wid & 1;
  const int c0 = blockIdx.x * 128, r0 = blockIdx.y * 128;
  const int srow = tid >> 1, half = tid & 1;

  const u32* ag = aop + (size_t)(r0 + srow) * 768 + half * 16;
  const u16* bgh = bthi + (size_t)(c0 + srow) * 768 + half * 16;
  const u16* bgl = btlo + (size_t)(c0 + srow) * 768 + half * 16;

  uint4 paw[4]; uint4 pbh[2], pbl[2];
#pragma unroll
  for (int j = 0; j < 4; j++) paw[j] = *(const uint4*)(ag + j * 4);
  pbh[0] = *(const uint4*)bgh; pbh[1] = *(const uint4*)(bgh + 8);
  pbl[0] = *(const uint4*)bgl; pbl[1] = *(const uint4*)(bgl + 8);

  f32x4 acc[4][4] = {};

  for (int ks = 0; ks < 24; ks++) {
    __syncthreads();
    {
      u16 hb[16], lb[16];
      const u32* pw = (const u32*)&paw[0];
#pragma unroll
      for (int j = 0; j < 16; j++) {
        hb[j] = (u16)(pw[j] & 0xffffu);
        lb[j] = (u16)(pw[j] >> 16);
      }
      u16* d1 = Ah + srow * 40 + half * 16;
      u16* d2 = Al + srow * 40 + half * 16;
      u16* d3 = Bh2 + srow * 40 + half * 16;
      u16* d4 = Bl2 + srow * 40 + half * 16;
      *(uint4*)d1 = *(uint4*)&hb[0]; *(uint4*)(d1 + 8) = *(uint4*)&hb[8];
      *(uint4*)d2 = *(uint4*)&lb[0]; *(uint4*)(d2 + 8) = *(uint4*)&lb[8];
      *(uint4*)d3 = pbh[0]; *(uint4*)(d3 + 8) = pbh[1];
      *(uint4*)d4 = pbl[0]; *(uint4*)(d4 + 8) = pbl[1];
    }
    __syncthreads();
    if (ks < 23) {
      const int o = (ks + 1) * 32;
#pragma unroll
      for (int j = 0; j < 4; j++) paw[j] = *(const uint4*)(ag + o + j * 4);
      pbh[0] = *(const uint4*)(bgh + o); pbh[1] = *(const uint4*)(bgh + o + 8);
      pbl[0] = *(const uint4*)(bgl + o); pbl[1] = *(const uint4*)(bgl + o + 8);
    }
    s16x8 bfh[4], bfl[4];
#pragma unroll
    for (int nt = 0; nt < 4; nt++) {
      bfh[nt] = *(const s16x8*)(Bh2 + (wc * 64 + nt * 16 + ql) * 40 + g * 8);
      bfl[nt] = *(const s16x8*)(Bl2 + (wc * 64 + nt * 16 + ql) * 40 + g * 8);
    }
#pragma unroll
    for (int mt = 0; mt < 4; mt++) {
      s16x8 ah = *(const s16x8*)(Ah + (wr * 64 + mt * 16 + ql) * 40 + g * 8);
      s16x8 al = *(const s16x8*)(Al + (wr * 64 + mt * 16 + ql) * 40 + g * 8);
#pragma unroll
      for (int nt = 0; nt < 4; nt++) {
        acc[mt][nt] = __builtin_amdgcn_mfma_f32_16x16x32_bf16(ah, bfh[nt], acc[mt][nt], 0, 0, 0);
        acc[mt][nt] = __builtin_amdgcn_mfma_f32_16x16x32_bf16(ah, bfl[nt], acc[mt][nt], 0, 0, 0);
        acc[mt][nt] = __builtin_amdgcn_mfma_f32_16x16x32_bf16(al, bfh[nt], acc[mt][nt], 0, 0, 0);
      }
    }
  }
  const int col0 = c0 + wc * 64;
  const int row0 = r0 + wr * 64;
  float bb[4];
#pragma unroll
  for (int nt = 0; nt < 4; nt++) bb[nt] = bias[col0 + nt * 16 + ql];
#pragma unroll
  for (int mt = 0; mt < 4; mt++)
#pragma unroll
    for (int nt = 0; nt < 4; nt++)
#pragma unroll
      for (int r = 0; r < 4; r++)
        out[(size_t)(row0 + mt * 16 + g * 4 + r) * 768 + col0 + nt * 16 + ql] =
            acc[mt][nt][r] + bb[nt];
}

extern "C" void kernel_launch(void* const* d_in, const int* in_sizes, int n_in,
                              void* d_out, int out_size, void* d_ws, size_t ws_size,
                              hipStream_t stream) {
  const float* x      = (const float*)d_in[0];
  const float* qkv_w  = (const float*)d_in[1];
  const float* qkv_b  = (const float*)d_in[2];
  const float* proj_w = (const float*)d_in[3];
  const float* proj_b = (const float*)d_in[4];
  const float* rph    = (const float*)d_in[5];
  const float* rpw    = (const float*)d_in[6];
  float* out = (float*)d_out;
  float* ws  = (float*)d_ws;

  const size_t SZ = (size_t)24 * SEQ * HD;   // 3,538,944 elems (== 4608*768)
  float* qbuf = ws;                          // SZ f32
  u16* khi = (u16*)(ws + SZ);                // 4 x SZ u16
  u16* klo = khi + SZ;
  u16* vhi = klo + SZ;
  u16* vlo = vhi + SZ;
  u16* xhi = (u16*)(ws + 3 * SZ);            // 2 x SZ u16
  u16* xlo = xhi + SZ;
  u32* aop = (u32*)(ws + 4 * SZ);            // SZ u32 (packed hi|lo)
  u16* wqThi = (u16*)(ws + 5 * SZ);          // 768*2304 x2
  u16* wqTlo = wqThi + 768 * 2304;
  u16* wpThi = wqTlo + 768 * 2304;           // 768*768 x2
  u16* wpTlo = wpThi + 768 * 768;

  conv_split_k<<<1728, 256, 0, stream>>>(x, xhi, xlo);
  conv_wT_k <<<dim3(36, 12), 256, 0, stream>>>(qkv_w, wqThi, wqTlo, 768, 2304);
  conv_wT_k <<<dim3(12, 12), 256, 0, stream>>>(proj_w, wpThi, wpTlo, 768, 768);
  qkv_mfma_k<<<dim3(18, 36), 256, 0, stream>>>(xhi, xlo, wqThi, wqTlo, qkv_b,
                                               qbuf, khi, klo, vhi, vlo);
  attn_k    <<<dim3(24, 36), 512, 0, stream>>>(qbuf, khi, klo, vhi, vlo, rph, rpw, aop);
  proj_mfma_k<<<dim3(6, 36), 256, 0, stream>>>(aop, wpThi, wpTlo, proj_b, out);
}

// Round 9
// 577.060 us; speedup vs baseline: 1.1701x; 1.0185x over previous
//
#include <hip/hip_runtime.h>
#include <hip/hip_fp16.h>

#define HD 64
#define SEQ 2304

typedef unsigned short u16;
typedef unsigned int u32;
using f32x4 = __attribute__((ext_vector_type(4))) float;
using s16x8 = __attribute__((ext_vector_type(8))) short;

static __device__ __forceinline__ float bf2f(u16 h) {
  union { float f; u32 u; } a; a.u = ((u32)h) << 16; return a.f;
}
// truncation split: x ~= hi + lo, |err| ~ 2^-16 |x|
static __device__ __forceinline__ void split2(float x, u16& h, u16& l) {
  u32 u = __float_as_uint(x);
  h = (u16)(u >> 16);
  float r = x - __uint_as_float(u & 0xffff0000u);
  l = (u16)(__float_as_uint(r) >> 16);
}

// ---------------- split fp32 -> bf16 hi/lo, 8 elems/thread
__global__ __launch_bounds__(256) void conv_split_k(
    const float* __restrict__ src, u16* __restrict__ dhi, u16* __restrict__ dlo)
{
  const size_t i = ((size_t)blockIdx.x * 256 + threadIdx.x) * 8;
  f32x4 a = *(const f32x4*)(src + i);
  f32x4 b = *(const f32x4*)(src + i + 4);
  u16 h[8], l[8];
#pragma unroll
  for (int j = 0; j < 8; j++) {
    float x = j < 4 ? a[j] : b[j - 4];
    split2(x, h[j], l[j]);
  }
  *(uint4*)(dhi + i) = *(uint4*)&h[0];
  *(uint4*)(dlo + i) = *(uint4*)&l[0];
}

// ---------------- convert + transpose weights: w[K][N] f32 -> wT[N][K] bf16 hi/lo
__global__ __launch_bounds__(256) void conv_wT_k(
    const float* __restrict__ src, u16* __restrict__ dhi, u16* __restrict__ dlo,
    int K, int N)
{
  __shared__ u32 t[64][65];
  const int tid = threadIdx.x;
  const int n0 = blockIdx.x * 64, k0 = blockIdx.y * 64;
  const int r = tid >> 2, c0 = (tid & 3) * 16;
  const float* sp = src + (size_t)(k0 + r) * N + n0 + c0;
#pragma unroll
  for (int j = 0; j < 16; j += 4) {
    f32x4 v = *(const f32x4*)(sp + j);
#pragma unroll
    for (int e = 0; e < 4; e++) {
      u16 h, l;
      split2(v[e], h, l);
      t[r][c0 + j + e] = (u32)h | ((u32)l << 16);
    }
  }
  __syncthreads();
  u16 hb[16], lb[16];
#pragma unroll
  for (int j = 0; j < 16; j++) {
    u32 p = t[c0 + j][r];
    hb[j] = (u16)(p & 0xffffu);
    lb[j] = (u16)(p >> 16);
  }
  size_t off = (size_t)(n0 + r) * K + k0 + c0;
  *(uint4*)(dhi + off)     = *(uint4*)&hb[0];
  *(uint4*)(dhi + off + 8) = *(uint4*)&hb[8];
  *(uint4*)(dlo + off)     = *(uint4*)&lb[0];
  *(uint4*)(dlo + off + 8) = *(uint4*)&lb[8];
}

// ---------------- QKV GEMM via split-bf16 MFMA (A pre-split): -> q fp32 + K/V images
// Blocks are pure q/K/V (which-boundaries on even head-groups): bx 0-5 q, 6-11 K, 12-17 V.
// K/V image epilogue: LDS-assemble per-wave 64x64 tile, then contiguous 128B/lane stores.
__global__ __launch_bounds__(256) void qkv_mfma_k(
    const u16* __restrict__ xhi, const u16* __restrict__ xlo,
    const u16* __restrict__ bthi, const u16* __restrict__ btlo,
    const float* __restrict__ bias,
    float* __restrict__ qbuf, u16* __restrict__ khi, u16* __restrict__ klo,
    u16* __restrict__ vhi, u16* __restrict__ vlo)
{
  __shared__ __align__(16) char qpool[40960];
  u16* Ah  = (u16*)qpool;              // [128][40]
  u16* Al  = (u16*)(qpool + 10240);
  u16* Bh2 = (u16*)(qpool + 20480);
  u16* Bl2 = (u16*)(qpool + 30720);
  u16* img = (u16*)qpool;              // epilogue alias: [4 waves][4096]

  const int tid = threadIdx.x;
  const int lane = tid & 63, wid = tid >> 6;
  const int g = lane >> 4, ql = lane & 15;
  const int wr = wid >> 1, wc = wid & 1;
  const int c0 = blockIdx.x * 128, r0 = blockIdx.y * 128;
  const int srow = tid >> 1, half = tid & 1;

  const u16* agh = xhi + (size_t)(r0 + srow) * 768 + half * 16;
  const u16* agl = xlo + (size_t)(r0 + srow) * 768 + half * 16;
  const u16* bgh = bthi + (size_t)(c0 + srow) * 768 + half * 16;
  const u16* bgl = btlo + (size_t)(c0 + srow) * 768 + half * 16;

  uint4 pah[2], pal[2], pbh[2], pbl[2];
  pah[0] = *(const uint4*)agh; pah[1] = *(const uint4*)(agh + 8);
  pal[0] = *(const uint4*)agl; pal[1] = *(const uint4*)(agl + 8);
  pbh[0] = *(const uint4*)bgh; pbh[1] = *(const uint4*)(bgh + 8);
  pbl[0] = *(const uint4*)bgl; pbl[1] = *(const uint4*)(bgl + 8);

  f32x4 acc[4][4] = {};

  for (int ks = 0; ks < 24; ks++) {
    __syncthreads();
    {
      u16* d1 = Ah + srow * 40 + half * 16;
      u16* d2 = Al + srow * 40 + half * 16;
      u16* d3 = Bh2 + srow * 40 + half * 16;
      u16* d4 = Bl2 + srow * 40 + half * 16;
      *(uint4*)d1 = pah[0]; *(uint4*)(d1 + 8) = pah[1];
      *(uint4*)d2 = pal[0]; *(uint4*)(d2 + 8) = pal[1];
      *(uint4*)d3 = pbh[0]; *(uint4*)(d3 + 8) = pbh[1];
      *(uint4*)d4 = pbl[0]; *(uint4*)(d4 + 8) = pbl[1];
    }
    __syncthreads();
    if (ks < 23) {
      const int o = (ks + 1) * 32;
      pah[0] = *(const uint4*)(agh + o); pah[1] = *(const uint4*)(agh + o + 8);
      pal[0] = *(const uint4*)(agl + o); pal[1] = *(const uint4*)(agl + o + 8);
      pbh[0] = *(const uint4*)(bgh + o); pbh[1] = *(const uint4*)(bgh + o + 8);
      pbl[0] = *(const uint4*)(bgl + o); pbl[1] = *(const uint4*)(bgl + o + 8);
    }
    s16x8 bfh[4], bfl[4];
#pragma unroll
    for (int nt = 0; nt < 4; nt++) {
      bfh[nt] = *(const s16x8*)(Bh2 + (wc * 64 + nt * 16 + ql) * 40 + g * 8);
      bfl[nt] = *(const s16x8*)(Bl2 + (wc * 64 + nt * 16 + ql) * 40 + g * 8);
    }
#pragma unroll
    for (int mt = 0; mt < 4; mt++) {
      s16x8 ah = *(const s16x8*)(Ah + (wr * 64 + mt * 16 + ql) * 40 + g * 8);
      s16x8 al = *(const s16x8*)(Al + (wr * 64 + mt * 16 + ql) * 40 + g * 8);
#pragma unroll
      for (int nt = 0; nt < 4; nt++) {
        acc[mt][nt] = __builtin_amdgcn_mfma_f32_16x16x32_bf16(ah, bfh[nt], acc[mt][nt], 0, 0, 0);
        acc[mt][nt] = __builtin_amdgcn_mfma_f32_16x16x32_bf16(ah, bfl[nt], acc[mt][nt], 0, 0, 0);
        acc[mt][nt] = __builtin_amdgcn_mfma_f32_16x16x32_bf16(al, bfh[nt], acc[mt][nt], 0, 0, 0);
      }
    }
  }
  // ---- epilogue
  const int col0 = c0 + wc * 64;
  const int row0 = r0 + wr * 64;
  const int hb36 = col0 >> 6;
  const int which = hb36 / 12, head = hb36 - (hb36 / 12) * 12;
  const int b = row0 / 2304;
  const int sb = row0 - b * 2304;
  const int bh = b * 12 + head;
  float bb[4];
#pragma unroll
  for (int nt = 0; nt < 4; nt++) bb[nt] = bias[col0 + nt * 16 + ql];
#pragma unroll
  for (int mt = 0; mt < 4; mt++)
#pragma unroll
    for (int nt = 0; nt < 4; nt++)
#pragma unroll
      for (int r = 0; r < 4; r++)
        acc[mt][nt][r] += bb[nt];

  if (which == 0) {
#pragma unroll
    for (int mt = 0; mt < 4; mt++)
#pragma unroll
      for (int nt = 0; nt < 4; nt++)
#pragma unroll
        for (int r = 0; r < 4; r++) {
          int s = sb + mt * 16 + g * 4 + r;
          qbuf[((size_t)bh * SEQ + s) * 64 + nt * 16 + ql] = acc[mt][nt][r];
        }
  } else {
    const int kt = sb >> 6;
    const size_t tile = ((size_t)bh * 36 + kt) * 4096;
    u16* const dsth = (which == 1) ? khi : vhi;
    u16* const dstl = (which == 1) ? klo : vlo;
    u16* const reg = img + wid * 4096;
    // pass 1: HI image assembled in LDS, then contiguous stores
    __syncthreads();   // main-loop LDS reads complete before alias reuse
#pragma unroll
    for (int mt = 0; mt < 4; mt++)
#pragma unroll
      for (int nt = 0; nt < 4; nt++) {
        int pcK = (nt >> 1) * 32 + (ql >> 2) * 8 + (nt & 1) * 4 + (ql & 3);
#pragma unroll
        for (int r = 0; r < 4; r++) {
          u16 h, l;
          split2(acc[mt][nt][r], h, l);
          int off = (which == 1)
              ? (mt * 16 + g * 4 + r) * 64 + pcK
              : (nt * 16 + ql) * 64 + (mt >> 1) * 32 + g * 8 + (mt & 1) * 4 + r;
          reg[off] = h;
        }
      }
    __syncthreads();
    {
      const u16* src = img + wid * 4096 + lane * 64;
      u16* dst = dsth + tile + lane * 64;
#pragma unroll
      for (int j = 0; j < 8; j++)
        *(uint4*)(dst + j * 8) = *(const uint4*)(src + j * 8);
    }
    // pass 2: LO image
    __syncthreads();
#pragma unroll
    for (int mt = 0; mt < 4; mt++)
#pragma unroll
      for (int nt = 0; nt < 4; nt++) {
        int pcK = (nt >> 1) * 32 + (ql >> 2) * 8 + (nt & 1) * 4 + (ql & 3);
#pragma unroll
        for (int r = 0; r < 4; r++) {
          u16 h, l;
          split2(acc[mt][nt][r], h, l);
          int off = (which == 1)
              ? (mt * 16 + g * 4 + r) * 64 + pcK
              : (nt * 16 + ql) * 64 + (mt >> 1) * 32 + g * 8 + (mt & 1) * 4 + r;
          reg[off] = l;
        }
      }
    __syncthreads();
    {
      const u16* src = img + wid * 4096 + lane * 64;
      u16* dst = dstl + tile + lane * 64;
#pragma unroll
      for (int j = 0; j < 8; j++)
        *(uint4*)(dst + j * 8) = *(const uint4*)(src + j * 8);
    }
  }
}

// ---------------- Fused attention (r8, known-good): 64 q-rows/block, 864 blocks,
// LDS-staged K/V, split-bf16 MFMA, swapped QK^T, online softmax.
// grid(bh=24, qt=36): 24%8==0 -> XCD = bh%8 for all qt (K/V image L2-pinned).
#define BH_OFF 36864                      // Bh: 49 x 66 u16 (row 48 = wrap slack)
#define BW_OFF (BH_OFF + 49*66*2)         // 43332
#define MS_OFF (BW_OFF + 48*66*2)         // 49668
#define LS_OFF (MS_OFF + 256)             // 49924
__global__ __launch_bounds__(512) void attn_k(
    const float* __restrict__ qb,
    const u16* __restrict__ khi, const u16* __restrict__ klo,
    const u16* __restrict__ vhi, const u16* __restrict__ vlo,
    const float* __restrict__ rph, const float* __restrict__ rpw,
    u32* __restrict__ aop)
{
  __shared__ __align__(16) char pool[LS_OFF + 256];
  u16* KhiL = (u16*)pool;              // [64 key][72]
  u16* KloL = (u16*)(pool + 9216);
  u16* VhL  = (u16*)(pool + 18432);    // [64 d][72]
  u16* VlL  = (u16*)(pool + 27648);
  __half* Bh = (__half*)(pool + BH_OFF);  // [49 kh][66 pad]
  __half* Bw = (__half*)(pool + BW_OFF);  // [48 kw][66 pad]
  float* m_s = (float*)(pool + MS_OFF);   // [64]
  float* l_s = (float*)(pool + LS_OFF);   // [64]
  float* qlds = (float*)pool;             // prologue alias [64][68] f32
  float* o_s  = (float*)pool;             // epilogue alias [64][68] f32

  const int tid  = threadIdx.x;
  const int lane = tid & 63;
  const int wid  = tid >> 6;
  const int g    = lane >> 4;
  const int ql   = lane & 15;
  const int wq   = wid & 3;     // q-group: rows [16*wq, 16*wq+16)
  const int hh   = wid >> 2;    // key-half stream
  const int bh   = blockIdx.x;  // 24
  const int qt   = blockIdx.y;  // 36
  const int s0   = qt * 64;

  // ---- stage Q tile fp32 -> LDS
  {
    int row = tid >> 3, c0 = (tid & 7) * 8;
    const float* src = qb + ((size_t)bh * SEQ + s0 + row) * HD + c0;
    f32x4 v0 = *(const f32x4*)src;
    f32x4 v1 = *(const f32x4*)(src + 4);
    *(f32x4*)&qlds[row * 68 + c0]     = v0;
    *(f32x4*)&qlds[row * 68 + c0 + 4] = v1;
  }
  __syncthreads();

  // ---- Q fragments hi/lo (lane's q = 16*wq + ql)
  s16x8 qfh[2], qfl[2];
  {
    int qrow = wq * 16 + ql;
#pragma unroll
    for (int ds = 0; ds < 2; ds++) {
#pragma unroll
      for (int h2 = 0; h2 < 2; h2++) {
        f32x4 qv = *(const f32x4*)&qlds[qrow * 68 + g * 4 + h2 * 16 + ds * 32];
#pragma unroll
        for (int j = 0; j < 4; j++) {
          u16 hi, lo;
          split2(qv[j], hi, lo);
          qfh[ds][h2 * 4 + j] = (short)hi;
          qfl[ds][h2 * 4 + j] = (short)lo;
        }
      }
    }
  }

  // ---- prefetch tile 0
  const size_t tbK = (size_t)bh * 36 * 4096;
  const int srow = tid >> 3;
  const int sch  = ((tid & 7) - (srow & 7)) & 7;
  const size_t soff = (size_t)srow * 64 + sch * 8;
  uint4 rkh = *(const uint4*)(khi + tbK + soff);
  uint4 rkl = *(const uint4*)(klo + tbK + soff);
  uint4 rvh = *(const uint4*)(vhi + tbK + soff);
  uint4 rvl = *(const uint4*)(vlo + tbK + soff);

  // ---- decomposed rel-pos bias tables (fp16, stride 66)
  for (int i = tid; i < 64 * 96; i += 512) {
    int q = i / 96, j = i - (i / 96) * 96;
    int s = s0 + q;
    int qhg = s / 48, qw = s - qhg * 48;
    const float* tab;
    int ridx, col;
    if (j < 48) { col = j;      ridx = qhg - j + 47;        tab = rph; }
    else        { col = j - 48; ridx = qw - (j - 48) + 47;  tab = rpw; }
    const float* rp = tab + (size_t)ridx * HD;
    const float* qp = &qlds[q * 68];
    float s1 = 0.f;
#pragma unroll 4
    for (int d = 0; d < 64; d += 4) {
      f32x4 a = *(const f32x4*)(qp + d);
      f32x4 bv = *(const f32x4*)(rp + d);
      s1 += a[0]*bv[0] + a[1]*bv[1] + a[2]*bv[2] + a[3]*bv[3];
    }
    if (j < 48) Bh[col * 66 + q] = __float2half_rn(s1);
    else        Bw[col * 66 + q] = __float2half_rn(s1);
  }

  float m_r = -3.0e38f, l_r = 0.f;
  f32x4 oacc[4] = {};   // O[q = 4g+r][d = ql + 16*dt]
  const int q64b = wq * 16 + ql;

  for (int kt = 0; kt < 36; kt++) {
    __syncthreads();
    *(uint4*)(KhiL + srow * 72 + sch * 8) = rkh;
    *(uint4*)(KloL + srow * 72 + sch * 8) = rkl;
    *(uint4*)(VhL  + srow * 72 + sch * 8) = rvh;
    *(uint4*)(VlL  + srow * 72 + sch * 8) = rvl;
    __syncthreads();
    if (kt < 35) {     // T14: issue next-tile loads; land under MFMA phase
      size_t tb = tbK + (size_t)(kt + 1) * 4096;
      rkh = *(const uint4*)(khi + tb + soff);
      rkl = *(const uint4*)(klo + tb + soff);
      rvh = *(const uint4*)(vhi + tb + soff);
      rvl = *(const uint4*)(vlo + tb + soff);
    }

    // ---- QK^T (swapped): S^T[key][q]
    f32x4 sacc[2] = {};
    __builtin_amdgcn_s_setprio(1);
#pragma unroll
    for (int ds = 0; ds < 2; ds++) {
#pragma unroll
      for (int t2 = 0; t2 < 2; t2++) {
        int row = (hh * 2 + t2) * 16 + ql;
        s16x8 af = *(const s16x8*)(KhiL + row * 72 + ds * 32 + g * 8);
        s16x8 al = *(const s16x8*)(KloL + row * 72 + ds * 32 + g * 8);
        sacc[t2] = __builtin_amdgcn_mfma_f32_16x16x32_bf16(af, qfh[ds], sacc[t2], 0, 0, 0);
        sacc[t2] = __builtin_amdgcn_mfma_f32_16x16x32_bf16(af, qfl[ds], sacc[t2], 0, 0, 0);
        sacc[t2] = __builtin_amdgcn_mfma_f32_16x16x32_bf16(al, qfh[ds], sacc[t2], 0, 0, 0);
      }
    }
    __builtin_amdgcn_s_setprio(0);

    // ---- bias gather: kh in {kh0,kh0+1} within a half-tile
    u32 kg0 = (u32)(kt * 64 + hh * 32);
    u32 kh0 = kg0 / 48u;
    int kw0 = (int)(kg0 - kh0 * 48u);
    float bh0 = __half2float(Bh[kh0 * 66 + q64b]);
    float bh1 = __half2float(Bh[(kh0 + 1) * 66 + q64b]);
    float lg[8];
    float tmax = -3.0e38f;
#pragma unroll
    for (int t2 = 0; t2 < 2; t2++)
#pragma unroll
      for (int r = 0; r < 4; r++) {
        int j = t2 * 4 + r;
        int w = kw0 + t2 * 16 + g * 4 + r;
        bool wrap = w >= 48;
        float bw = __half2float(Bw[(wrap ? w - 48 : w) * 66 + q64b]);
        float x = sacc[t2][r] * 0.125f + (wrap ? bh1 : bh0) + bw;
        lg[j] = x;
        tmax = fmaxf(tmax, x);
      }
    tmax = fmaxf(tmax, __shfl_xor(tmax, 16));
    tmax = fmaxf(tmax, __shfl_xor(tmax, 32));
    if (__any(tmax > m_r + 6.0f)) {   // T13 defer-max
      float mnew = fmaxf(m_r, tmax);
      float corr = __expf(m_r - mnew);
      l_r *= corr;
      m_r = mnew;
      float cq[4];
#pragma unroll
      for (int r = 0; r < 4; r++) cq[r] = __shfl(corr, g * 4 + r);
#pragma unroll
      for (int dt = 0; dt < 4; dt++)
#pragma unroll
        for (int r = 0; r < 4; r++) oacc[dt][r] *= cq[r];
    }
    float psum = 0.f;
    s16x8 pfh, pfl;
#pragma unroll
    for (int j = 0; j < 8; j++) {
      float p = __expf(lg[j] - m_r);
      psum += p;
      u16 hi, lo;
      split2(p, hi, lo);
      pfh[j] = (short)hi;
      pfl[j] = (short)lo;
    }
    psum += __shfl_xor(psum, 16);
    psum += __shfl_xor(psum, 32);
    l_r += psum;

    // ---- PV
    __builtin_amdgcn_s_setprio(1);
#pragma unroll
    for (int dt = 0; dt < 4; dt++) {
      int row = ql + 16 * dt;
      s16x8 bhf = *(const s16x8*)(VhL + row * 72 + hh * 32 + g * 8);
      s16x8 blf = *(const s16x8*)(VlL + row * 72 + hh * 32 + g * 8);
      oacc[dt] = __builtin_amdgcn_mfma_f32_16x16x32_bf16(pfh, bhf, oacc[dt], 0, 0, 0);
      oacc[dt] = __builtin_amdgcn_mfma_f32_16x16x32_bf16(pfh, blf, oacc[dt], 0, 0, 0);
      oacc[dt] = __builtin_amdgcn_mfma_f32_16x16x32_bf16(pfl, bhf, oacc[dt], 0, 0, 0);
    }
    __builtin_amdgcn_s_setprio(0);
  }

  // ---- merge the two key-streams per q-group, write out (packed u32 hi|lo)
  __syncthreads();
  if (hh == 1) {
    if (g == 0) { m_s[q64b] = m_r; l_s[q64b] = l_r; }
#pragma unroll
    for (int dt = 0; dt < 4; dt++)
#pragma unroll
      for (int r = 0; r < 4; r++)
        o_s[(wq * 16 + g * 4 + r) * 68 + ql + 16 * dt] = oacc[dt][r];
  }
  __syncthreads();
  if (hh == 0) {
    float m2 = m_s[q64b];
    float l2 = l_s[q64b];
    float mf = fmaxf(m_r, m2);
    float c1 = __expf(m_r - mf);
    float c2 = __expf(m2 - mf);
    float lf = l_r * c1 + l2 * c2;
    float c1q[4], c2q[4], lfq[4];
#pragma unroll
    for (int r = 0; r < 4; r++) {
      c1q[r] = __shfl(c1, g * 4 + r);
      c2q[r] = __shfl(c2, g * 4 + r);
      lfq[r] = __shfl(lf, g * 4 + r);
    }
    const int b = bh / 12, head = bh - (bh / 12) * 12;
#pragma unroll
    for (int dt = 0; dt < 4; dt++)
#pragma unroll
      for (int r = 0; r < 4; r++) {
        float oo = oacc[dt][r] * c1q[r]
                 + o_s[(wq * 16 + g * 4 + r) * 68 + ql + 16 * dt] * c2q[r];
        float on = oo / lfq[r];
        int s = s0 + wq * 16 + g * 4 + r;
        size_t idx = ((size_t)b * SEQ + s) * 768 + head * 64 + ql + 16 * dt;
        u16 h, l;
        split2(on, h, l);
        aop[idx] = (u32)h | ((u32)l << 16);
      }
  }
}

// ---------------- proj GEMM via split-bf16 MFMA (A = packed u32 hi|lo): -> out
__global__ __launch_bounds__(256) void proj_mfma_k(
    const u32* __restrict__ aop,
    const u16* __restrict__ bthi, const u16* __restrict__ btlo,
    const float* __restrict__ bias, float* __restrict__ out)
{
  __shared__ __align__(16) u16 Ah[128*40], Al[128*40], Bh2[128*40], Bl2[128*40];
  const int tid = threadIdx.x;
  const int lane = tid & 63, wid = tid >> 6;
  const int g = lane >> 4, ql = lane & 15;
  const int wr = wid >> 1, wc = wid & 1;
  const int c0 = blockIdx.x * 128, r0 = blockIdx.y * 128;
  const int srow = tid >> 1, half = tid & 1;

  const u32* ag = aop + (size_t)(r0 + srow) * 768 + half * 16;
  const u16* bgh = bthi + (size_t)(c0 + srow) * 768 + half * 16;
  const u16* bgl = btlo + (size_t)(c0 + srow) * 768 + half * 16;

  uint4 paw[4]; uint4 pbh[2], pbl[2];
#pragma unroll
  for (int j = 0; j < 4; j++) paw[j] = *(const uint4*)(ag + j * 4);
  pbh[0] = *(const uint4*)bgh; pbh[1] = *(const uint4*)(bgh + 8);
  pbl[0] = *(const uint4*)bgl; pbl[1] = *(const uint4*)(bgl + 8);

  f32x4 acc[4][4] = {};

  for (int ks = 0; ks < 24; ks++) {
    __syncthreads();
    {
      u16 hb[16], lb[16];
      const u32* pw = (const u32*)&paw[0];
#pragma unroll
      for (int j = 0; j < 16; j++) {
        hb[j] = (u16)(pw[j] & 0xffffu);
        lb[j] = (u16)(pw[j] >> 16);
      }
      u16* d1 = Ah + srow * 40 + half * 16;
      u16* d2 = Al + srow * 40 + half * 16;
      u16* d3 = Bh2 + srow * 40 + half * 16;
      u16* d4 = Bl2 + srow * 40 + half * 16;
      *(uint4*)d1 = *(uint4*)&hb[0]; *(uint4*)(d1 + 8) = *(uint4*)&hb[8];
      *(uint4*)d2 = *(uint4*)&lb[0]; *(uint4*)(d2 + 8) = *(uint4*)&lb[8];
      *(uint4*)d3 = pbh[0]; *(uint4*)(d3 + 8) = pbh[1];
      *(uint4*)d4 = pbl[0]; *(uint4*)(d4 + 8) = pbl[1];
    }
    __syncthreads();
    if (ks < 23) {
      const int o = (ks + 1) * 32;
#pragma unroll
      for (int j = 0; j < 4; j++) paw[j] = *(const uint4*)(ag + o + j * 4);
      pbh[0] = *(const uint4*)(bgh + o); pbh[1] = *(const uint4*)(bgh + o + 8);
      pbl[0] = *(const uint4*)(bgl + o); pbl[1] = *(const uint4*)(bgl + o + 8);
    }
    s16x8 bfh[4], bfl[4];
#pragma unroll
    for (int nt = 0; nt < 4; nt++) {
      bfh[nt] = *(const s16x8*)(Bh2 + (wc * 64 + nt * 16 + ql) * 40 + g * 8);
      bfl[nt] = *(const s16x8*)(Bl2 + (wc * 64 + nt * 16 + ql) * 40 + g * 8);
    }
#pragma unroll
    for (int mt = 0; mt < 4; mt++) {
      s16x8 ah = *(const s16x8*)(Ah + (wr * 64 + mt * 16 + ql) * 40 + g * 8);
      s16x8 al = *(const s16x8*)(Al + (wr * 64 + mt * 16 + ql) * 40 + g * 8);
#pragma unroll
      for (int nt = 0; nt < 4; nt++) {
        acc[mt][nt] = __builtin_amdgcn_mfma_f32_16x16x32_bf16(ah, bfh[nt], acc[mt][nt], 0, 0, 0);
        acc[mt][nt] = __builtin_amdgcn_mfma_f32_16x16x32_bf16(ah, bfl[nt], acc[mt][nt], 0, 0, 0);
        acc[mt][nt] = __builtin_amdgcn_mfma_f32_16x16x32_bf16(al, bfh[nt], acc[mt][nt], 0, 0, 0);
      }
    }
  }
  const int col0 = c0 + wc * 64;
  const int row0 = r0 + wr * 64;
  float bb[4];
#pragma unroll
  for (int nt = 0; nt < 4; nt++) bb[nt] = bias[col0 + nt * 16 + ql];
#pragma unroll
  for (int mt = 0; mt < 4; mt++)
#pragma unroll
    for (int nt = 0; nt < 4; nt++)
#pragma unroll
      for (int r = 0; r < 4; r++)
        out[(size_t)(row0 + mt * 16 + g * 4 + r) * 768 + col0 + nt * 16 + ql] =
            acc[mt][nt][r] + bb[nt];
}

extern "C" void kernel_launch(void* const* d_in, const int* in_sizes, int n_in,
                              void* d_out, int out_size, void* d_ws, size_t ws_size,
                              hipStream_t stream) {
  const float* x      = (const float*)d_in[0];
  const float* qkv_w  = (const float*)d_in[1];
  const float* qkv_b  = (const float*)d_in[2];
  const float* proj_w = (const float*)d_in[3];
  const float* proj_b = (const float*)d_in[4];
  const float* rph    = (const float*)d_in[5];
  const float* rpw    = (const float*)d_in[6];
  float* out = (float*)d_out;
  float* ws  = (float*)d_ws;

  const size_t SZ = (size_t)24 * SEQ * HD;   // 3,538,944 elems (== 4608*768)
  float* qbuf = ws;                          // SZ f32
  u16* khi = (u16*)(ws + SZ);                // 4 x SZ u16
  u16* klo = khi + SZ;
  u16* vhi = klo + SZ;
  u16* vlo = vhi + SZ;
  u16* xhi = (u16*)(ws + 3 * SZ);            // 2 x SZ u16
  u16* xlo = xhi + SZ;
  u32* aop = (u32*)(ws + 4 * SZ);            // SZ u32 (packed hi|lo)
  u16* wqThi = (u16*)(ws + 5 * SZ);          // 768*2304 x2
  u16* wqTlo = wqThi + 768 * 2304;
  u16* wpThi = wqTlo + 768 * 2304;           // 768*768 x2
  u16* wpTlo = wpThi + 768 * 768;

  conv_split_k<<<1728, 256, 0, stream>>>(x, xhi, xlo);
  conv_wT_k <<<dim3(36, 12), 256, 0, stream>>>(qkv_w, wqThi, wqTlo, 768, 2304);
  conv_wT_k <<<dim3(12, 12), 256, 0, stream>>>(proj_w, wpThi, wpTlo, 768, 768);
  qkv_mfma_k<<<dim3(18, 36), 256, 0, stream>>>(xhi, xlo, wqThi, wqTlo, qkv_b,
                                               qbuf, khi, klo, vhi, vlo);
  attn_k    <<<dim3(24, 36), 512, 0, stream>>>(qbuf, khi, klo, vhi, vlo, rph, rpw, aop);
  proj_mfma_k<<<dim3(6, 36), 256, 0, stream>>>(aop, wpThi, wpTlo, proj_b, out);
}

// Round 10
// 566.269 us; speedup vs baseline: 1.1924x; 1.0191x over previous
//
#include <hip/hip_runtime.h>
#include <hip/hip_fp16.h>

#define HD 64
#define SEQ 2304

typedef unsigned short u16;
typedef unsigned int u32;
using f32x4 = __attribute__((ext_vector_type(4))) float;
using s16x8 = __attribute__((ext_vector_type(8))) short;

#define QSCALE 0.18033688f    // 0.125 * log2(e)
#define L2E    1.44269504f
#define DEFER_THR 8.65617f    // 6 * log2(e)

static __device__ __forceinline__ float bf2f(u16 h) {
  union { float f; u32 u; } a; a.u = ((u32)h) << 16; return a.f;
}
// truncation split: x ~= hi + lo, |err| ~ 2^-16 |x|
static __device__ __forceinline__ void split2(float x, u16& h, u16& l) {
  u32 u = __float_as_uint(x);
  h = (u16)(u >> 16);
  float r = x - __uint_as_float(u & 0xffff0000u);
  l = (u16)(__float_as_uint(r) >> 16);
}

// ---------------- split fp32 -> bf16 hi/lo, 8 elems/thread
__global__ __launch_bounds__(256) void conv_split_k(
    const float* __restrict__ src, u16* __restrict__ dhi, u16* __restrict__ dlo)
{
  const size_t i = ((size_t)blockIdx.x * 256 + threadIdx.x) * 8;
  f32x4 a = *(const f32x4*)(src + i);
  f32x4 b = *(const f32x4*)(src + i + 4);
  u16 h[8], l[8];
#pragma unroll
  for (int j = 0; j < 8; j++) {
    float x = j < 4 ? a[j] : b[j - 4];
    split2(x, h[j], l[j]);
  }
  *(uint4*)(dhi + i) = *(uint4*)&h[0];
  *(uint4*)(dlo + i) = *(uint4*)&l[0];
}

// ---------------- convert + transpose weights: w[K][N] f32 -> wT[N][K] bf16 hi/lo
__global__ __launch_bounds__(256) void conv_wT_k(
    const float* __restrict__ src, u16* __restrict__ dhi, u16* __restrict__ dlo,
    int K, int N)
{
  __shared__ u32 t[64][65];
  const int tid = threadIdx.x;
  const int n0 = blockIdx.x * 64, k0 = blockIdx.y * 64;
  const int r = tid >> 2, c0 = (tid & 3) * 16;
  const float* sp = src + (size_t)(k0 + r) * N + n0 + c0;
#pragma unroll
  for (int j = 0; j < 16; j += 4) {
    f32x4 v = *(const f32x4*)(sp + j);
#pragma unroll
    for (int e = 0; e < 4; e++) {
      u16 h, l;
      split2(v[e], h, l);
      t[r][c0 + j + e] = (u32)h | ((u32)l << 16);
    }
  }
  __syncthreads();
  u16 hb[16], lb[16];
#pragma unroll
  for (int j = 0; j < 16; j++) {
    u32 p = t[c0 + j][r];
    hb[j] = (u16)(p & 0xffffu);
    lb[j] = (u16)(p >> 16);
  }
  size_t off = (size_t)(n0 + r) * K + k0 + c0;
  *(uint4*)(dhi + off)     = *(uint4*)&hb[0];
  *(uint4*)(dhi + off + 8) = *(uint4*)&hb[8];
  *(uint4*)(dlo + off)     = *(uint4*)&lb[0];
  *(uint4*)(dlo + off + 8) = *(uint4*)&lb[8];
}

// ---- direct-fragment helpers (qkv): 16 global b128 loads / 48 MFMAs per K-step
static __device__ __forceinline__ void load16(
    const u16* pAh, const u16* pAl, const u16* pBh, const u16* pBl, int kk,
    s16x8 ah[4], s16x8 al[4], s16x8 bh[4], s16x8 bl[4])
{
#pragma unroll
  for (int mt = 0; mt < 4; mt++) {
    size_t o = (size_t)mt * 12288 + (size_t)kk * 32;   // mt*16 rows, kk*32 cols
    ah[mt] = *(const s16x8*)(pAh + o);
    al[mt] = *(const s16x8*)(pAl + o);
    bh[mt] = *(const s16x8*)(pBh + o);
    bl[mt] = *(const s16x8*)(pBl + o);
  }
}
static __device__ __forceinline__ void mfma48(
    const s16x8 ah[4], const s16x8 al[4], const s16x8 bh[4], const s16x8 bl[4],
    f32x4 acc[4][4])
{
#pragma unroll
  for (int mt = 0; mt < 4; mt++)
#pragma unroll
    for (int nt = 0; nt < 4; nt++) {
      acc[mt][nt] = __builtin_amdgcn_mfma_f32_16x16x32_bf16(ah[mt], bh[nt], acc[mt][nt], 0, 0, 0);
      acc[mt][nt] = __builtin_amdgcn_mfma_f32_16x16x32_bf16(ah[mt], bl[nt], acc[mt][nt], 0, 0, 0);
      acc[mt][nt] = __builtin_amdgcn_mfma_f32_16x16x32_bf16(al[mt], bh[nt], acc[mt][nt], 0, 0, 0);
    }
}

// ---------------- QKV GEMM, barrier-free direct-fragment: -> q fp32 + K/V images
// All fragments are per-lane contiguous b128 global loads (L2-resident inputs);
// X/Y ping-pong prefetch one K-step ahead hides L2 latency under 48 MFMAs.
__global__ __launch_bounds__(256, 2) void qkv_mfma_k(
    const u16* __restrict__ xhi, const u16* __restrict__ xlo,
    const u16* __restrict__ bthi, const u16* __restrict__ btlo,
    const float* __restrict__ bias,
    float* __restrict__ qbuf, u16* __restrict__ khi, u16* __restrict__ klo,
    u16* __restrict__ vhi, u16* __restrict__ vlo)
{
  __shared__ __align__(16) u16 img[4][4096];   // epilogue only (wave-private)
  const int tid = threadIdx.x;
  const int lane = tid & 63, wid = tid >> 6;
  const int g = lane >> 4, ql = lane & 15;
  const int wr = wid >> 1, wc = wid & 1;
  const int c0 = blockIdx.x * 128, r0 = blockIdx.y * 128;

  const u16* pAh = xhi  + (size_t)(r0 + wr * 64 + ql) * 768 + g * 8;
  const u16* pAl = xlo  + (size_t)(r0 + wr * 64 + ql) * 768 + g * 8;
  const u16* pBh = bthi + (size_t)(c0 + wc * 64 + ql) * 768 + g * 8;
  const u16* pBl = btlo + (size_t)(c0 + wc * 64 + ql) * 768 + g * 8;

  s16x8 Xah[4], Xal[4], Xbh[4], Xbl[4];
  s16x8 Yah[4], Yal[4], Ybh[4], Ybl[4];
  f32x4 acc[4][4] = {};

  load16(pAh, pAl, pBh, pBl, 0, Xah, Xal, Xbh, Xbl);
  for (int ks = 0; ks < 24; ks += 2) {
    load16(pAh, pAl, pBh, pBl, ks + 1, Yah, Yal, Ybh, Ybl);
    mfma48(Xah, Xal, Xbh, Xbl, acc);
    if (ks + 2 < 24)
      load16(pAh, pAl, pBh, pBl, ks + 2, Xah, Xal, Xbh, Xbl);
    mfma48(Yah, Yal, Ybh, Ybl, acc);
  }

  // ---- epilogue: q fp32 scatter / K,V permuted tile-images via LDS (wave-private)
  const int col0 = c0 + wc * 64;
  const int row0 = r0 + wr * 64;
  const int hb36 = col0 >> 6;
  const int which = hb36 / 12, head = hb36 - (hb36 / 12) * 12;
  const int b = row0 / 2304;
  const int sb = row0 - b * 2304;
  const int bh = b * 12 + head;
  float bb[4];
#pragma unroll
  for (int nt = 0; nt < 4; nt++) bb[nt] = bias[col0 + nt * 16 + ql];
#pragma unroll
  for (int mt = 0; mt < 4; mt++)
#pragma unroll
    for (int nt = 0; nt < 4; nt++)
#pragma unroll
      for (int r = 0; r < 4; r++)
        acc[mt][nt][r] += bb[nt];

  if (which == 0) {
#pragma unroll
    for (int mt = 0; mt < 4; mt++)
#pragma unroll
      for (int nt = 0; nt < 4; nt++)
#pragma unroll
        for (int r = 0; r < 4; r++) {
          int s = sb + mt * 16 + g * 4 + r;
          qbuf[((size_t)bh * SEQ + s) * 64 + nt * 16 + ql] = acc[mt][nt][r];
        }
  } else {
    const int kt = sb >> 6;
    const size_t tile = ((size_t)bh * 36 + kt) * 4096;
    u16* const dsth = (which == 1) ? khi : vhi;
    u16* const dstl = (which == 1) ? klo : vlo;
    u16* const reg = img[wid];
    // pass 1: HI image (wave-private LDS region -> no barriers)
#pragma unroll
    for (int mt = 0; mt < 4; mt++)
#pragma unroll
      for (int nt = 0; nt < 4; nt++) {
        int pcK = (nt >> 1) * 32 + (ql >> 2) * 8 + (nt & 1) * 4 + (ql & 3);
#pragma unroll
        for (int r = 0; r < 4; r++) {
          u16 h, l;
          split2(acc[mt][nt][r], h, l);
          int off = (which == 1)
              ? (mt * 16 + g * 4 + r) * 64 + pcK
              : (nt * 16 + ql) * 64 + (mt >> 1) * 32 + g * 8 + (mt & 1) * 4 + r;
          reg[off] = h;
        }
      }
    {
      const u16* src = reg + lane * 64;
      u16* dst = dsth + tile + lane * 64;
#pragma unroll
      for (int j = 0; j < 8; j++)
        *(uint4*)(dst + j * 8) = *(const uint4*)(src + j * 8);
    }
    // pass 2: LO image
#pragma unroll
    for (int mt = 0; mt < 4; mt++)
#pragma unroll
      for (int nt = 0; nt < 4; nt++) {
        int pcK = (nt >> 1) * 32 + (ql >> 2) * 8 + (nt & 1) * 4 + (ql & 3);
#pragma unroll
        for (int r = 0; r < 4; r++) {
          u16 h, l;
          split2(acc[mt][nt][r], h, l);
          int off = (which == 1)
              ? (mt * 16 + g * 4 + r) * 64 + pcK
              : (nt * 16 + ql) * 64 + (mt >> 1) * 32 + g * 8 + (mt & 1) * 4 + r;
          reg[off] = l;
        }
      }
    {
      const u16* src = reg + lane * 64;
      u16* dst = dstl + tile + lane * 64;
#pragma unroll
      for (int j = 0; j < 8; j++)
        *(uint4*)(dst + j * 8) = *(const uint4*)(src + j * 8);
    }
  }
}

// ---------------- Fused attention: 64 q-rows/block, 864 blocks, exp2-domain softmax.
// grid(bh=24, qt=36): 24%8==0 -> XCD = bh%8 for all qt (K/V image L2-pinned).
#define BH_OFF  36864                     // Bh: 49 x 66 u16 (row 48 = wrap slack)
#define BWT_OFF (BH_OFF + 49*66*2)        // 43332: BwT [64 q][72 w-extended]
#define MS_OFF  (BWT_OFF + 64*72*2)       // 52548
#define LS_OFF  (MS_OFF + 256)            // 52804
__global__ __launch_bounds__(512) void attn_k(
    const float* __restrict__ qb,
    const u16* __restrict__ khi, const u16* __restrict__ klo,
    const u16* __restrict__ vhi, const u16* __restrict__ vlo,
    const float* __restrict__ rph, const float* __restrict__ rpw,
    u32* __restrict__ aop)
{
  __shared__ __align__(16) char pool[LS_OFF + 256];
  u16* KhiL = (u16*)pool;              // [64 key][72]
  u16* KloL = (u16*)(pool + 9216);
  u16* VhL  = (u16*)(pool + 18432);    // [64 d][72]
  u16* VlL  = (u16*)(pool + 27648);
  __half* Bh  = (__half*)(pool + BH_OFF);   // [49 kh][66 pad], pre-scaled by log2e
  __half* BwT = (__half*)(pool + BWT_OFF);  // [64 q][72], w in [0,64) extended
  float* m_s = (float*)(pool + MS_OFF);     // [64]
  float* l_s = (float*)(pool + LS_OFF);     // [64]
  float* qlds = (float*)pool;               // prologue alias [64][68] f32
  float* o_s  = (float*)pool;               // epilogue alias [64][68] f32

  const int tid  = threadIdx.x;
  const int lane = tid & 63;
  const int wid  = tid >> 6;
  const int g    = lane >> 4;
  const int ql   = lane & 15;
  const int wq   = wid & 3;     // q-group: rows [16*wq, 16*wq+16)
  const int hh   = wid >> 2;    // key-half stream
  const int bh   = blockIdx.x;  // 24
  const int qt   = blockIdx.y;  // 36
  const int s0   = qt * 64;

  // ---- stage Q tile fp32 -> LDS
  {
    int row = tid >> 3, c0 = (tid & 7) * 8;
    const float* src = qb + ((size_t)bh * SEQ + s0 + row) * HD + c0;
    f32x4 v0 = *(const f32x4*)src;
    f32x4 v1 = *(const f32x4*)(src + 4);
    *(f32x4*)&qlds[row * 68 + c0]     = v0;
    *(f32x4*)&qlds[row * 68 + c0 + 4] = v1;
  }
  __syncthreads();

  // ---- Q fragments hi/lo, pre-scaled by 0.125*log2e (lane's q = 16*wq + ql)
  s16x8 qfh[2], qfl[2];
  {
    int qrow = wq * 16 + ql;
#pragma unroll
    for (int ds = 0; ds < 2; ds++) {
#pragma unroll
      for (int h2 = 0; h2 < 2; h2++) {
        f32x4 qv = *(const f32x4*)&qlds[qrow * 68 + g * 4 + h2 * 16 + ds * 32];
#pragma unroll
        for (int j = 0; j < 4; j++) {
          u16 hi, lo;
          split2(qv[j] * QSCALE, hi, lo);
          qfh[ds][h2 * 4 + j] = (short)hi;
          qfl[ds][h2 * 4 + j] = (short)lo;
        }
      }
    }
  }

  // ---- prefetch tile 0
  const size_t tbK = (size_t)bh * 36 * 4096;
  const int srow = tid >> 3;
  const int sch  = tid & 7;
  const size_t soff = (size_t)srow * 64 + sch * 8;
  uint4 rkh = *(const uint4*)(khi + tbK + soff);
  uint4 rkl = *(const uint4*)(klo + tbK + soff);
  uint4 rvh = *(const uint4*)(vhi + tbK + soff);
  uint4 rvl = *(const uint4*)(vlo + tbK + soff);

  // ---- bias tables (log2e-scaled): Bh [49 kh][66 q], BwT [64 q][72 w-extended]
  for (int i = tid; i < 64 * 112; i += 512) {
    int q = i / 112, j = i - (i / 112) * 112;
    int s = s0 + q;
    int qhg = s / 48, qw = s - qhg * 48;
    const float* rp;
    if (j < 48) {
      rp = rph + (size_t)(qhg - j + 47) * HD;
    } else {
      int w = j - 48;
      int kw = w < 48 ? w : w - 48;
      rp = rpw + (size_t)(qw - kw + 47) * HD;
    }
    const float* qp = &qlds[q * 68];
    float s1 = 0.f;
#pragma unroll 4
    for (int d = 0; d < 64; d += 4) {
      f32x4 a = *(const f32x4*)(qp + d);
      f32x4 bv = *(const f32x4*)(rp + d);
      s1 += a[0]*bv[0] + a[1]*bv[1] + a[2]*bv[2] + a[3]*bv[3];
    }
    __half hv = __float2half_rn(s1 * L2E);
    if (j < 48) Bh[j * 66 + q] = hv;
    else        BwT[q * 72 + (j - 48)] = hv;
  }

  float m_r = -3.0e38f, l_r = 0.f;
  f32x4 oacc[4] = {};   // O[q = 4g+r][d = ql + 16*dt]
  const int q64b = wq * 16 + ql;

  for (int kt = 0; kt < 36; kt++) {
    __syncthreads();
    *(uint4*)(KhiL + srow * 72 + sch * 8) = rkh;
    *(uint4*)(KloL + srow * 72 + sch * 8) = rkl;
    *(uint4*)(VhL  + srow * 72 + sch * 8) = rvh;
    *(uint4*)(VlL  + srow * 72 + sch * 8) = rvl;
    __syncthreads();
    if (kt < 35) {     // T14: issue next-tile loads; land under MFMA phase
      size_t tb = tbK + (size_t)(kt + 1) * 4096;
      rkh = *(const uint4*)(khi + tb + soff);
      rkl = *(const uint4*)(klo + tb + soff);
      rvh = *(const uint4*)(vhi + tb + soff);
      rvl = *(const uint4*)(vlo + tb + soff);
    }

    // ---- QK^T (swapped): S^T[key][q], pre-scaled logits (log2 domain)
    f32x4 sacc[2] = {};
    __builtin_amdgcn_s_setprio(1);
#pragma unroll
    for (int ds = 0; ds < 2; ds++) {
#pragma unroll
      for (int t2 = 0; t2 < 2; t2++) {
        int row = (hh * 2 + t2) * 16 + ql;
        s16x8 af = *(const s16x8*)(KhiL + row * 72 + ds * 32 + g * 8);
        s16x8 al = *(const s16x8*)(KloL + row * 72 + ds * 32 + g * 8);
        sacc[t2] = __builtin_amdgcn_mfma_f32_16x16x32_bf16(af, qfh[ds], sacc[t2], 0, 0, 0);
        sacc[t2] = __builtin_amdgcn_mfma_f32_16x16x32_bf16(af, qfl[ds], sacc[t2], 0, 0, 0);
        sacc[t2] = __builtin_amdgcn_mfma_f32_16x16x32_bf16(al, qfh[ds], sacc[t2], 0, 0, 0);
      }
    }
    __builtin_amdgcn_s_setprio(0);

    // ---- bias gather: 2 scalar Bh + 2 b64 BwT reads (extended table, no index wrap)
    u32 kg0 = (u32)(kt * 64 + hh * 32);
    u32 kh0 = kg0 / 48u;
    int kw0 = (int)(kg0 - kh0 * 48u);   // in {0,16,32}
    float bh0 = __half2float(Bh[kh0 * 66 + q64b]);
    float bh1 = __half2float(Bh[(kh0 + 1) * 66 + q64b]);
    const __half* bwrow = BwT + q64b * 72 + kw0 + g * 4;
    uint2 bwa = *(const uint2*)bwrow;         // w0..w0+3
    uint2 bwb = *(const uint2*)(bwrow + 16);  // w0+16..w0+19
    float bwf[8];
    {
      float2 f0 = __half22float2(*(__half2*)&bwa.x);
      float2 f1 = __half22float2(*(__half2*)&bwa.y);
      float2 f2 = __half22float2(*(__half2*)&bwb.x);
      float2 f3 = __half22float2(*(__half2*)&bwb.y);
      bwf[0] = f0.x; bwf[1] = f0.y; bwf[2] = f1.x; bwf[3] = f1.y;
      bwf[4] = f2.x; bwf[5] = f2.y; bwf[6] = f3.x; bwf[7] = f3.y;
    }
    float lg[8];
    float tmax = -3.0e38f;
#pragma unroll
    for (int t2 = 0; t2 < 2; t2++)
#pragma unroll
      for (int r = 0; r < 4; r++) {
        int j = t2 * 4 + r;
        int w = kw0 + t2 * 16 + g * 4 + r;
        float x = sacc[t2][r] + ((w >= 48) ? bh1 : bh0) + bwf[j];
        lg[j] = x;
        tmax = fmaxf(tmax, x);
      }
    tmax = fmaxf(tmax, __shfl_xor(tmax, 16));
    tmax = fmaxf(tmax, __shfl_xor(tmax, 32));
    if (__any(tmax > m_r + DEFER_THR)) {   // T13 defer-max (log2 domain)
      float mnew = fmaxf(m_r, tmax);
      float corr = exp2f(m_r - mnew);
      l_r *= corr;
      m_r = mnew;
      float cq[4];
#pragma unroll
      for (int r = 0; r < 4; r++) cq[r] = __shfl(corr, g * 4 + r);
#pragma unroll
      for (int dt = 0; dt < 4; dt++)
#pragma unroll
        for (int r = 0; r < 4; r++) oacc[dt][r] *= cq[r];
    }
    float psum = 0.f;
    s16x8 pfh, pfl;
#pragma unroll
    for (int j = 0; j < 8; j++) {
      float p = exp2f(lg[j] - m_r);
      psum += p;
      u16 hi, lo;
      split2(p, hi, lo);
      pfh[j] = (short)hi;
      pfl[j] = (short)lo;
    }
    psum += __shfl_xor(psum, 16);
    psum += __shfl_xor(psum, 32);
    l_r += psum;

    // ---- PV
    __builtin_amdgcn_s_setprio(1);
#pragma unroll
    for (int dt = 0; dt < 4; dt++) {
      int row = ql + 16 * dt;
      s16x8 bhf = *(const s16x8*)(VhL + row * 72 + hh * 32 + g * 8);
      s16x8 blf = *(const s16x8*)(VlL + row * 72 + hh * 32 + g * 8);
      oacc[dt] = __builtin_amdgcn_mfma_f32_16x16x32_bf16(pfh, bhf, oacc[dt], 0, 0, 0);
      oacc[dt] = __builtin_amdgcn_mfma_f32_16x16x32_bf16(pfh, blf, oacc[dt], 0, 0, 0);
      oacc[dt] = __builtin_amdgcn_mfma_f32_16x16x32_bf16(pfl, bhf, oacc[dt], 0, 0, 0);
    }
    __builtin_amdgcn_s_setprio(0);
  }

  // ---- merge the two key-streams per q-group, write out (packed u32 hi|lo)
  __syncthreads();
  if (hh == 1) {
    if (g == 0) { m_s[q64b] = m_r; l_s[q64b] = l_r; }
#pragma unroll
    for (int dt = 0; dt < 4; dt++)
#pragma unroll
      for (int r = 0; r < 4; r++)
        o_s[(wq * 16 + g * 4 + r) * 68 + ql + 16 * dt] = oacc[dt][r];
  }
  __syncthreads();
  if (hh == 0) {
    float m2 = m_s[q64b];
    float l2 = l_s[q64b];
    float mf = fmaxf(m_r, m2);
    float c1 = exp2f(m_r - mf);
    float c2 = exp2f(m2 - mf);
    float lf = l_r * c1 + l2 * c2;
    float c1q[4], c2q[4], lfq[4];
#pragma unroll
    for (int r = 0; r < 4; r++) {
      c1q[r] = __shfl(c1, g * 4 + r);
      c2q[r] = __shfl(c2, g * 4 + r);
      lfq[r] = __shfl(lf, g * 4 + r);
    }
    const int b = bh / 12, head = bh - (bh / 12) * 12;
#pragma unroll
    for (int dt = 0; dt < 4; dt++)
#pragma unroll
      for (int r = 0; r < 4; r++) {
        float oo = oacc[dt][r] * c1q[r]
                 + o_s[(wq * 16 + g * 4 + r) * 68 + ql + 16 * dt] * c2q[r];
        float on = oo / lfq[r];
        int s = s0 + wq * 16 + g * 4 + r;
        size_t idx = ((size_t)b * SEQ + s) * 768 + head * 64 + ql + 16 * dt;
        u16 h, l;
        split2(on, h, l);
        aop[idx] = (u32)h | ((u32)l << 16);
      }
  }
}

// ---------------- proj GEMM via split-bf16 MFMA (A = packed u32 hi|lo): -> out
__global__ __launch_bounds__(256) void proj_mfma_k(
    const u32* __restrict__ aop,
    const u16* __restrict__ bthi, const u16* __restrict__ btlo,
    const float* __restrict__ bias, float* __restrict__ out)
{
  __shared__ __align__(16) u16 Ah[128*40], Al[128*40], Bh2[128*40], Bl2[128*40];
  const int tid = threadIdx.x;
  const int lane = tid & 63, wid = tid >> 6;
  const int g = lane >> 4, ql = lane & 15;
  const int wr = wid >> 1, wc = wid & 1;
  const int c0 = blockIdx.x * 128, r0 = blockIdx.y * 128;
  const int srow = tid >> 1, half = tid & 1;

  const u32* ag = aop + (size_t)(r0 + srow) * 768 + half * 16;
  const u16* bgh = bthi + (size_t)(c0 + srow) * 768 + half * 16;
  const u16* bgl = btlo + (size_t)(c0 + srow) * 768 + half * 16;

  uint4 paw[4]; uint4 pbh[2], pbl[2];
#pragma unroll
  for (int j = 0; j < 4; j++) paw[j] = *(const uint4*)(ag + j * 4);
  pbh[0] = *(const uint4*)bgh; pbh[1] = *(const uint4*)(bgh + 8);
  pbl[0] = *(const uint4*)bgl; pbl[1] = *(const uint4*)(bgl + 8);

  f32x4 acc[4][4] = {};

  for (int ks = 0; ks < 24; ks++) {
    __syncthreads();
    {
      u16 hb[16], lb[16];
      const u32* pw = (const u32*)&paw[0];
#pragma unroll
      for (int j = 0; j < 16; j++) {
        hb[j] = (u16)(pw[j] & 0xffffu);
        lb[j] = (u16)(pw[j] >> 16);
      }
      u16* d1 = Ah + srow * 40 + half * 16;
      u16* d2 = Al + srow * 40 + half * 16;
      u16* d3 = Bh2 + srow * 40 + half * 16;
      u16* d4 = Bl2 + srow * 40 + half * 16;
      *(uint4*)d1 = *(uint4*)&hb[0]; *(uint4*)(d1 + 8) = *(uint4*)&hb[8];
      *(uint4*)d2 = *(uint4*)&lb[0]; *(uint4*)(d2 + 8) = *(uint4*)&lb[8];
      *(uint4*)d3 = pbh[0]; *(uint4*)(d3 + 8) = pbh[1];
      *(uint4*)d4 = pbl[0]; *(uint4*)(d4 + 8) = pbl[1];
    }
    __syncthreads();
    if (ks < 23) {
      const int o = (ks + 1) * 32;
#pragma unroll
      for (int j = 0; j < 4; j++) paw[j] = *(const uint4*)(ag + o + j * 4);
      pbh[0] = *(const uint4*)(bgh + o); pbh[1] = *(const uint4*)(bgh + o + 8);
      pbl[0] = *(const uint4*)(bgl + o); pbl[1] = *(const uint4*)(bgl + o + 8);
    }
    s16x8 bfh[4], bfl[4];
#pragma unroll
    for (int nt = 0; nt < 4; nt++) {
      bfh[nt] = *(const s16x8*)(Bh2 + (wc * 64 + nt * 16 + ql) * 40 + g * 8);
      bfl[nt] = *(const s16x8*)(Bl2 + (wc * 64 + nt * 16 + ql) * 40 + g * 8);
    }
#pragma unroll
    for (int mt = 0; mt < 4; mt++) {
      s16x8 ah = *(const s16x8*)(Ah + (wr * 64 + mt * 16 + ql) * 40 + g * 8);
      s16x8 al = *(const s16x8*)(Al + (wr * 64 + mt * 16 + ql) * 40 + g * 8);
#pragma unroll
      for (int nt = 0; nt < 4; nt++) {
        acc[mt][nt] = __builtin_amdgcn_mfma_f32_16x16x32_bf16(ah, bfh[nt], acc[mt][nt], 0, 0, 0);
        acc[mt][nt] = __builtin_amdgcn_mfma_f32_16x16x32_bf16(ah, bfl[nt], acc[mt][nt], 0, 0, 0);
        acc[mt][nt] = __builtin_amdgcn_mfma_f32_16x16x32_bf16(al, bfh[nt], acc[mt][nt], 0, 0, 0);
      }
    }
  }
  const int col0 = c0 + wc * 64;
  const int row0 = r0 + wr * 64;
  float bb[4];
#pragma unroll
  for (int nt = 0; nt < 4; nt++) bb[nt] = bias[col0 + nt * 16 + ql];
#pragma unroll
  for (int mt = 0; mt < 4; mt++)
#pragma unroll
    for (int nt = 0; nt < 4; nt++)
#pragma unroll
      for (int r = 0; r < 4; r++)
        out[(size_t)(row0 + mt * 16 + g * 4 + r) * 768 + col0 + nt * 16 + ql] =
            acc[mt][nt][r] + bb[nt];
}

extern "C" void kernel_launch(void* const* d_in, const int* in_sizes, int n_in,
                              void* d_out, int out_size, void* d_ws, size_t ws_size,
                              hipStream_t stream) {
  const float* x      = (const float*)d_in[0];
  const float* qkv_w  = (const float*)d_in[1];
  const float* qkv_b  = (const float*)d_in[2];
  const float* proj_w = (const float*)d_in[3];
  const float* proj_b = (const float*)d_in[4];
  const float* rph    = (const float*)d_in[5];
  const float* rpw    = (const float*)d_in[6];
  float* out = (float*)d_out;
  float* ws  = (float*)d_ws;

  const size_t SZ = (size_t)24 * SEQ * HD;   // 3,538,944 elems (== 4608*768)
  float* qbuf = ws;                          // SZ f32
  u16* khi = (u16*)(ws + SZ);                // 4 x SZ u16
  u16* klo = khi + SZ;
  u16* vhi = klo + SZ;
  u16* vlo = vhi + SZ;
  u16* xhi = (u16*)(ws + 3 * SZ);            // 2 x SZ u16
  u16* xlo = xhi + SZ;
  u32* aop = (u32*)(ws + 4 * SZ);            // SZ u32 (packed hi|lo)
  u16* wqThi = (u16*)(ws + 5 * SZ);          // 768*2304 x2
  u16* wqTlo = wqThi + 768 * 2304;
  u16* wpThi = wqTlo + 768 * 2304;           // 768*768 x2
  u16* wpTlo = wpThi + 768 * 768;

  conv_split_k<<<1728, 256, 0, stream>>>(x, xhi, xlo);
  conv_wT_k <<<dim3(36, 12), 256, 0, stream>>>(qkv_w, wqThi, wqTlo, 768, 2304);
  conv_wT_k <<<dim3(12, 12), 256, 0, stream>>>(proj_w, wpThi, wpTlo, 768, 768);
  qkv_mfma_k<<<dim3(18, 36), 256, 0, stream>>>(xhi, xlo, wqThi, wqTlo, qkv_b,
                                               qbuf, khi, klo, vhi, vlo);
  attn_k    <<<dim3(24, 36), 512, 0, stream>>>(qbuf, khi, klo, vhi, vlo, rph, rpw, aop);
  proj_mfma_k<<<dim3(6, 36), 256, 0, stream>>>(aop, wpThi, wpTlo, proj_b, out);
}

// Round 11
// 559.632 us; speedup vs baseline: 1.2066x; 1.0119x over previous
//
#include <hip/hip_runtime.h>
#include <hip/hip_fp16.h>

#define HD 64
#define SEQ 2304

typedef unsigned short u16;
typedef unsigned int u32;
using f32x4 = __attribute__((ext_vector_type(4))) float;
using s16x8 = __attribute__((ext_vector_type(8))) short;

#define QSCALE 0.18033688f    // 0.125 * log2(e)
#define L2E    1.44269504f
#define DEFER_THR 8.65617f    // 6 * log2(e)

static __device__ __forceinline__ float bf2f(u16 h) {
  union { float f; u32 u; } a; a.u = ((u32)h) << 16; return a.f;
}
// truncation split: x ~= hi + lo, |err| ~ 2^-16 |x|
static __device__ __forceinline__ void split2(float x, u16& h, u16& l) {
  u32 u = __float_as_uint(x);
  h = (u16)(u >> 16);
  float r = x - __uint_as_float(u & 0xffff0000u);
  l = (u16)(__float_as_uint(r) >> 16);
}
// hardware 2^x (v_exp_f32 is natively exp2) — libm exp2f carries precise-path overhead
static __device__ __forceinline__ float exp2fast(float x) {
  float r;
  asm("v_exp_f32 %0, %1" : "=v"(r) : "v"(x));
  return r;
}

// ---------------- split fp32 -> bf16 hi/lo, 8 elems/thread
__global__ __launch_bounds__(256) void conv_split_k(
    const float* __restrict__ src, u16* __restrict__ dhi, u16* __restrict__ dlo)
{
  const size_t i = ((size_t)blockIdx.x * 256 + threadIdx.x) * 8;
  f32x4 a = *(const f32x4*)(src + i);
  f32x4 b = *(const f32x4*)(src + i + 4);
  u16 h[8], l[8];
#pragma unroll
  for (int j = 0; j < 8; j++) {
    float x = j < 4 ? a[j] : b[j - 4];
    split2(x, h[j], l[j]);
  }
  *(uint4*)(dhi + i) = *(uint4*)&h[0];
  *(uint4*)(dlo + i) = *(uint4*)&l[0];
}

// ---------------- convert + transpose weights: w[K][N] f32 -> wT[N][K] bf16 hi/lo
__global__ __launch_bounds__(256) void conv_wT_k(
    const float* __restrict__ src, u16* __restrict__ dhi, u16* __restrict__ dlo,
    int K, int N)
{
  __shared__ u32 t[64][65];
  const int tid = threadIdx.x;
  const int n0 = blockIdx.x * 64, k0 = blockIdx.y * 64;
  const int r = tid >> 2, c0 = (tid & 3) * 16;
  const float* sp = src + (size_t)(k0 + r) * N + n0 + c0;
#pragma unroll
  for (int j = 0; j < 16; j += 4) {
    f32x4 v = *(const f32x4*)(sp + j);
#pragma unroll
    for (int e = 0; e < 4; e++) {
      u16 h, l;
      split2(v[e], h, l);
      t[r][c0 + j + e] = (u32)h | ((u32)l << 16);
    }
  }
  __syncthreads();
  u16 hb[16], lb[16];
#pragma unroll
  for (int j = 0; j < 16; j++) {
    u32 p = t[c0 + j][r];
    hb[j] = (u16)(p & 0xffffu);
    lb[j] = (u16)(p >> 16);
  }
  size_t off = (size_t)(n0 + r) * K + k0 + c0;
  *(uint4*)(dhi + off)     = *(uint4*)&hb[0];
  *(uint4*)(dhi + off + 8) = *(uint4*)&hb[8];
  *(uint4*)(dlo + off)     = *(uint4*)&lb[0];
  *(uint4*)(dlo + off + 8) = *(uint4*)&lb[8];
}

// ---- direct-fragment helpers (qkv): 16 global b128 loads / 48 MFMAs per K-step
static __device__ __forceinline__ void load16(
    const u16* pAh, const u16* pAl, const u16* pBh, const u16* pBl, int kk,
    s16x8 ah[4], s16x8 al[4], s16x8 bh[4], s16x8 bl[4])
{
#pragma unroll
  for (int mt = 0; mt < 4; mt++) {
    size_t o = (size_t)mt * 12288 + (size_t)kk * 32;   // mt*16 rows, kk*32 cols
    ah[mt] = *(const s16x8*)(pAh + o);
    al[mt] = *(const s16x8*)(pAl + o);
    bh[mt] = *(const s16x8*)(pBh + o);
    bl[mt] = *(const s16x8*)(pBl + o);
  }
}
static __device__ __forceinline__ void mfma48(
    const s16x8 ah[4], const s16x8 al[4], const s16x8 bh[4], const s16x8 bl[4],
    f32x4 acc[4][4])
{
#pragma unroll
  for (int mt = 0; mt < 4; mt++)
#pragma unroll
    for (int nt = 0; nt < 4; nt++) {
      acc[mt][nt] = __builtin_amdgcn_mfma_f32_16x16x32_bf16(ah[mt], bh[nt], acc[mt][nt], 0, 0, 0);
      acc[mt][nt] = __builtin_amdgcn_mfma_f32_16x16x32_bf16(ah[mt], bl[nt], acc[mt][nt], 0, 0, 0);
      acc[mt][nt] = __builtin_amdgcn_mfma_f32_16x16x32_bf16(al[mt], bh[nt], acc[mt][nt], 0, 0, 0);
    }
}

// ---------------- QKV GEMM, barrier-free direct-fragment: -> q fp32 + K/V images
__global__ __launch_bounds__(256, 2) void qkv_mfma_k(
    const u16* __restrict__ xhi, const u16* __restrict__ xlo,
    const u16* __restrict__ bthi, const u16* __restrict__ btlo,
    const float* __restrict__ bias,
    float* __restrict__ qbuf, u16* __restrict__ khi, u16* __restrict__ klo,
    u16* __restrict__ vhi, u16* __restrict__ vlo)
{
  __shared__ __align__(16) u16 img[4][4096];   // epilogue only (wave-private)
  const int tid = threadIdx.x;
  const int lane = tid & 63, wid = tid >> 6;
  const int g = lane >> 4, ql = lane & 15;
  const int wr = wid >> 1, wc = wid & 1;
  const int c0 = blockIdx.x * 128, r0 = blockIdx.y * 128;

  const u16* pAh = xhi  + (size_t)(r0 + wr * 64 + ql) * 768 + g * 8;
  const u16* pAl = xlo  + (size_t)(r0 + wr * 64 + ql) * 768 + g * 8;
  const u16* pBh = bthi + (size_t)(c0 + wc * 64 + ql) * 768 + g * 8;
  const u16* pBl = btlo + (size_t)(c0 + wc * 64 + ql) * 768 + g * 8;

  s16x8 Xah[4], Xal[4], Xbh[4], Xbl[4];
  s16x8 Yah[4], Yal[4], Ybh[4], Ybl[4];
  f32x4 acc[4][4] = {};

  load16(pAh, pAl, pBh, pBl, 0, Xah, Xal, Xbh, Xbl);
  for (int ks = 0; ks < 24; ks += 2) {
    load16(pAh, pAl, pBh, pBl, ks + 1, Yah, Yal, Ybh, Ybl);
    mfma48(Xah, Xal, Xbh, Xbl, acc);
    if (ks + 2 < 24)
      load16(pAh, pAl, pBh, pBl, ks + 2, Xah, Xal, Xbh, Xbl);
    mfma48(Yah, Yal, Ybh, Ybl, acc);
  }

  // ---- epilogue: q fp32 scatter / K,V permuted tile-images via LDS (wave-private)
  const int col0 = c0 + wc * 64;
  const int row0 = r0 + wr * 64;
  const int hb36 = col0 >> 6;
  const int which = hb36 / 12, head = hb36 - (hb36 / 12) * 12;
  const int b = row0 / 2304;
  const int sb = row0 - b * 2304;
  const int bh = b * 12 + head;
  float bb[4];
#pragma unroll
  for (int nt = 0; nt < 4; nt++) bb[nt] = bias[col0 + nt * 16 + ql];
#pragma unroll
  for (int mt = 0; mt < 4; mt++)
#pragma unroll
    for (int nt = 0; nt < 4; nt++)
#pragma unroll
      for (int r = 0; r < 4; r++)
        acc[mt][nt][r] += bb[nt];

  if (which == 0) {
#pragma unroll
    for (int mt = 0; mt < 4; mt++)
#pragma unroll
      for (int nt = 0; nt < 4; nt++)
#pragma unroll
        for (int r = 0; r < 4; r++) {
          int s = sb + mt * 16 + g * 4 + r;
          qbuf[((size_t)bh * SEQ + s) * 64 + nt * 16 + ql] = acc[mt][nt][r];
        }
  } else {
    const int kt = sb >> 6;
    const size_t tile = ((size_t)bh * 36 + kt) * 4096;
    u16* const dsth = (which == 1) ? khi : vhi;
    u16* const dstl = (which == 1) ? klo : vlo;
    u16* const reg = img[wid];
    // pass 1: HI image (wave-private LDS region -> no barriers)
#pragma unroll
    for (int mt = 0; mt < 4; mt++)
#pragma unroll
      for (int nt = 0; nt < 4; nt++) {
        int pcK = (nt >> 1) * 32 + (ql >> 2) * 8 + (nt & 1) * 4 + (ql & 3);
#pragma unroll
        for (int r = 0; r < 4; r++) {
          u16 h, l;
          split2(acc[mt][nt][r], h, l);
          int off = (which == 1)
              ? (mt * 16 + g * 4 + r) * 64 + pcK
              : (nt * 16 + ql) * 64 + (mt >> 1) * 32 + g * 8 + (mt & 1) * 4 + r;
          reg[off] = h;
        }
      }
    {
      const u16* src = reg + lane * 64;
      u16* dst = dsth + tile + lane * 64;
#pragma unroll
      for (int j = 0; j < 8; j++)
        *(uint4*)(dst + j * 8) = *(const uint4*)(src + j * 8);
    }
    // pass 2: LO image
#pragma unroll
    for (int mt = 0; mt < 4; mt++)
#pragma unroll
      for (int nt = 0; nt < 4; nt++) {
        int pcK = (nt >> 1) * 32 + (ql >> 2) * 8 + (nt & 1) * 4 + (ql & 3);
#pragma unroll
        for (int r = 0; r < 4; r++) {
          u16 h, l;
          split2(acc[mt][nt][r], h, l);
          int off = (which == 1)
              ? (mt * 16 + g * 4 + r) * 64 + pcK
              : (nt * 16 + ql) * 64 + (mt >> 1) * 32 + g * 8 + (mt & 1) * 4 + r;
          reg[off] = l;
        }
      }
    {
      const u16* src = reg + lane * 64;
      u16* dst = dstl + tile + lane * 64;
#pragma unroll
      for (int j = 0; j < 8; j++)
        *(uint4*)(dst + j * 8) = *(const uint4*)(src + j * 8);
    }
  }
}

// ---------------- Fused attention: 64 q-rows/block, 864 blocks, exp2-domain softmax
// with HW v_exp_f32. grid(bh=24, qt=36): XCD = bh%8 (K/V image L2-pinned).
#define BH_OFF  36864                     // Bh: 49 x 66 u16
#define BWT_OFF (BH_OFF + 49*66*2)        // 43332: BwT [64 q][72 w-extended]
#define MS_OFF  (BWT_OFF + 64*72*2)       // 52548
#define LS_OFF  (MS_OFF + 256)            // 52804
__global__ __launch_bounds__(512) void attn_k(
    const float* __restrict__ qb,
    const u16* __restrict__ khi, const u16* __restrict__ klo,
    const u16* __restrict__ vhi, const u16* __restrict__ vlo,
    const float* __restrict__ rph, const float* __restrict__ rpw,
    u32* __restrict__ aop)
{
  __shared__ __align__(16) char pool[LS_OFF + 256];
  u16* KhiL = (u16*)pool;              // [64 key][72]
  u16* KloL = (u16*)(pool + 9216);
  u16* VhL  = (u16*)(pool + 18432);    // [64 d][72]
  u16* VlL  = (u16*)(pool + 27648);
  __half* Bh  = (__half*)(pool + BH_OFF);   // [49 kh][66 pad], pre-scaled by log2e
  __half* BwT = (__half*)(pool + BWT_OFF);  // [64 q][72], w in [0,64) extended
  float* m_s = (float*)(pool + MS_OFF);     // [64]
  float* l_s = (float*)(pool + LS_OFF);     // [64]
  float* qlds = (float*)pool;               // prologue alias [64][68] f32
  float* o_s  = (float*)pool;               // epilogue alias [64][68] f32

  const int tid  = threadIdx.x;
  const int lane = tid & 63;
  const int wid  = tid >> 6;
  const int g    = lane >> 4;
  const int ql   = lane & 15;
  const int wq   = wid & 3;     // q-group: rows [16*wq, 16*wq+16)
  const int hh   = wid >> 2;    // key-half stream
  const int bh   = blockIdx.x;  // 24
  const int qt   = blockIdx.y;  // 36
  const int s0   = qt * 64;

  // ---- stage Q tile fp32 -> LDS
  {
    int row = tid >> 3, c0 = (tid & 7) * 8;
    const float* src = qb + ((size_t)bh * SEQ + s0 + row) * HD + c0;
    f32x4 v0 = *(const f32x4*)src;
    f32x4 v1 = *(const f32x4*)(src + 4);
    *(f32x4*)&qlds[row * 68 + c0]     = v0;
    *(f32x4*)&qlds[row * 68 + c0 + 4] = v1;
  }
  __syncthreads();

  // ---- Q fragments hi/lo, pre-scaled by 0.125*log2e (lane's q = 16*wq + ql)
  s16x8 qfh[2], qfl[2];
  {
    int qrow = wq * 16 + ql;
#pragma unroll
    for (int ds = 0; ds < 2; ds++) {
#pragma unroll
      for (int h2 = 0; h2 < 2; h2++) {
        f32x4 qv = *(const f32x4*)&qlds[qrow * 68 + g * 4 + h2 * 16 + ds * 32];
#pragma unroll
        for (int j = 0; j < 4; j++) {
          u16 hi, lo;
          split2(qv[j] * QSCALE, hi, lo);
          qfh[ds][h2 * 4 + j] = (short)hi;
          qfl[ds][h2 * 4 + j] = (short)lo;
        }
      }
    }
  }

  // ---- prefetch tile 0
  const size_t tbK = (size_t)bh * 36 * 4096;
  const int srow = tid >> 3;
  const int sch  = tid & 7;
  const size_t soff = (size_t)srow * 64 + sch * 8;
  uint4 rkh = *(const uint4*)(khi + tbK + soff);
  uint4 rkl = *(const uint4*)(klo + tbK + soff);
  uint4 rvh = *(const uint4*)(vhi + tbK + soff);
  uint4 rvl = *(const uint4*)(vlo + tbK + soff);

  // ---- bias tables (log2e-scaled): Bh [49 kh][66 q], BwT [64 q][72 w-extended]
  for (int i = tid; i < 64 * 112; i += 512) {
    int q = i / 112, j = i - (i / 112) * 112;
    int s = s0 + q;
    int qhg = s / 48, qw = s - qhg * 48;
    const float* rp;
    if (j < 48) {
      rp = rph + (size_t)(qhg - j + 47) * HD;
    } else {
      int w = j - 48;
      int kw = w < 48 ? w : w - 48;
      rp = rpw + (size_t)(qw - kw + 47) * HD;
    }
    const float* qp = &qlds[q * 68];
    float s1 = 0.f;
#pragma unroll 4
    for (int d = 0; d < 64; d += 4) {
      f32x4 a = *(const f32x4*)(qp + d);
      f32x4 bv = *(const f32x4*)(rp + d);
      s1 += a[0]*bv[0] + a[1]*bv[1] + a[2]*bv[2] + a[3]*bv[3];
    }
    __half hv = __float2half_rn(s1 * L2E);
    if (j < 48) Bh[j * 66 + q] = hv;
    else        BwT[q * 72 + (j - 48)] = hv;
  }

  float m_r = -3.0e38f, l_r = 0.f;
  f32x4 oacc[4] = {};   // O[q = 4g+r][d = ql + 16*dt]
  const int q64b = wq * 16 + ql;

  for (int kt = 0; kt < 36; kt++) {
    __syncthreads();
    *(uint4*)(KhiL + srow * 72 + sch * 8) = rkh;
    *(uint4*)(KloL + srow * 72 + sch * 8) = rkl;
    *(uint4*)(VhL  + srow * 72 + sch * 8) = rvh;
    *(uint4*)(VlL  + srow * 72 + sch * 8) = rvl;
    __syncthreads();
    if (kt < 35) {     // T14: issue next-tile loads; land under MFMA phase
      size_t tb = tbK + (size_t)(kt + 1) * 4096;
      rkh = *(const uint4*)(khi + tb + soff);
      rkl = *(const uint4*)(klo + tb + soff);
      rvh = *(const uint4*)(vhi + tb + soff);
      rvl = *(const uint4*)(vlo + tb + soff);
    }

    // ---- QK^T (swapped): S^T[key][q], pre-scaled logits (log2 domain)
    f32x4 sacc[2] = {};
    __builtin_amdgcn_s_setprio(1);
#pragma unroll
    for (int ds = 0; ds < 2; ds++) {
#pragma unroll
      for (int t2 = 0; t2 < 2; t2++) {
        int row = (hh * 2 + t2) * 16 + ql;
        s16x8 af = *(const s16x8*)(KhiL + row * 72 + ds * 32 + g * 8);
        s16x8 al = *(const s16x8*)(KloL + row * 72 + ds * 32 + g * 8);
        sacc[t2] = __builtin_amdgcn_mfma_f32_16x16x32_bf16(af, qfh[ds], sacc[t2], 0, 0, 0);
        sacc[t2] = __builtin_amdgcn_mfma_f32_16x16x32_bf16(af, qfl[ds], sacc[t2], 0, 0, 0);
        sacc[t2] = __builtin_amdgcn_mfma_f32_16x16x32_bf16(al, qfh[ds], sacc[t2], 0, 0, 0);
      }
    }
    __builtin_amdgcn_s_setprio(0);

    // ---- bias gather: 2 scalar Bh + 2 b64 BwT reads (extended table, no index wrap)
    u32 kg0 = (u32)(kt * 64 + hh * 32);
    u32 kh0 = kg0 / 48u;
    int kw0 = (int)(kg0 - kh0 * 48u);   // in {0,16,32}
    float bh0 = __half2float(Bh[kh0 * 66 + q64b]);
    float bh1 = __half2float(Bh[(kh0 + 1) * 66 + q64b]);
    const __half* bwrow = BwT + q64b * 72 + kw0 + g * 4;
    uint2 bwa = *(const uint2*)bwrow;         // w0..w0+3
    uint2 bwb = *(const uint2*)(bwrow + 16);  // w0+16..w0+19
    float bwf[8];
    {
      float2 f0 = __half22float2(*(__half2*)&bwa.x);
      float2 f1 = __half22float2(*(__half2*)&bwa.y);
      float2 f2 = __half22float2(*(__half2*)&bwb.x);
      float2 f3 = __half22float2(*(__half2*)&bwb.y);
      bwf[0] = f0.x; bwf[1] = f0.y; bwf[2] = f1.x; bwf[3] = f1.y;
      bwf[4] = f2.x; bwf[5] = f2.y; bwf[6] = f3.x; bwf[7] = f3.y;
    }
    float lg[8];
    float tmax = -3.0e38f;
#pragma unroll
    for (int t2 = 0; t2 < 2; t2++)
#pragma unroll
      for (int r = 0; r < 4; r++) {
        int j = t2 * 4 + r;
        int w = kw0 + t2 * 16 + g * 4 + r;
        float x = sacc[t2][r] + ((w >= 48) ? bh1 : bh0) + bwf[j];
        lg[j] = x;
        tmax = fmaxf(tmax, x);
      }
    tmax = fmaxf(tmax, __shfl_xor(tmax, 16));
    tmax = fmaxf(tmax, __shfl_xor(tmax, 32));
    if (__any(tmax > m_r + DEFER_THR)) {   // T13 defer-max (log2 domain)
      float mnew = fmaxf(m_r, tmax);
      float corr = exp2fast(m_r - mnew);
      l_r *= corr;
      m_r = mnew;
      float cq[4];
#pragma unroll
      for (int r = 0; r < 4; r++) cq[r] = __shfl(corr, g * 4 + r);
#pragma unroll
      for (int dt = 0; dt < 4; dt++)
#pragma unroll
        for (int r = 0; r < 4; r++) oacc[dt][r] *= cq[r];
    }
    float psum = 0.f;
    s16x8 pfh, pfl;
#pragma unroll
    for (int j = 0; j < 8; j++) {
      float p = exp2fast(lg[j] - m_r);
      psum += p;
      u16 hi, lo;
      split2(p, hi, lo);
      pfh[j] = (short)hi;
      pfl[j] = (short)lo;
    }
    psum += __shfl_xor(psum, 16);
    psum += __shfl_xor(psum, 32);
    l_r += psum;

    // ---- PV
    __builtin_amdgcn_s_setprio(1);
#pragma unroll
    for (int dt = 0; dt < 4; dt++) {
      int row = ql + 16 * dt;
      s16x8 bhf = *(const s16x8*)(VhL + row * 72 + hh * 32 + g * 8);
      s16x8 blf = *(const s16x8*)(VlL + row * 72 + hh * 32 + g * 8);
      oacc[dt] = __builtin_amdgcn_mfma_f32_16x16x32_bf16(pfh, bhf, oacc[dt], 0, 0, 0);
      oacc[dt] = __builtin_amdgcn_mfma_f32_16x16x32_bf16(pfh, blf, oacc[dt], 0, 0, 0);
      oacc[dt] = __builtin_amdgcn_mfma_f32_16x16x32_bf16(pfl, bhf, oacc[dt], 0, 0, 0);
    }
    __builtin_amdgcn_s_setprio(0);
  }

  // ---- merge the two key-streams per q-group, write out (packed u32 hi|lo)
  __syncthreads();
  if (hh == 1) {
    if (g == 0) { m_s[q64b] = m_r; l_s[q64b] = l_r; }
#pragma unroll
    for (int dt = 0; dt < 4; dt++)
#pragma unroll
      for (int r = 0; r < 4; r++)
        o_s[(wq * 16 + g * 4 + r) * 68 + ql + 16 * dt] = oacc[dt][r];
  }
  __syncthreads();
  if (hh == 0) {
    float m2 = m_s[q64b];
    float l2 = l_s[q64b];
    float mf = fmaxf(m_r, m2);
    float c1 = exp2fast(m_r - mf);
    float c2 = exp2fast(m2 - mf);
    float lf = l_r * c1 + l2 * c2;
    float c1q[4], c2q[4], lfq[4];
#pragma unroll
    for (int r = 0; r < 4; r++) {
      c1q[r] = __shfl(c1, g * 4 + r);
      c2q[r] = __shfl(c2, g * 4 + r);
      lfq[r] = __shfl(lf, g * 4 + r);
    }
    const int b = bh / 12, head = bh - (bh / 12) * 12;
#pragma unroll
    for (int dt = 0; dt < 4; dt++)
#pragma unroll
      for (int r = 0; r < 4; r++) {
        float oo = oacc[dt][r] * c1q[r]
                 + o_s[(wq * 16 + g * 4 + r) * 68 + ql + 16 * dt] * c2q[r];
        float on = oo / lfq[r];
        int s = s0 + wq * 16 + g * 4 + r;
        size_t idx = ((size_t)b * SEQ + s) * 768 + head * 64 + ql + 16 * dt;
        u16 h, l;
        split2(on, h, l);
        aop[idx] = (u32)h | ((u32)l << 16);
      }
  }
}

// ---------------- proj GEMM via split-bf16 MFMA (A = packed u32 hi|lo): -> out
__global__ __launch_bounds__(256) void proj_mfma_k(
    const u32* __restrict__ aop,
    const u16* __restrict__ bthi, const u16* __restrict__ btlo,
    const float* __restrict__ bias, float* __restrict__ out)
{
  __shared__ __align__(16) u16 Ah[128*40], Al[128*40], Bh2[128*40], Bl2[128*40];
  const int tid = threadIdx.x;
  const int lane = tid & 63, wid = tid >> 6;
  const int g = lane >> 4, ql = lane & 15;
  const int wr = wid >> 1, wc = wid & 1;
  const int c0 = blockIdx.x * 128, r0 = blockIdx.y * 128;
  const int srow = tid >> 1, half = tid & 1;

  const u32* ag = aop + (size_t)(r0 + srow) * 768 + half * 16;
  const u16* bgh = bthi + (size_t)(c0 + srow) * 768 + half * 16;
  const u16* bgl = btlo + (size_t)(c0 + srow) * 768 + half * 16;

  uint4 paw[4]; uint4 pbh[2], pbl[2];
#pragma unroll
  for (int j = 0; j < 4; j++) paw[j] = *(const uint4*)(ag + j * 4);
  pbh[0] = *(const uint4*)bgh; pbh[1] = *(const uint4*)(bgh + 8);
  pbl[0] = *(const uint4*)bgl; pbl[1] = *(const uint4*)(bgl + 8);

  f32x4 acc[4][4] = {};

  for (int ks = 0; ks < 24; ks++) {
    __syncthreads();
    {
      u16 hb[16], lb[16];
      const u32* pw = (const u32*)&paw[0];
#pragma unroll
      for (int j = 0; j < 16; j++) {
        hb[j] = (u16)(pw[j] & 0xffffu);
        lb[j] = (u16)(pw[j] >> 16);
      }
      u16* d1 = Ah + srow * 40 + half * 16;
      u16* d2 = Al + srow * 40 + half * 16;
      u16* d3 = Bh2 + srow * 40 + half * 16;
      u16* d4 = Bl2 + srow * 40 + half * 16;
      *(uint4*)d1 = *(uint4*)&hb[0]; *(uint4*)(d1 + 8) = *(uint4*)&hb[8];
      *(uint4*)d2 = *(uint4*)&lb[0]; *(uint4*)(d2 + 8) = *(uint4*)&lb[8];
      *(uint4*)d3 = pbh[0]; *(uint4*)(d3 + 8) = pbh[1];
      *(uint4*)d4 = pbl[0]; *(uint4*)(d4 + 8) = pbl[1];
    }
    __syncthreads();
    if (ks < 23) {
      const int o = (ks + 1) * 32;
#pragma unroll
      for (int j = 0; j < 4; j++) paw[j] = *(const uint4*)(ag + o + j * 4);
      pbh[0] = *(const uint4*)(bgh + o); pbh[1] = *(const uint4*)(bgh + o + 8);
      pbl[0] = *(const uint4*)(bgl + o); pbl[1] = *(const uint4*)(bgl + o + 8);
    }
    s16x8 bfh[4], bfl[4];
#pragma unroll
    for (int nt = 0; nt < 4; nt++) {
      bfh[nt] = *(const s16x8*)(Bh2 + (wc * 64 + nt * 16 + ql) * 40 + g * 8);
      bfl[nt] = *(const s16x8*)(Bl2 + (wc * 64 + nt * 16 + ql) * 40 + g * 8);
    }
#pragma unroll
    for (int mt = 0; mt < 4; mt++) {
      s16x8 ah = *(const s16x8*)(Ah + (wr * 64 + mt * 16 + ql) * 40 + g * 8);
      s16x8 al = *(const s16x8*)(Al + (wr * 64 + mt * 16 + ql) * 40 + g * 8);
#pragma unroll
      for (int nt = 0; nt < 4; nt++) {
        acc[mt][nt] = __builtin_amdgcn_mfma_f32_16x16x32_bf16(ah, bfh[nt], acc[mt][nt], 0, 0, 0);
        acc[mt][nt] = __builtin_amdgcn_mfma_f32_16x16x32_bf16(ah, bfl[nt], acc[mt][nt], 0, 0, 0);
        acc[mt][nt] = __builtin_amdgcn_mfma_f32_16x16x32_bf16(al, bfh[nt], acc[mt][nt], 0, 0, 0);
      }
    }
  }
  const int col0 = c0 + wc * 64;
  const int row0 = r0 + wr * 64;
  float bb[4];
#pragma unroll
  for (int nt = 0; nt < 4; nt++) bb[nt] = bias[col0 + nt * 16 + ql];
#pragma unroll
  for (int mt = 0; mt < 4; mt++)
#pragma unroll
    for (int nt = 0; nt < 4; nt++)
#pragma unroll
      for (int r = 0; r < 4; r++)
        out[(size_t)(row0 + mt * 16 + g * 4 + r) * 768 + col0 + nt * 16 + ql] =
            acc[mt][nt][r] + bb[nt];
}

extern "C" void kernel_launch(void* const* d_in, const int* in_sizes, int n_in,
                              void* d_out, int out_size, void* d_ws, size_t ws_size,
                              hipStream_t stream) {
  const float* x      = (const float*)d_in[0];
  const float* qkv_w  = (const float*)d_in[1];
  const float* qkv_b  = (const float*)d_in[2];
  const float* proj_w = (const float*)d_in[3];
  const float* proj_b = (const float*)d_in[4];
  const float* rph    = (const float*)d_in[5];
  const float* rpw    = (const float*)d_in[6];
  float* out = (float*)d_out;
  float* ws  = (float*)d_ws;

  const size_t SZ = (size_t)24 * SEQ * HD;   // 3,538,944 elems (== 4608*768)
  float* qbuf = ws;                          // SZ f32
  u16* khi = (u16*)(ws + SZ);                // 4 x SZ u16
  u16* klo = khi + SZ;
  u16* vhi = klo + SZ;
  u16* vlo = vhi + SZ;
  u16* xhi = (u16*)(ws + 3 * SZ);            // 2 x SZ u16
  u16* xlo = xhi + SZ;
  u32* aop = (u32*)(ws + 4 * SZ);            // SZ u32 (packed hi|lo)
  u16* wqThi = (u16*)(ws + 5 * SZ);          // 768*2304 x2
  u16* wqTlo = wqThi + 768 * 2304;
  u16* wpThi = wqTlo + 768 * 2304;           // 768*768 x2
  u16* wpTlo = wpThi + 768 * 768;

  conv_split_k<<<1728, 256, 0, stream>>>(x, xhi, xlo);
  conv_wT_k <<<dim3(36, 12), 256, 0, stream>>>(qkv_w, wqThi, wqTlo, 768, 2304);
  conv_wT_k <<<dim3(12, 12), 256, 0, stream>>>(proj_w, wpThi, wpTlo, 768, 768);
  qkv_mfma_k<<<dim3(18, 36), 256, 0, stream>>>(xhi, xlo, wqThi, wqTlo, qkv_b,
                                               qbuf, khi, klo, vhi, vlo);
  attn_k    <<<dim3(24, 36), 512, 0, stream>>>(qbuf, khi, klo, vhi, vlo, rph, rpw, aop);
  proj_mfma_k<<<dim3(6, 36), 256, 0, stream>>>(aop, wpThi, wpTlo, proj_b, out);
}

// Round 12
// 506.236 us; speedup vs baseline: 1.3338x; 1.1055x over previous
//
#include <hip/hip_runtime.h>
#include <hip/hip_fp16.h>

#define HD 64
#define SEQ 2304

typedef unsigned short u16;
typedef unsigned int u32;
using f32x4 = __attribute__((ext_vector_type(4))) float;
using s16x8 = __attribute__((ext_vector_type(8))) short;

static __device__ __forceinline__ float bf2f(u16 h) {
  union { float f; u32 u; } a; a.u = ((u32)h) << 16; return a.f;
}
// truncation split: x ~= hi + lo, |err| ~ 2^-16 |x|
static __device__ __forceinline__ void split2(float x, u16& h, u16& l) {
  u32 u = __float_as_uint(x);
  h = (u16)(u >> 16);
  float r = x - __uint_as_float(u & 0xffff0000u);
  l = (u16)(__float_as_uint(r) >> 16);
}

// ---------------- split fp32 -> bf16 hi/lo, 8 elems/thread
__global__ __launch_bounds__(256) void conv_split_k(
    const float* __restrict__ src, u16* __restrict__ dhi, u16* __restrict__ dlo)
{
  const size_t i = ((size_t)blockIdx.x * 256 + threadIdx.x) * 8;
  f32x4 a = *(const f32x4*)(src + i);
  f32x4 b = *(const f32x4*)(src + i + 4);
  u16 h[8], l[8];
#pragma unroll
  for (int j = 0; j < 8; j++) {
    float x = j < 4 ? a[j] : b[j - 4];
    split2(x, h[j], l[j]);
  }
  *(uint4*)(dhi + i) = *(uint4*)&h[0];
  *(uint4*)(dlo + i) = *(uint4*)&l[0];
}

// ---------------- convert + transpose weights: w[K][N] f32 -> wT[N][K] bf16 hi/lo
__global__ __launch_bounds__(256) void conv_wT_k(
    const float* __restrict__ src, u16* __restrict__ dhi, u16* __restrict__ dlo,
    int K, int N)
{
  __shared__ u32 t[64][65];
  const int tid = threadIdx.x;
  const int n0 = blockIdx.x * 64, k0 = blockIdx.y * 64;
  const int r = tid >> 2, c0 = (tid & 3) * 16;
  const float* sp = src + (size_t)(k0 + r) * N + n0 + c0;
#pragma unroll
  for (int j = 0; j < 16; j += 4) {
    f32x4 v = *(const f32x4*)(sp + j);
#pragma unroll
    for (int e = 0; e < 4; e++) {
      u16 h, l;
      split2(v[e], h, l);
      t[r][c0 + j + e] = (u32)h | ((u32)l << 16);
    }
  }
  __syncthreads();
  u16 hb[16], lb[16];
#pragma unroll
  for (int j = 0; j < 16; j++) {
    u32 p = t[c0 + j][r];
    hb[j] = (u16)(p & 0xffffu);
    lb[j] = (u16)(p >> 16);
  }
  size_t off = (size_t)(n0 + r) * K + k0 + c0;
  *(uint4*)(dhi + off)     = *(uint4*)&hb[0];
  *(uint4*)(dhi + off + 8) = *(uint4*)&hb[8];
  *(uint4*)(dlo + off)     = *(uint4*)&lb[0];
  *(uint4*)(dlo + off + 8) = *(uint4*)&lb[8];
}

// ---- direct-fragment helpers (qkv): 16 global b128 loads / 48 MFMAs per K-step
static __device__ __forceinline__ void load16(
    const u16* pAh, const u16* pAl, const u16* pBh, const u16* pBl, int kk,
    s16x8 ah[4], s16x8 al[4], s16x8 bh[4], s16x8 bl[4])
{
#pragma unroll
  for (int mt = 0; mt < 4; mt++) {
    size_t o = (size_t)mt * 12288 + (size_t)kk * 32;   // mt*16 rows, kk*32 cols
    ah[mt] = *(const s16x8*)(pAh + o);
    al[mt] = *(const s16x8*)(pAl + o);
    bh[mt] = *(const s16x8*)(pBh + o);
    bl[mt] = *(const s16x8*)(pBl + o);
  }
}
static __device__ __forceinline__ void mfma48(
    const s16x8 ah[4], const s16x8 al[4], const s16x8 bh[4], const s16x8 bl[4],
    f32x4 acc[4][4])
{
#pragma unroll
  for (int mt = 0; mt < 4; mt++)
#pragma unroll
    for (int nt = 0; nt < 4; nt++) {
      acc[mt][nt] = __builtin_amdgcn_mfma_f32_16x16x32_bf16(ah[mt], bh[nt], acc[mt][nt], 0, 0, 0);
      acc[mt][nt] = __builtin_amdgcn_mfma_f32_16x16x32_bf16(ah[mt], bl[nt], acc[mt][nt], 0, 0, 0);
      acc[mt][nt] = __builtin_amdgcn_mfma_f32_16x16x32_bf16(al[mt], bh[nt], acc[mt][nt], 0, 0, 0);
    }
}

// ---------------- QKV GEMM, barrier-free direct-fragment: -> q fp32 + K/V images
__global__ __launch_bounds__(256, 2) void qkv_mfma_k(
    const u16* __restrict__ xhi, const u16* __restrict__ xlo,
    const u16* __restrict__ bthi, const u16* __restrict__ btlo,
    const float* __restrict__ bias,
    float* __restrict__ qbuf, u16* __restrict__ khi, u16* __restrict__ klo,
    u16* __restrict__ vhi, u16* __restrict__ vlo)
{
  __shared__ __align__(16) u16 img[4][4096];   // epilogue only (wave-private)
  const int tid = threadIdx.x;
  const int lane = tid & 63, wid = tid >> 6;
  const int g = lane >> 4, ql = lane & 15;
  const int wr = wid >> 1, wc = wid & 1;
  const int c0 = blockIdx.x * 128, r0 = blockIdx.y * 128;

  const u16* pAh = xhi  + (size_t)(r0 + wr * 64 + ql) * 768 + g * 8;
  const u16* pAl = xlo  + (size_t)(r0 + wr * 64 + ql) * 768 + g * 8;
  const u16* pBh = bthi + (size_t)(c0 + wc * 64 + ql) * 768 + g * 8;
  const u16* pBl = btlo + (size_t)(c0 + wc * 64 + ql) * 768 + g * 8;

  s16x8 Xah[4], Xal[4], Xbh[4], Xbl[4];
  s16x8 Yah[4], Yal[4], Ybh[4], Ybl[4];
  f32x4 acc[4][4] = {};

  load16(pAh, pAl, pBh, pBl, 0, Xah, Xal, Xbh, Xbl);
  for (int ks = 0; ks < 24; ks += 2) {
    load16(pAh, pAl, pBh, pBl, ks + 1, Yah, Yal, Ybh, Ybl);
    mfma48(Xah, Xal, Xbh, Xbl, acc);
    if (ks + 2 < 24)
      load16(pAh, pAl, pBh, pBl, ks + 2, Xah, Xal, Xbh, Xbl);
    mfma48(Yah, Yal, Ybh, Ybl, acc);
  }

  // ---- epilogue: q fp32 scatter / K,V permuted tile-images via LDS (wave-private)
  const int col0 = c0 + wc * 64;
  const int row0 = r0 + wr * 64;
  const int hb36 = col0 >> 6;
  const int which = hb36 / 12, head = hb36 - (hb36 / 12) * 12;
  const int b = row0 / 2304;
  const int sb = row0 - b * 2304;
  const int bh = b * 12 + head;
  float bb[4];
#pragma unroll
  for (int nt = 0; nt < 4; nt++) bb[nt] = bias[col0 + nt * 16 + ql];
#pragma unroll
  for (int mt = 0; mt < 4; mt++)
#pragma unroll
    for (int nt = 0; nt < 4; nt++)
#pragma unroll
      for (int r = 0; r < 4; r++)
        acc[mt][nt][r] += bb[nt];

  if (which == 0) {
#pragma unroll
    for (int mt = 0; mt < 4; mt++)
#pragma unroll
      for (int nt = 0; nt < 4; nt++)
#pragma unroll
        for (int r = 0; r < 4; r++) {
          int s = sb + mt * 16 + g * 4 + r;
          qbuf[((size_t)bh * SEQ + s) * 64 + nt * 16 + ql] = acc[mt][nt][r];
        }
  } else {
    const int kt = sb >> 6;
    const size_t tile = ((size_t)bh * 36 + kt) * 4096;
    u16* const dsth = (which == 1) ? khi : vhi;
    u16* const dstl = (which == 1) ? klo : vlo;
    u16* const reg = img[wid];
    // pass 1: HI image (wave-private LDS region -> no barriers)
#pragma unroll
    for (int mt = 0; mt < 4; mt++)
#pragma unroll
      for (int nt = 0; nt < 4; nt++) {
        int pcK = (nt >> 1) * 32 + (ql >> 2) * 8 + (nt & 1) * 4 + (ql & 3);
#pragma unroll
        for (int r = 0; r < 4; r++) {
          u16 h, l;
          split2(acc[mt][nt][r], h, l);
          int off = (which == 1)
              ? (mt * 16 + g * 4 + r) * 64 + pcK
              : (nt * 16 + ql) * 64 + (mt >> 1) * 32 + g * 8 + (mt & 1) * 4 + r;
          reg[off] = h;
        }
      }
    {
      const u16* src = reg + lane * 64;
      u16* dst = dsth + tile + lane * 64;
#pragma unroll
      for (int j = 0; j < 8; j++)
        *(uint4*)(dst + j * 8) = *(const uint4*)(src + j * 8);
    }
    // pass 2: LO image
#pragma unroll
    for (int mt = 0; mt < 4; mt++)
#pragma unroll
      for (int nt = 0; nt < 4; nt++) {
        int pcK = (nt >> 1) * 32 + (ql >> 2) * 8 + (nt & 1) * 4 + (ql & 3);
#pragma unroll
        for (int r = 0; r < 4; r++) {
          u16 h, l;
          split2(acc[mt][nt][r], h, l);
          int off = (which == 1)
              ? (mt * 16 + g * 4 + r) * 64 + pcK
              : (nt * 16 + ql) * 64 + (mt >> 1) * 32 + g * 8 + (mt & 1) * 4 + r;
          reg[off] = l;
        }
      }
    {
      const u16* src = reg + lane * 64;
      u16* dst = dstl + tile + lane * 64;
#pragma unroll
      for (int j = 0; j < 8; j++)
        *(uint4*)(dst + j * 8) = *(const uint4*)(src + j * 8);
    }
  }
}

// ---------------- Fused attention (exact r8/r9 known-good, 332 us): 64 q-rows/block,
// 864 blocks, LDS-staged K/V, split-bf16 MFMA, swapped QK^T, online softmax.
// grid(bh=24, qt=36): 24%8==0 -> XCD = bh%8 for all qt (K/V image L2-pinned).
#define BH_OFF 36864                      // Bh: 49 x 66 u16 (row 48 = wrap slack)
#define BW_OFF (BH_OFF + 49*66*2)         // 43332
#define MS_OFF (BW_OFF + 48*66*2)         // 49668
#define LS_OFF (MS_OFF + 256)             // 49924
__global__ __launch_bounds__(512) void attn_k(
    const float* __restrict__ qb,
    const u16* __restrict__ khi, const u16* __restrict__ klo,
    const u16* __restrict__ vhi, const u16* __restrict__ vlo,
    const float* __restrict__ rph, const float* __restrict__ rpw,
    u32* __restrict__ aop)
{
  __shared__ __align__(16) char pool[LS_OFF + 256];
  u16* KhiL = (u16*)pool;              // [64 key][72]
  u16* KloL = (u16*)(pool + 9216);
  u16* VhL  = (u16*)(pool + 18432);    // [64 d][72]
  u16* VlL  = (u16*)(pool + 27648);
  __half* Bh = (__half*)(pool + BH_OFF);  // [49 kh][66 pad]
  __half* Bw = (__half*)(pool + BW_OFF);  // [48 kw][66 pad]
  float* m_s = (float*)(pool + MS_OFF);   // [64]
  float* l_s = (float*)(pool + LS_OFF);   // [64]
  float* qlds = (float*)pool;             // prologue alias [64][68] f32
  float* o_s  = (float*)pool;             // epilogue alias [64][68] f32

  const int tid  = threadIdx.x;
  const int lane = tid & 63;
  const int wid  = tid >> 6;
  const int g    = lane >> 4;
  const int ql   = lane & 15;
  const int wq   = wid & 3;     // q-group: rows [16*wq, 16*wq+16)
  const int hh   = wid >> 2;    // key-half stream
  const int bh   = blockIdx.x;  // 24
  const int qt   = blockIdx.y;  // 36
  const int s0   = qt * 64;

  // ---- stage Q tile fp32 -> LDS
  {
    int row = tid >> 3, c0 = (tid & 7) * 8;
    const float* src = qb + ((size_t)bh * SEQ + s0 + row) * HD + c0;
    f32x4 v0 = *(const f32x4*)src;
    f32x4 v1 = *(const f32x4*)(src + 4);
    *(f32x4*)&qlds[row * 68 + c0]     = v0;
    *(f32x4*)&qlds[row * 68 + c0 + 4] = v1;
  }
  __syncthreads();

  // ---- Q fragments hi/lo (lane's q = 16*wq + ql)
  s16x8 qfh[2], qfl[2];
  {
    int qrow = wq * 16 + ql;
#pragma unroll
    for (int ds = 0; ds < 2; ds++) {
#pragma unroll
      for (int h2 = 0; h2 < 2; h2++) {
        f32x4 qv = *(const f32x4*)&qlds[qrow * 68 + g * 4 + h2 * 16 + ds * 32];
#pragma unroll
        for (int j = 0; j < 4; j++) {
          u16 hi, lo;
          split2(qv[j], hi, lo);
          qfh[ds][h2 * 4 + j] = (short)hi;
          qfl[ds][h2 * 4 + j] = (short)lo;
        }
      }
    }
  }

  // ---- prefetch tile 0
  const size_t tbK = (size_t)bh * 36 * 4096;
  const int srow = tid >> 3;
  const int sch  = ((tid & 7) - (srow & 7)) & 7;
  const size_t soff = (size_t)srow * 64 + sch * 8;
  uint4 rkh = *(const uint4*)(khi + tbK + soff);
  uint4 rkl = *(const uint4*)(klo + tbK + soff);
  uint4 rvh = *(const uint4*)(vhi + tbK + soff);
  uint4 rvl = *(const uint4*)(vlo + tbK + soff);

  // ---- decomposed rel-pos bias tables (fp16, stride 66)
  for (int i = tid; i < 64 * 96; i += 512) {
    int q = i / 96, j = i - (i / 96) * 96;
    int s = s0 + q;
    int qhg = s / 48, qw = s - qhg * 48;
    const float* tab;
    int ridx, col;
    if (j < 48) { col = j;      ridx = qhg - j + 47;        tab = rph; }
    else        { col = j - 48; ridx = qw - (j - 48) + 47;  tab = rpw; }
    const float* rp = tab + (size_t)ridx * HD;
    const float* qp = &qlds[q * 68];
    float s1 = 0.f;
#pragma unroll 4
    for (int d = 0; d < 64; d += 4) {
      f32x4 a = *(const f32x4*)(qp + d);
      f32x4 bv = *(const f32x4*)(rp + d);
      s1 += a[0]*bv[0] + a[1]*bv[1] + a[2]*bv[2] + a[3]*bv[3];
    }
    if (j < 48) Bh[col * 66 + q] = __float2half_rn(s1);
    else        Bw[col * 66 + q] = __float2half_rn(s1);
  }

  float m_r = -3.0e38f, l_r = 0.f;
  f32x4 oacc[4] = {};   // O[q = 4g+r][d = ql + 16*dt]
  const int q64b = wq * 16 + ql;

  for (int kt = 0; kt < 36; kt++) {
    __syncthreads();
    *(uint4*)(KhiL + srow * 72 + sch * 8) = rkh;
    *(uint4*)(KloL + srow * 72 + sch * 8) = rkl;
    *(uint4*)(VhL  + srow * 72 + sch * 8) = rvh;
    *(uint4*)(VlL  + srow * 72 + sch * 8) = rvl;
    __syncthreads();
    if (kt < 35) {     // T14: issue next-tile loads; land under MFMA phase
      size_t tb = tbK + (size_t)(kt + 1) * 4096;
      rkh = *(const uint4*)(khi + tb + soff);
      rkl = *(const uint4*)(klo + tb + soff);
      rvh = *(const uint4*)(vhi + tb + soff);
      rvl = *(const uint4*)(vlo + tb + soff);
    }

    // ---- QK^T (swapped): S^T[key][q]
    f32x4 sacc[2] = {};
    __builtin_amdgcn_s_setprio(1);
#pragma unroll
    for (int ds = 0; ds < 2; ds++) {
#pragma unroll
      for (int t2 = 0; t2 < 2; t2++) {
        int row = (hh * 2 + t2) * 16 + ql;
        s16x8 af = *(const s16x8*)(KhiL + row * 72 + ds * 32 + g * 8);
        s16x8 al = *(const s16x8*)(KloL + row * 72 + ds * 32 + g * 8);
        sacc[t2] = __builtin_amdgcn_mfma_f32_16x16x32_bf16(af, qfh[ds], sacc[t2], 0, 0, 0);
        sacc[t2] = __builtin_amdgcn_mfma_f32_16x16x32_bf16(af, qfl[ds], sacc[t2], 0, 0, 0);
        sacc[t2] = __builtin_amdgcn_mfma_f32_16x16x32_bf16(al, qfh[ds], sacc[t2], 0, 0, 0);
      }
    }
    __builtin_amdgcn_s_setprio(0);

    // ---- bias gather: kh in {kh0,kh0+1} within a half-tile
    u32 kg0 = (u32)(kt * 64 + hh * 32);
    u32 kh0 = kg0 / 48u;
    int kw0 = (int)(kg0 - kh0 * 48u);
    float bh0 = __half2float(Bh[kh0 * 66 + q64b]);
    float bh1 = __half2float(Bh[(kh0 + 1) * 66 + q64b]);
    float lg[8];
    float tmax = -3.0e38f;
#pragma unroll
    for (int t2 = 0; t2 < 2; t2++)
#pragma unroll
      for (int r = 0; r < 4; r++) {
        int j = t2 * 4 + r;
        int w = kw0 + t2 * 16 + g * 4 + r;
        bool wrap = w >= 48;
        float bw = __half2float(Bw[(wrap ? w - 48 : w) * 66 + q64b]);
        float x = sacc[t2][r] * 0.125f + (wrap ? bh1 : bh0) + bw;
        lg[j] = x;
        tmax = fmaxf(tmax, x);
      }
    tmax = fmaxf(tmax, __shfl_xor(tmax, 16));
    tmax = fmaxf(tmax, __shfl_xor(tmax, 32));
    if (__any(tmax > m_r + 6.0f)) {   // T13 defer-max
      float mnew = fmaxf(m_r, tmax);
      float corr = __expf(m_r - mnew);
      l_r *= corr;
      m_r = mnew;
      float cq[4];
#pragma unroll
      for (int r = 0; r < 4; r++) cq[r] = __shfl(corr, g * 4 + r);
#pragma unroll
      for (int dt = 0; dt < 4; dt++)
#pragma unroll
        for (int r = 0; r < 4; r++) oacc[dt][r] *= cq[r];
    }
    float psum = 0.f;
    s16x8 pfh, pfl;
#pragma unroll
    for (int j = 0; j < 8; j++) {
      float p = __expf(lg[j] - m_r);
      psum += p;
      u16 hi, lo;
      split2(p, hi, lo);
      pfh[j] = (short)hi;
      pfl[j] = (short)lo;
    }
    psum += __shfl_xor(psum, 16);
    psum += __shfl_xor(psum, 32);
    l_r += psum;

    // ---- PV
    __builtin_amdgcn_s_setprio(1);
#pragma unroll
    for (int dt = 0; dt < 4; dt++) {
      int row = ql + 16 * dt;
      s16x8 bhf = *(const s16x8*)(VhL + row * 72 + hh * 32 + g * 8);
      s16x8 blf = *(const s16x8*)(VlL + row * 72 + hh * 32 + g * 8);
      oacc[dt] = __builtin_amdgcn_mfma_f32_16x16x32_bf16(pfh, bhf, oacc[dt], 0, 0, 0);
      oacc[dt] = __builtin_amdgcn_mfma_f32_16x16x32_bf16(pfh, blf, oacc[dt], 0, 0, 0);
      oacc[dt] = __builtin_amdgcn_mfma_f32_16x16x32_bf16(pfl, bhf, oacc[dt], 0, 0, 0);
    }
    __builtin_amdgcn_s_setprio(0);
  }

  // ---- merge the two key-streams per q-group, write out (packed u32 hi|lo)
  __syncthreads();
  if (hh == 1) {
    if (g == 0) { m_s[q64b] = m_r; l_s[q64b] = l_r; }
#pragma unroll
    for (int dt = 0; dt < 4; dt++)
#pragma unroll
      for (int r = 0; r < 4; r++)
        o_s[(wq * 16 + g * 4 + r) * 68 + ql + 16 * dt] = oacc[dt][r];
  }
  __syncthreads();
  if (hh == 0) {
    float m2 = m_s[q64b];
    float l2 = l_s[q64b];
    float mf = fmaxf(m_r, m2);
    float c1 = __expf(m_r - mf);
    float c2 = __expf(m2 - mf);
    float lf = l_r * c1 + l2 * c2;
    float c1q[4], c2q[4], lfq[4];
#pragma unroll
    for (int r = 0; r < 4; r++) {
      c1q[r] = __shfl(c1, g * 4 + r);
      c2q[r] = __shfl(c2, g * 4 + r);
      lfq[r] = __shfl(lf, g * 4 + r);
    }
    const int b = bh / 12, head = bh - (bh / 12) * 12;
#pragma unroll
    for (int dt = 0; dt < 4; dt++)
#pragma unroll
      for (int r = 0; r < 4; r++) {
        float oo = oacc[dt][r] * c1q[r]
                 + o_s[(wq * 16 + g * 4 + r) * 68 + ql + 16 * dt] * c2q[r];
        float on = oo / lfq[r];
        int s = s0 + wq * 16 + g * 4 + r;
        size_t idx = ((size_t)b * SEQ + s) * 768 + head * 64 + ql + 16 * dt;
        u16 h, l;
        split2(on, h, l);
        aop[idx] = (u32)h | ((u32)l << 16);
      }
  }
}

// ---------------- proj GEMM via split-bf16 MFMA (A = packed u32 hi|lo): -> out
__global__ __launch_bounds__(256) void proj_mfma_k(
    const u32* __restrict__ aop,
    const u16* __restrict__ bthi, const u16* __restrict__ btlo,
    const float* __restrict__ bias, float* __restrict__ out)
{
  __shared__ __align__(16) u16 Ah[128*40], Al[128*40], Bh2[128*40], Bl2[128*40];
  const int tid = threadIdx.x;
  const int lane = tid & 63, wid = tid >> 6;
  const int g = lane >> 4, ql = lane & 15;
  const int wr = wid >> 1, wc = wid & 1;
  const int c0 = blockIdx.x * 128, r0 = blockIdx.y * 128;
  const int srow = tid >> 1, half = tid & 1;

  const u32* ag = aop + (size_t)(r0 + srow) * 768 + half * 16;
  const u16* bgh = bthi + (size_t)(c0 + srow) * 768 + half * 16;
  const u16* bgl = btlo + (size_t)(c0 + srow) * 768 + half * 16;

  uint4 paw[4]; uint4 pbh[2], pbl[2];
#pragma unroll
  for (int j = 0; j < 4; j++) paw[j] = *(const uint4*)(ag + j * 4);
  pbh[0] = *(const uint4*)bgh; pbh[1] = *(const uint4*)(bgh + 8);
  pbl[0] = *(const uint4*)bgl; pbl[1] = *(const uint4*)(bgl + 8);

  f32x4 acc[4][4] = {};

  for (int ks = 0; ks < 24; ks++) {
    __syncthreads();
    {
      u16 hb[16], lb[16];
      const u32* pw = (const u32*)&paw[0];
#pragma unroll
      for (int j = 0; j < 16; j++) {
        hb[j] = (u16)(pw[j] & 0xffffu);
        lb[j] = (u16)(pw[j] >> 16);
      }
      u16* d1 = Ah + srow * 40 + half * 16;
      u16* d2 = Al + srow * 40 + half * 16;
      u16* d3 = Bh2 + srow * 40 + half * 16;
      u16* d4 = Bl2 + srow * 40 + half * 16;
      *(uint4*)d1 = *(uint4*)&hb[0]; *(uint4*)(d1 + 8) = *(uint4*)&hb[8];
      *(uint4*)d2 = *(uint4*)&lb[0]; *(uint4*)(d2 + 8) = *(uint4*)&lb[8];
      *(uint4*)d3 = pbh[0]; *(uint4*)(d3 + 8) = pbh[1];
      *(uint4*)d4 = pbl[0]; *(uint4*)(d4 + 8) = pbl[1];
    }
    __syncthreads();
    if (ks < 23) {
      const int o = (ks + 1) * 32;
#pragma unroll
      for (int j = 0; j < 4; j++) paw[j] = *(const uint4*)(ag + o + j * 4);
      pbh[0] = *(const uint4*)(bgh + o); pbh[1] = *(const uint4*)(bgh + o + 8);
      pbl[0] = *(const uint4*)(bgl + o); pbl[1] = *(const uint4*)(bgl + o + 8);
    }
    s16x8 bfh[4], bfl[4];
#pragma unroll
    for (int nt = 0; nt < 4; nt++) {
      bfh[nt] = *(const s16x8*)(Bh2 + (wc * 64 + nt * 16 + ql) * 40 + g * 8);
      bfl[nt] = *(const s16x8*)(Bl2 + (wc * 64 + nt * 16 + ql) * 40 + g * 8);
    }
#pragma unroll
    for (int mt = 0; mt < 4; mt++) {
      s16x8 ah = *(const s16x8*)(Ah + (wr * 64 + mt * 16 + ql) * 40 + g * 8);
      s16x8 al = *(const s16x8*)(Al + (wr * 64 + mt * 16 + ql) * 40 + g * 8);
#pragma unroll
      for (int nt = 0; nt < 4; nt++) {
        acc[mt][nt] = __builtin_amdgcn_mfma_f32_16x16x32_bf16(ah, bfh[nt], acc[mt][nt], 0, 0, 0);
        acc[mt][nt] = __builtin_amdgcn_mfma_f32_16x16x32_bf16(ah, bfl[nt], acc[mt][nt], 0, 0, 0);
        acc[mt][nt] = __builtin_amdgcn_mfma_f32_16x16x32_bf16(al, bfh[nt], acc[mt][nt], 0, 0, 0);
      }
    }
  }
  const int col0 = c0 + wc * 64;
  const int row0 = r0 + wr * 64;
  float bb[4];
#pragma unroll
  for (int nt = 0; nt < 4; nt++) bb[nt] = bias[col0 + nt * 16 + ql];
#pragma unroll
  for (int mt = 0; mt < 4; mt++)
#pragma unroll
    for (int nt = 0; nt < 4; nt++)
#pragma unroll
      for (int r = 0; r < 4; r++)
        out[(size_t)(row0 + mt * 16 + g * 4 + r) * 768 + col0 + nt * 16 + ql] =
            acc[mt][nt][r] + bb[nt];
}

extern "C" void kernel_launch(void* const* d_in, const int* in_sizes, int n_in,
                              void* d_out, int out_size, void* d_ws, size_t ws_size,
                              hipStream_t stream) {
  const float* x      = (const float*)d_in[0];
  const float* qkv_w  = (const float*)d_in[1];
  const float* qkv_b  = (const float*)d_in[2];
  const float* proj_w = (const float*)d_in[3];
  const float* proj_b = (const float*)d_in[4];
  const float* rph    = (const float*)d_in[5];
  const float* rpw    = (const float*)d_in[6];
  float* out = (float*)d_out;
  float* ws  = (float*)d_ws;

  const size_t SZ = (size_t)24 * SEQ * HD;   // 3,538,944 elems (== 4608*768)
  float* qbuf = ws;                          // SZ f32
  u16* khi = (u16*)(ws + SZ);                // 4 x SZ u16
  u16* klo = khi + SZ;
  u16* vhi = klo + SZ;
  u16* vlo = vhi + SZ;
  u16* xhi = (u16*)(ws + 3 * SZ);            // 2 x SZ u16
  u16* xlo = xhi + SZ;
  u32* aop = (u32*)(ws + 4 * SZ);            // SZ u32 (packed hi|lo)
  u16* wqThi = (u16*)(ws + 5 * SZ);          // 768*2304 x2
  u16* wqTlo = wqThi + 768 * 2304;
  u16* wpThi = wqTlo + 768 * 2304;           // 768*768 x2
  u16* wpTlo = wpThi + 768 * 768;

  conv_split_k<<<1728, 256, 0, stream>>>(x, xhi, xlo);
  conv_wT_k <<<dim3(36, 12), 256, 0, stream>>>(qkv_w, wqThi, wqTlo, 768, 2304);
  conv_wT_k <<<dim3(12, 12), 256, 0, stream>>>(proj_w, wpThi, wpTlo, 768, 768);
  qkv_mfma_k<<<dim3(18, 36), 256, 0, stream>>>(xhi, xlo, wqThi, wqTlo, qkv_b,
                                               qbuf, khi, klo, vhi, vlo);
  attn_k    <<<dim3(24, 36), 512, 0, stream>>>(qbuf, khi, klo, vhi, vlo, rph, rpw, aop);
  proj_mfma_k<<<dim3(6, 36), 256, 0, stream>>>(aop, wpThi, wpTlo, proj_b, out);
}

// Round 13
// 482.679 us; speedup vs baseline: 1.3989x; 1.0488x over previous
//
#include <hip/hip_runtime.h>
#include <hip/hip_fp16.h>

#define HD 64
#define SEQ 2304

typedef unsigned short u16;
typedef unsigned int u32;
using f32x4 = __attribute__((ext_vector_type(4))) float;
using s16x8 = __attribute__((ext_vector_type(8))) short;

static __device__ __forceinline__ float bf2f(u16 h) {
  union { float f; u32 u; } a; a.u = ((u32)h) << 16; return a.f;
}
// truncation split: x ~= hi + lo, |err| ~ 2^-16 |x|
static __device__ __forceinline__ void split2(float x, u16& h, u16& l) {
  u32 u = __float_as_uint(x);
  h = (u16)(u >> 16);
  float r = x - __uint_as_float(u & 0xffff0000u);
  l = (u16)(__float_as_uint(r) >> 16);
}
// round-to-nearest-even bf16 (unbiased: used for V which is consumed hi-only)
static __device__ __forceinline__ u16 rne_bf16(float x) {
  u32 u = __float_as_uint(x);
  return (u16)((u + 0x7fffu + ((u >> 16) & 1u)) >> 16);
}

// ---------------- split fp32 -> bf16 hi/lo, 8 elems/thread
__global__ __launch_bounds__(256) void conv_split_k(
    const float* __restrict__ src, u16* __restrict__ dhi, u16* __restrict__ dlo)
{
  const size_t i = ((size_t)blockIdx.x * 256 + threadIdx.x) * 8;
  f32x4 a = *(const f32x4*)(src + i);
  f32x4 b = *(const f32x4*)(src + i + 4);
  u16 h[8], l[8];
#pragma unroll
  for (int j = 0; j < 8; j++) {
    float x = j < 4 ? a[j] : b[j - 4];
    split2(x, h[j], l[j]);
  }
  *(uint4*)(dhi + i) = *(uint4*)&h[0];
  *(uint4*)(dlo + i) = *(uint4*)&l[0];
}

// ---------------- convert + transpose weights: w[K][N] f32 -> wT[N][K] bf16 hi/lo
__global__ __launch_bounds__(256) void conv_wT_k(
    const float* __restrict__ src, u16* __restrict__ dhi, u16* __restrict__ dlo,
    int K, int N)
{
  __shared__ u32 t[64][65];
  const int tid = threadIdx.x;
  const int n0 = blockIdx.x * 64, k0 = blockIdx.y * 64;
  const int r = tid >> 2, c0 = (tid & 3) * 16;
  const float* sp = src + (size_t)(k0 + r) * N + n0 + c0;
#pragma unroll
  for (int j = 0; j < 16; j += 4) {
    f32x4 v = *(const f32x4*)(sp + j);
#pragma unroll
    for (int e = 0; e < 4; e++) {
      u16 h, l;
      split2(v[e], h, l);
      t[r][c0 + j + e] = (u32)h | ((u32)l << 16);
    }
  }
  __syncthreads();
  u16 hb[16], lb[16];
#pragma unroll
  for (int j = 0; j < 16; j++) {
    u32 p = t[c0 + j][r];
    hb[j] = (u16)(p & 0xffffu);
    lb[j] = (u16)(p >> 16);
  }
  size_t off = (size_t)(n0 + r) * K + k0 + c0;
  *(uint4*)(dhi + off)     = *(uint4*)&hb[0];
  *(uint4*)(dhi + off + 8) = *(uint4*)&hb[8];
  *(uint4*)(dlo + off)     = *(uint4*)&lb[0];
  *(uint4*)(dlo + off + 8) = *(uint4*)&lb[8];
}

// ---- direct-fragment helpers (qkv): 16 global b128 loads / 48 MFMAs per K-step
static __device__ __forceinline__ void load16(
    const u16* pAh, const u16* pAl, const u16* pBh, const u16* pBl, int kk,
    s16x8 ah[4], s16x8 al[4], s16x8 bh[4], s16x8 bl[4])
{
#pragma unroll
  for (int mt = 0; mt < 4; mt++) {
    size_t o = (size_t)mt * 12288 + (size_t)kk * 32;   // mt*16 rows, kk*32 cols
    ah[mt] = *(const s16x8*)(pAh + o);
    al[mt] = *(const s16x8*)(pAl + o);
    bh[mt] = *(const s16x8*)(pBh + o);
    bl[mt] = *(const s16x8*)(pBl + o);
  }
}
static __device__ __forceinline__ void mfma48(
    const s16x8 ah[4], const s16x8 al[4], const s16x8 bh[4], const s16x8 bl[4],
    f32x4 acc[4][4])
{
#pragma unroll
  for (int mt = 0; mt < 4; mt++)
#pragma unroll
    for (int nt = 0; nt < 4; nt++) {
      acc[mt][nt] = __builtin_amdgcn_mfma_f32_16x16x32_bf16(ah[mt], bh[nt], acc[mt][nt], 0, 0, 0);
      acc[mt][nt] = __builtin_amdgcn_mfma_f32_16x16x32_bf16(ah[mt], bl[nt], acc[mt][nt], 0, 0, 0);
      acc[mt][nt] = __builtin_amdgcn_mfma_f32_16x16x32_bf16(al[mt], bh[nt], acc[mt][nt], 0, 0, 0);
    }
}

// ---------------- QKV GEMM, barrier-free direct-fragment: -> q fp32 + K (hi/lo) +
// V (single RNE bf16) images
__global__ __launch_bounds__(256, 2) void qkv_mfma_k(
    const u16* __restrict__ xhi, const u16* __restrict__ xlo,
    const u16* __restrict__ bthi, const u16* __restrict__ btlo,
    const float* __restrict__ bias,
    float* __restrict__ qbuf, u16* __restrict__ khi, u16* __restrict__ klo,
    u16* __restrict__ vhi)
{
  __shared__ __align__(16) u16 img[4][4096];   // epilogue only (wave-private)
  const int tid = threadIdx.x;
  const int lane = tid & 63, wid = tid >> 6;
  const int g = lane >> 4, ql = lane & 15;
  const int wr = wid >> 1, wc = wid & 1;
  const int c0 = blockIdx.x * 128, r0 = blockIdx.y * 128;

  const u16* pAh = xhi  + (size_t)(r0 + wr * 64 + ql) * 768 + g * 8;
  const u16* pAl = xlo  + (size_t)(r0 + wr * 64 + ql) * 768 + g * 8;
  const u16* pBh = bthi + (size_t)(c0 + wc * 64 + ql) * 768 + g * 8;
  const u16* pBl = btlo + (size_t)(c0 + wc * 64 + ql) * 768 + g * 8;

  s16x8 Xah[4], Xal[4], Xbh[4], Xbl[4];
  s16x8 Yah[4], Yal[4], Ybh[4], Ybl[4];
  f32x4 acc[4][4] = {};

  load16(pAh, pAl, pBh, pBl, 0, Xah, Xal, Xbh, Xbl);
  for (int ks = 0; ks < 24; ks += 2) {
    load16(pAh, pAl, pBh, pBl, ks + 1, Yah, Yal, Ybh, Ybl);
    mfma48(Xah, Xal, Xbh, Xbl, acc);
    if (ks + 2 < 24)
      load16(pAh, pAl, pBh, pBl, ks + 2, Xah, Xal, Xbh, Xbl);
    mfma48(Yah, Yal, Ybh, Ybl, acc);
  }

  // ---- epilogue: q fp32 scatter / K,V permuted tile-images via LDS (wave-private)
  const int col0 = c0 + wc * 64;
  const int row0 = r0 + wr * 64;
  const int hb36 = col0 >> 6;
  const int which = hb36 / 12, head = hb36 - (hb36 / 12) * 12;
  const int b = row0 / 2304;
  const int sb = row0 - b * 2304;
  const int bh = b * 12 + head;
  float bb[4];
#pragma unroll
  for (int nt = 0; nt < 4; nt++) bb[nt] = bias[col0 + nt * 16 + ql];
#pragma unroll
  for (int mt = 0; mt < 4; mt++)
#pragma unroll
    for (int nt = 0; nt < 4; nt++)
#pragma unroll
      for (int r = 0; r < 4; r++)
        acc[mt][nt][r] += bb[nt];

  if (which == 0) {
#pragma unroll
    for (int mt = 0; mt < 4; mt++)
#pragma unroll
      for (int nt = 0; nt < 4; nt++)
#pragma unroll
        for (int r = 0; r < 4; r++) {
          int s = sb + mt * 16 + g * 4 + r;
          qbuf[((size_t)bh * SEQ + s) * 64 + nt * 16 + ql] = acc[mt][nt][r];
        }
  } else if (which == 1) {
    const int kt = sb >> 6;
    const size_t tile = ((size_t)bh * 36 + kt) * 4096;
    u16* const reg = img[wid];
    // pass 1: HI
#pragma unroll
    for (int mt = 0; mt < 4; mt++)
#pragma unroll
      for (int nt = 0; nt < 4; nt++) {
        int pcK = (nt >> 1) * 32 + (ql >> 2) * 8 + (nt & 1) * 4 + (ql & 3);
#pragma unroll
        for (int r = 0; r < 4; r++) {
          u16 h, l;
          split2(acc[mt][nt][r], h, l);
          reg[(mt * 16 + g * 4 + r) * 64 + pcK] = h;
        }
      }
    {
      const u16* src = reg + lane * 64;
      u16* dst = khi + tile + lane * 64;
#pragma unroll
      for (int j = 0; j < 8; j++)
        *(uint4*)(dst + j * 8) = *(const uint4*)(src + j * 8);
    }
    // pass 2: LO
#pragma unroll
    for (int mt = 0; mt < 4; mt++)
#pragma unroll
      for (int nt = 0; nt < 4; nt++) {
        int pcK = (nt >> 1) * 32 + (ql >> 2) * 8 + (nt & 1) * 4 + (ql & 3);
#pragma unroll
        for (int r = 0; r < 4; r++) {
          u16 h, l;
          split2(acc[mt][nt][r], h, l);
          reg[(mt * 16 + g * 4 + r) * 64 + pcK] = l;
        }
      }
    {
      const u16* src = reg + lane * 64;
      u16* dst = klo + tile + lane * 64;
#pragma unroll
      for (int j = 0; j < 8; j++)
        *(uint4*)(dst + j * 8) = *(const uint4*)(src + j * 8);
    }
  } else {
    // V image: single pass, RNE bf16 (consumed hi-only; RNE kills truncation bias)
    const int kt = sb >> 6;
    const size_t tile = ((size_t)bh * 36 + kt) * 4096;
    u16* const reg = img[wid];
#pragma unroll
    for (int mt = 0; mt < 4; mt++)
#pragma unroll
      for (int nt = 0; nt < 4; nt++)
#pragma unroll
        for (int r = 0; r < 4; r++) {
          int off = (nt * 16 + ql) * 64 + (mt >> 1) * 32 + g * 8 + (mt & 1) * 4 + r;
          reg[off] = rne_bf16(acc[mt][nt][r]);
        }
    {
      const u16* src = reg + lane * 64;
      u16* dst = vhi + tile + lane * 64;
#pragma unroll
      for (int j = 0; j < 8; j++)
        *(uint4*)(dst + j * 8) = *(const uint4*)(src + j * 8);
    }
  }
}

// ---------------- Fused attention: 64 q-rows/block, 864 blocks, LDS-staged K (hi/lo)
// + V (single bf16), split QK^T (3 MFMA), single-MFMA PV (error ~1e-4: random-signed
// rounding averages out under softmax weights). LDS 40.8KB -> 4 blocks/CU.
// grid(bh=24, qt=36): 24%8==0 -> XCD = bh%8 for all qt (K/V image L2-pinned).
#define BH_OFF 27648                      // Bh: 49 x 65 u16 (row 48 = wrap slack)
#define BW_OFF (BH_OFF + 49*65*2)         // 34018 -> align: 34020
#define BW_OFFA 34020
#define MS_OFF (BW_OFFA + 48*65*2)        // 40260
#define LS_OFF (MS_OFF + 256)             // 40516
__global__ __launch_bounds__(512) void attn_k(
    const float* __restrict__ qb,
    const u16* __restrict__ khi, const u16* __restrict__ klo,
    const u16* __restrict__ vhi,
    const float* __restrict__ rph, const float* __restrict__ rpw,
    u32* __restrict__ aop)
{
  __shared__ __align__(16) char pool[LS_OFF + 256];   // 40772 B
  u16* KhiL = (u16*)pool;              // [64 key][72]
  u16* KloL = (u16*)(pool + 9216);
  u16* VhL  = (u16*)(pool + 18432);    // [64 d][72]
  __half* Bh = (__half*)(pool + BH_OFF);   // [49 kh][65 pad]
  __half* Bw = (__half*)(pool + BW_OFFA);  // [48 kw][65 pad]
  float* m_s = (float*)(pool + MS_OFF);    // [64]
  float* l_s = (float*)(pool + LS_OFF);    // [64]
  float* qlds = (float*)pool;              // prologue alias [64][68] f32 (17408B)
  float* o_s  = (float*)pool;              // epilogue alias [64][68] f32

  const int tid  = threadIdx.x;
  const int lane = tid & 63;
  const int wid  = tid >> 6;
  const int g    = lane >> 4;
  const int ql   = lane & 15;
  const int wq   = wid & 3;     // q-group: rows [16*wq, 16*wq+16)
  const int hh   = wid >> 2;    // key-half stream
  const int bh   = blockIdx.x;  // 24
  const int qt   = blockIdx.y;  // 36
  const int s0   = qt * 64;

  // ---- stage Q tile fp32 -> LDS
  {
    int row = tid >> 3, c0 = (tid & 7) * 8;
    const float* src = qb + ((size_t)bh * SEQ + s0 + row) * HD + c0;
    f32x4 v0 = *(const f32x4*)src;
    f32x4 v1 = *(const f32x4*)(src + 4);
    *(f32x4*)&qlds[row * 68 + c0]     = v0;
    *(f32x4*)&qlds[row * 68 + c0 + 4] = v1;
  }
  __syncthreads();

  // ---- Q fragments hi/lo (lane's q = 16*wq + ql)
  s16x8 qfh[2], qfl[2];
  {
    int qrow = wq * 16 + ql;
#pragma unroll
    for (int ds = 0; ds < 2; ds++) {
#pragma unroll
      for (int h2 = 0; h2 < 2; h2++) {
        f32x4 qv = *(const f32x4*)&qlds[qrow * 68 + g * 4 + h2 * 16 + ds * 32];
#pragma unroll
        for (int j = 0; j < 4; j++) {
          u16 hi, lo;
          split2(qv[j], hi, lo);
          qfh[ds][h2 * 4 + j] = (short)hi;
          qfl[ds][h2 * 4 + j] = (short)lo;
        }
      }
    }
  }

  // ---- prefetch tile 0
  const size_t tbK = (size_t)bh * 36 * 4096;
  const int srow = tid >> 3;
  const int sch  = ((tid & 7) - (srow & 7)) & 7;
  const size_t soff = (size_t)srow * 64 + sch * 8;
  uint4 rkh = *(const uint4*)(khi + tbK + soff);
  uint4 rkl = *(const uint4*)(klo + tbK + soff);
  uint4 rvh = *(const uint4*)(vhi + tbK + soff);

  // ---- decomposed rel-pos bias tables (fp16, stride 65)
  for (int i = tid; i < 64 * 96; i += 512) {
    int q = i / 96, j = i - (i / 96) * 96;
    int s = s0 + q;
    int qhg = s / 48, qw = s - qhg * 48;
    const float* tab;
    int ridx, col;
    if (j < 48) { col = j;      ridx = qhg - j + 47;        tab = rph; }
    else        { col = j - 48; ridx = qw - (j - 48) + 47;  tab = rpw; }
    const float* rp = tab + (size_t)ridx * HD;
    const float* qp = &qlds[q * 68];
    float s1 = 0.f;
#pragma unroll 4
    for (int d = 0; d < 64; d += 4) {
      f32x4 a = *(const f32x4*)(qp + d);
      f32x4 bv = *(const f32x4*)(rp + d);
      s1 += a[0]*bv[0] + a[1]*bv[1] + a[2]*bv[2] + a[3]*bv[3];
    }
    if (j < 48) Bh[col * 65 + q] = __float2half_rn(s1);
    else        Bw[col * 65 + q] = __float2half_rn(s1);
  }

  float m_r = -3.0e38f, l_r = 0.f;
  f32x4 oacc[4] = {};   // O[q = 4g+r][d = ql + 16*dt]
  const int q64b = wq * 16 + ql;

  for (int kt = 0; kt < 36; kt++) {
    __syncthreads();
    *(uint4*)(KhiL + srow * 72 + sch * 8) = rkh;
    *(uint4*)(KloL + srow * 72 + sch * 8) = rkl;
    *(uint4*)(VhL  + srow * 72 + sch * 8) = rvh;
    __syncthreads();
    if (kt < 35) {     // T14: issue next-tile loads; land under MFMA phase
      size_t tb = tbK + (size_t)(kt + 1) * 4096;
      rkh = *(const uint4*)(khi + tb + soff);
      rkl = *(const uint4*)(klo + tb + soff);
      rvh = *(const uint4*)(vhi + tb + soff);
    }

    // ---- QK^T (swapped): S^T[key][q]
    f32x4 sacc[2] = {};
    __builtin_amdgcn_s_setprio(1);
#pragma unroll
    for (int ds = 0; ds < 2; ds++) {
#pragma unroll
      for (int t2 = 0; t2 < 2; t2++) {
        int row = (hh * 2 + t2) * 16 + ql;
        s16x8 af = *(const s16x8*)(KhiL + row * 72 + ds * 32 + g * 8);
        s16x8 al = *(const s16x8*)(KloL + row * 72 + ds * 32 + g * 8);
        sacc[t2] = __builtin_amdgcn_mfma_f32_16x16x32_bf16(af, qfh[ds], sacc[t2], 0, 0, 0);
        sacc[t2] = __builtin_amdgcn_mfma_f32_16x16x32_bf16(af, qfl[ds], sacc[t2], 0, 0, 0);
        sacc[t2] = __builtin_amdgcn_mfma_f32_16x16x32_bf16(al, qfh[ds], sacc[t2], 0, 0, 0);
      }
    }
    __builtin_amdgcn_s_setprio(0);

    // ---- bias gather: kh in {kh0,kh0+1} within a half-tile
    u32 kg0 = (u32)(kt * 64 + hh * 32);
    u32 kh0 = kg0 / 48u;
    int kw0 = (int)(kg0 - kh0 * 48u);
    float bh0 = __half2float(Bh[kh0 * 65 + q64b]);
    float bh1 = __half2float(Bh[(kh0 + 1) * 65 + q64b]);
    float lg[8];
    float tmax = -3.0e38f;
#pragma unroll
    for (int t2 = 0; t2 < 2; t2++)
#pragma unroll
      for (int r = 0; r < 4; r++) {
        int j = t2 * 4 + r;
        int w = kw0 + t2 * 16 + g * 4 + r;
        bool wrap = w >= 48;
        float bw = __half2float(Bw[(wrap ? w - 48 : w) * 65 + q64b]);
        float x = sacc[t2][r] * 0.125f + (wrap ? bh1 : bh0) + bw;
        lg[j] = x;
        tmax = fmaxf(tmax, x);
      }
    tmax = fmaxf(tmax, __shfl_xor(tmax, 16));
    tmax = fmaxf(tmax, __shfl_xor(tmax, 32));
    if (__any(tmax > m_r + 6.0f)) {   // T13 defer-max
      float mnew = fmaxf(m_r, tmax);
      float corr = __expf(m_r - mnew);
      l_r *= corr;
      m_r = mnew;
      float cq[4];
#pragma unroll
      for (int r = 0; r < 4; r++) cq[r] = __shfl(corr, g * 4 + r);
#pragma unroll
      for (int dt = 0; dt < 4; dt++)
#pragma unroll
        for (int r = 0; r < 4; r++) oacc[dt][r] *= cq[r];
    }
    float psum = 0.f;
    s16x8 pfh;
#pragma unroll
    for (int j = 0; j < 8; j++) {
      float p = __expf(lg[j] - m_r);
      psum += p;
      // truncation-to-bf16 of P: bias cancels in O/l (both scale together)
      pfh[j] = (short)(u16)(__float_as_uint(p) >> 16);
    }
    psum += __shfl_xor(psum, 16);
    psum += __shfl_xor(psum, 32);
    l_r += psum;

    // ---- PV: single MFMA per dt (P,V hi-only; random-signed rounding ~1e-4 in O/l)
    __builtin_amdgcn_s_setprio(1);
#pragma unroll
    for (int dt = 0; dt < 4; dt++) {
      int row = ql + 16 * dt;
      s16x8 bhf = *(const s16x8*)(VhL + row * 72 + hh * 32 + g * 8);
      oacc[dt] = __builtin_amdgcn_mfma_f32_16x16x32_bf16(pfh, bhf, oacc[dt], 0, 0, 0);
    }
    __builtin_amdgcn_s_setprio(0);
  }

  // ---- merge the two key-streams per q-group, write out (packed u32 hi|lo)
  __syncthreads();
  if (hh == 1) {
    if (g == 0) { m_s[q64b] = m_r; l_s[q64b] = l_r; }
#pragma unroll
    for (int dt = 0; dt < 4; dt++)
#pragma unroll
      for (int r = 0; r < 4; r++)
        o_s[(wq * 16 + g * 4 + r) * 68 + ql + 16 * dt] = oacc[dt][r];
  }
  __syncthreads();
  if (hh == 0) {
    float m2 = m_s[q64b];
    float l2 = l_s[q64b];
    float mf = fmaxf(m_r, m2);
    float c1 = __expf(m_r - mf);
    float c2 = __expf(m2 - mf);
    float lf = l_r * c1 + l2 * c2;
    float c1q[4], c2q[4], lfq[4];
#pragma unroll
    for (int r = 0; r < 4; r++) {
      c1q[r] = __shfl(c1, g * 4 + r);
      c2q[r] = __shfl(c2, g * 4 + r);
      lfq[r] = __shfl(lf, g * 4 + r);
    }
    const int b = bh / 12, head = bh - (bh / 12) * 12;
#pragma unroll
    for (int dt = 0; dt < 4; dt++)
#pragma unroll
      for (int r = 0; r < 4; r++) {
        float oo = oacc[dt][r] * c1q[r]
                 + o_s[(wq * 16 + g * 4 + r) * 68 + ql + 16 * dt] * c2q[r];
        float on = oo / lfq[r];
        int s = s0 + wq * 16 + g * 4 + r;
        size_t idx = ((size_t)b * SEQ + s) * 768 + head * 64 + ql + 16 * dt;
        u16 h, l;
        split2(on, h, l);
        aop[idx] = (u32)h | ((u32)l << 16);
      }
  }
}

// ---------------- proj GEMM via split-bf16 MFMA (A = packed u32 hi|lo): -> out
__global__ __launch_bounds__(256) void proj_mfma_k(
    const u32* __restrict__ aop,
    const u16* __restrict__ bthi, const u16* __restrict__ btlo,
    const float* __restrict__ bias, float* __restrict__ out)
{
  __shared__ __align__(16) u16 Ah[128*40], Al[128*40], Bh2[128*40], Bl2[128*40];
  const int tid = threadIdx.x;
  const int lane = tid & 63, wid = tid >> 6;
  const int g = lane >> 4, ql = lane & 15;
  const int wr = wid >> 1, wc = wid & 1;
  const int c0 = blockIdx.x * 128, r0 = blockIdx.y * 128;
  const int srow = tid >> 1, half = tid & 1;

  const u32* ag = aop + (size_t)(r0 + srow) * 768 + half * 16;
  const u16* bgh = bthi + (size_t)(c0 + srow) * 768 + half * 16;
  const u16* bgl = btlo + (size_t)(c0 + srow) * 768 + half * 16;

  uint4 paw[4]; uint4 pbh[2], pbl[2];
#pragma unroll
  for (int j = 0; j < 4; j++) paw[j] = *(const uint4*)(ag + j * 4);
  pbh[0] = *(const uint4*)bgh; pbh[1] = *(const uint4*)(bgh + 8);
  pbl[0] = *(const uint4*)bgl; pbl[1] = *(const uint4*)(bgl + 8);

  f32x4 acc[4][4] = {};

  for (int ks = 0; ks < 24; ks++) {
    __syncthreads();
    {
      u16 hb[16], lb[16];
      const u32* pw = (const u32*)&paw[0];
#pragma unroll
      for (int j = 0; j < 16; j++) {
        hb[j] = (u16)(pw[j] & 0xffffu);
        lb[j] = (u16)(pw[j] >> 16);
      }
      u16* d1 = Ah + srow * 40 + half * 16;
      u16* d2 = Al + srow * 40 + half * 16;
      u16* d3 = Bh2 + srow * 40 + half * 16;
      u16* d4 = Bl2 + srow * 40 + half * 16;
      *(uint4*)d1 = *(uint4*)&hb[0]; *(uint4*)(d1 + 8) = *(uint4*)&hb[8];
      *(uint4*)d2 = *(uint4*)&lb[0]; *(uint4*)(d2 + 8) = *(uint4*)&lb[8];
      *(uint4*)d3 = pbh[0]; *(uint4*)(d3 + 8) = pbh[1];
      *(uint4*)d4 = pbl[0]; *(uint4*)(d4 + 8) = pbl[1];
    }
    __syncthreads();
    if (ks < 23) {
      const int o = (ks + 1) * 32;
#pragma unroll
      for (int j = 0; j < 4; j++) paw[j] = *(const uint4*)(ag + o + j * 4);
      pbh[0] = *(const uint4*)(bgh + o); pbh[1] = *(const uint4*)(bgh + o + 8);
      pbl[0] = *(const uint4*)(bgl + o); pbl[1] = *(const uint4*)(bgl + o + 8);
    }
    s16x8 bfh[4], bfl[4];
#pragma unroll
    for (int nt = 0; nt < 4; nt++) {
      bfh[nt] = *(const s16x8*)(Bh2 + (wc * 64 + nt * 16 + ql) * 40 + g * 8);
      bfl[nt] = *(const s16x8*)(Bl2 + (wc * 64 + nt * 16 + ql) * 40 + g * 8);
    }
#pragma unroll
    for (int mt = 0; mt < 4; mt++) {
      s16x8 ah = *(const s16x8*)(Ah + (wr * 64 + mt * 16 + ql) * 40 + g * 8);
      s16x8 al = *(const s16x8*)(Al + (wr * 64 + mt * 16 + ql) * 40 + g * 8);
#pragma unroll
      for (int nt = 0; nt < 4; nt++) {
        acc[mt][nt] = __builtin_amdgcn_mfma_f32_16x16x32_bf16(ah, bfh[nt], acc[mt][nt], 0, 0, 0);
        acc[mt][nt] = __builtin_amdgcn_mfma_f32_16x16x32_bf16(ah, bfl[nt], acc[mt][nt], 0, 0, 0);
        acc[mt][nt] = __builtin_amdgcn_mfma_f32_16x16x32_bf16(al, bfh[nt], acc[mt][nt], 0, 0, 0);
      }
    }
  }
  const int col0 = c0 + wc * 64;
  const int row0 = r0 + wr * 64;
  float bb[4];
#pragma unroll
  for (int nt = 0; nt < 4; nt++) bb[nt] = bias[col0 + nt * 16 + ql];
#pragma unroll
  for (int mt = 0; mt < 4; mt++)
#pragma unroll
    for (int nt = 0; nt < 4; nt++)
#pragma unroll
      for (int r = 0; r < 4; r++)
        out[(size_t)(row0 + mt * 16 + g * 4 + r) * 768 + col0 + nt * 16 + ql] =
            acc[mt][nt][r] + bb[nt];
}

extern "C" void kernel_launch(void* const* d_in, const int* in_sizes, int n_in,
                              void* d_out, int out_size, void* d_ws, size_t ws_size,
                              hipStream_t stream) {
  const float* x      = (const float*)d_in[0];
  const float* qkv_w  = (const float*)d_in[1];
  const float* qkv_b  = (const float*)d_in[2];
  const float* proj_w = (const float*)d_in[3];
  const float* proj_b = (const float*)d_in[4];
  const float* rph    = (const float*)d_in[5];
  const float* rpw    = (const float*)d_in[6];
  float* out = (float*)d_out;
  float* ws  = (float*)d_ws;

  const size_t SZ = (size_t)24 * SEQ * HD;   // 3,538,944 elems (== 4608*768)
  float* qbuf = ws;                          // SZ f32
  u16* khi = (u16*)(ws + SZ);                // khi, klo, vhi (+dead slot)
  u16* klo = khi + SZ;
  u16* vhi = klo + SZ;
  u16* xhi = (u16*)(ws + 3 * SZ);            // 2 x SZ u16
  u16* xlo = xhi + SZ;
  u32* aop = (u32*)(ws + 4 * SZ);            // SZ u32 (packed hi|lo)
  u16* wqThi = (u16*)(ws + 5 * SZ);          // 768*2304 x2
  u16* wqTlo = wqThi + 768 * 2304;
  u16* wpThi = wqTlo + 768 * 2304;           // 768*768 x2
  u16* wpTlo = wpThi + 768 * 768;

  conv_split_k<<<1728, 256, 0, stream>>>(x, xhi, xlo);
  conv_wT_k <<<dim3(36, 12), 256, 0, stream>>>(qkv_w, wqThi, wqTlo, 768, 2304);
  conv_wT_k <<<dim3(12, 12), 256, 0, stream>>>(proj_w, wpThi, wpTlo, 768, 768);
  qkv_mfma_k<<<dim3(18, 36), 256, 0, stream>>>(xhi, xlo, wqThi, wqTlo, qkv_b,
                                               qbuf, khi, klo, vhi);
  attn_k    <<<dim3(24, 36), 512, 0, stream>>>(qbuf, khi, klo, vhi, rph, rpw, aop);
  proj_mfma_k<<<dim3(6, 36), 256, 0, stream>>>(aop, wpThi, wpTlo, proj_b, out);
}